// Round 18
// baseline (2486.710 us; speedup 1.0000x reference)
//
#include <hip/hip_runtime.h>

#define NS 512
#define NA 256
#define PGD_ITERS 300
#define POWER_ITERS 30

typedef _Float16 f16;
typedef __attribute__((ext_vector_type(4))) _Float16 f16x4;
typedef __attribute__((ext_vector_type(8))) _Float16 f16x8;
typedef __attribute__((ext_vector_type(4))) float f32x4;

// LDS layout (bytes). STG/CH live only during the syrk. YY0/YY1 (1 KiB each)
// are the atomic y-reduction buffers; ZH (512 B) is the f16 z vector.
// DTMP (512 f32 diag partials) overlays YY0+YY1.
#define CSTR 260            // f32 staging row stride (elems)
#define TSTR 24             // f16 C^T tile row stride (elems) = 48 B
#define OFF_CH  16640       // STG: 16*260*4
#define OFF_YY0 28928       // CH:  256*24*2
#define OFF_YY1 29952
#define OFF_ZH  30976
#define LDS_BYTES 31488

// ---- cross-lane primitives (VALU DPP; zero DS-pipe traffic) ----
// SAFETY: all call sites have FULL exec; branches only on wave-uniform
// scalars (readlane/readfirstlane results or wave-id comparisons).
template<int CTRL>
__device__ __forceinline__ float dpp_add(float x) {
  const int r = __builtin_amdgcn_update_dpp(0, __float_as_int(x), CTRL, 0xF, 0xF, true);
  return x + __int_as_float(r);
}
template<int CTRL>
__device__ __forceinline__ float dpp_max(float x) {
  const int r = __builtin_amdgcn_update_dpp(0, __float_as_int(x), CTRL, 0xF, 0xF, true);
  return fmaxf(x, __int_as_float(r));
}
__device__ __forceinline__ float red16(float x) {
  x = dpp_add<0x121>(x);
  x = dpp_add<0x122>(x);
  x = dpp_add<0x124>(x);
  x = dpp_add<0x128>(x);
  return x;
}
__device__ __forceinline__ float redwave_add(float x) {
  x = red16(x);
  {
    const int r = __builtin_amdgcn_update_dpp(0, __float_as_int(x), 0x142, 0xA, 0xF, true);
    x += __int_as_float(r);
  }
  {
    const int r = __builtin_amdgcn_update_dpp(0, __float_as_int(x), 0x143, 0xC, 0xF, true);
    x += __int_as_float(r);
  }
  return __int_as_float(__builtin_amdgcn_readlane(__float_as_int(x), 63));
}
__device__ __forceinline__ float redwave_max(float x) {
  x = dpp_max<0x121>(x);
  x = dpp_max<0x122>(x);
  x = dpp_max<0x124>(x);
  x = dpp_max<0x128>(x);
  {
    const int r = __builtin_amdgcn_update_dpp(__float_as_int(x), __float_as_int(x), 0x142, 0xA, 0xF, false);
    x = fmaxf(x, __int_as_float(r));
  }
  {
    const int r = __builtin_amdgcn_update_dpp(__float_as_int(x), __float_as_int(x), 0x143, 0xC, 0xF, false);
    x = fmaxf(x, __int_as_float(r));
  }
  return __int_as_float(__builtin_amdgcn_readlane(__float_as_int(x), 63));
}
__device__ __forceinline__ float rfl(float x) {
  return __int_as_float(__builtin_amdgcn_readfirstlane(__float_as_int(x)));
}
__device__ __forceinline__ float clamp01(float x) {
  return __builtin_amdgcn_fmed3f(x, 0.f, 1.f);
}
// select 1-of-4 f32 by 2-bit index (3 cndmask)
__device__ __forceinline__ float sel4f(float a0, float a1, float a2, float a3, int g) {
  const float ab = (g & 1) ? a1 : a0;
  const float cd = (g & 1) ? a3 : a2;
  return (g & 2) ? cd : ab;
}

__global__ __launch_bounds__(512, 4) void markowitz_kernel(
    const float* __restrict__ rets, const float* __restrict__ cov,
    const float* __restrict__ gam,  const float* __restrict__ alp,
    float* __restrict__ out)
{
  __shared__ char smem[LDS_BYTES] __attribute__((aligned(16)));
  float* STG  = (float*)smem;
  f16*   CH   = (f16*)(smem + OFF_CH);
  float* DTMP = (float*)(smem + OFF_YY0);   // 512 f32 overlay (YY0+YY1)

  const int t    = threadIdx.x;
  const int lane = t & 63;
  const int w8   = t >> 6;          // wave 0..7 (owns k-tiles w8, w8+8)
  const int lm   = lane & 15;
  const int hq   = lane >> 4;

  const int b = blockIdx.x;
  const float g  = gam[b];
  const float aa = fabsf(alp[b]);
  const float* __restrict__ C = cov + (size_t)b * (NA * NA);

  // ===== Phase 1: Q = (gC)^T(gC), stored as MFMA B-fragments (f16x4) =====
  // ahB[ii][J] = B-frag of Q-tile (I=w8+8ii, J): lane (lm,hq) reg i holds
  // Q[16I+4hq+i][16J+lm]  (diag slots zeroed; exact diag via dg4)
  f16x4 ahB[2][16];
  float dacc = 0.f;

  #pragma unroll
  for (int pass = 0; pass < 2; ++pass) {
    f32x4 acc1[16];
    #pragma unroll
    for (int j = 0; j < 16; ++j) acc1[j] = f32x4{0.f, 0.f, 0.f, 0.f};

    #pragma unroll 1
    for (int kb = 0; kb < 16; ++kb) {
      { // stage 16x256 f32 (gamma-folded), coalesced
        const int kk = t >> 5;
        const int ib = (t & 31) << 3;
        const float* src = C + (size_t)(kb * 16 + kk) * NA + ib;
        float* dst = STG + kk * CSTR + ib;
        float4 c0 = *(const float4*)(src);
        float4 c1 = *(const float4*)(src + 4);
        *(float4*)(dst)     = make_float4(c0.x * g, c0.y * g, c0.z * g, c0.w * g);
        *(float4*)(dst + 4) = make_float4(c1.x * g, c1.y * g, c1.z * g, c1.w * g);
      }
      __syncthreads();
      { // transpose to f16 C^T tile; pass 0 also accumulates exact diag
        const int ti = t & 255;
        const int th = t >> 8;
        f16x8 vh;
        #pragma unroll
        for (int s2 = 0; s2 < 8; ++s2) {
          const float x = STG[(8 * th + s2) * CSTR + ti];
          if (pass == 0) dacc += x * x;
          vh[s2] = (f16)x;
        }
        *(f16x8*)(CH + ti * TSTR + 8 * th) = vh;
      }
      __syncthreads();
      const int I = w8 + 8 * pass;
      const f16x4 aH = *(const f16x4*)(CH + (16 * I + lm) * TSTR + 4 * hq);
      #pragma unroll
      for (int J = 0; J < 16; ++J) {
        const f16x4 bH = *(const f16x4*)(CH + (16 * J + lm) * TSTR + 4 * hq);
        acc1[J] = __builtin_amdgcn_mfma_f32_16x16x16f16(aH, bH, acc1[J], 0, 0, 0);
      }
    }
    // pack to B-frag f16x4; zero diag element (row 16I+4hq+c == col 16J+lm)
    const int dj = w8 + 8 * pass;
    #pragma unroll
    for (int J = 0; J < 16; ++J) {
      f32x4 a = acc1[J];
      #pragma unroll
      for (int c = 0; c < 4; ++c)
        if (J == dj && lm == 4 * hq + c) a[c] = 0.f;
      f16x4 bb;
      bb[0] = (f16)a[0]; bb[1] = (f16)a[1]; bb[2] = (f16)a[2]; bb[3] = (f16)a[3];
      ahB[pass][J] = bb;
    }
  }

  // exact diag + rets for OWN columns {16*(4hq+c)+lm}
  {
    const int ti = t & 255;
    const int th = t >> 8;
    DTMP[th * 256 + ti] = dacc;
  }
  __syncthreads();
  float dg4[4], rr4[4];
  #pragma unroll
  for (int c = 0; c < 4; ++c) {
    const int col = ((4 * hq + c) << 4) + lm;
    dg4[c] = DTMP[col] + DTMP[256 + col] + aa;
    rr4[c] = rets[b * NA + col];
  }
  __syncthreads();   // DTMP dead

  float* const YY0 = (float*)(smem + OFF_YY0);
  float* const YY1 = (float*)(smem + OFF_YY1);
  f16*   const ZH  = (f16*)(smem + OFF_ZH);

  if (t < 256) { YY0[t] = 0.f; YY1[t] = 0.f; ZH[t] = (f16)1.f; }
  float zown[4];
  #pragma unroll
  for (int c = 0; c < 4; ++c) zown[c] = 1.f;   // power b0 = ones
  __syncthreads();

  const f32x4 zero4 = {0.f, 0.f, 0.f, 0.f};

  // MFMA matvec: A = z-broadcast (per I-tile, one b64 read), B = ahB.
  // D rows identical -> reg0 = I-partial of y[16J+lm]; cross-wave sum via
  // ds_add_f32. 32 MFMA on the (otherwise idle) matrix pipe; zero VALU reduce.
  auto mfma_matvec = [&](float* YYp) {
    const f16x4 a0 = *(const f16x4*)(ZH + 16 * w8 + 4 * hq);
    const f16x4 a1 = *(const f16x4*)(ZH + 16 * (w8 + 8) + 4 * hq);
    #pragma unroll
    for (int q = 0; q < 4; ++q) {
      f32x4 D0 = __builtin_amdgcn_mfma_f32_16x16x16f16(a0, ahB[0][4 * q + 0], zero4, 0, 0, 0);
      D0 = __builtin_amdgcn_mfma_f32_16x16x16f16(a1, ahB[1][4 * q + 0], D0, 0, 0, 0);
      f32x4 D1 = __builtin_amdgcn_mfma_f32_16x16x16f16(a0, ahB[0][4 * q + 1], zero4, 0, 0, 0);
      D1 = __builtin_amdgcn_mfma_f32_16x16x16f16(a1, ahB[1][4 * q + 1], D1, 0, 0, 0);
      f32x4 D2 = __builtin_amdgcn_mfma_f32_16x16x16f16(a0, ahB[0][4 * q + 2], zero4, 0, 0, 0);
      D2 = __builtin_amdgcn_mfma_f32_16x16x16f16(a1, ahB[1][4 * q + 2], D2, 0, 0, 0);
      f32x4 D3 = __builtin_amdgcn_mfma_f32_16x16x16f16(a0, ahB[0][4 * q + 3], zero4, 0, 0, 0);
      D3 = __builtin_amdgcn_mfma_f32_16x16x16f16(a1, ahB[1][4 * q + 3], D3, 0, 0, 0);
      const float val = sel4f(D0[0], D1[0], D2[0], D3[0], hq);  // J = 4q+hq
      atomicAdd(&YYp[((4 * q + hq) << 4) + lm], val);
    }
  };

  int bufsel = 0;

  // ===== Phase 2: power iteration + Rayleigh step (2 barriers/iter) =====
  float step;
  {
    #pragma unroll 1
    for (int pi = 0; pi < POWER_ITERS; ++pi) {
      float* YYp = bufsel ? YY1 : YY0;
      float* YYo = bufsel ? YY0 : YY1;
      mfma_matvec(YYp);
      __syncthreads();                         // adds visible
      float yv[4];
      float nrm = 0.f;
      #pragma unroll
      for (int c = 0; c < 4; ++c) {
        yv[c] = YYp[((4 * hq + c) << 4) + lm] + dg4[c] * zown[c];
        nrm += yv[c] * yv[c];
      }
      nrm = redwave_add(nrm);                  // own-cols partition all 256
      const float rb = 1.f / (sqrtf(nrm) + 1e-12f);
      #pragma unroll
      for (int c = 0; c < 4; ++c) zown[c] = yv[c] * rb;
      if (w8 == 0) {
        #pragma unroll
        for (int c = 0; c < 4; ++c) {
          const int col = ((4 * hq + c) << 4) + lm;
          YYo[col] = 0.f;                      // re-zero idle buffer
          ZH[col] = (f16)zown[c];
        }
      }
      __syncthreads();                         // z + zeros visible
      bufsel ^= 1;
    }
    { // lambda = z^T Q z
      float* YYp = bufsel ? YY1 : YY0;
      float* YYo = bufsel ? YY0 : YY1;
      mfma_matvec(YYp);
      __syncthreads();
      float lam = 0.f;
      #pragma unroll
      for (int c = 0; c < 4; ++c) {
        const float yv = YYp[((4 * hq + c) << 4) + lm] + dg4[c] * zown[c];
        lam += zown[c] * yv;
      }
      lam = redwave_add(lam);
      step = 1.f / (2.f * lam + 1e-6f);
      // FISTA init folded into this window
      if (w8 == 0) {
        #pragma unroll
        for (int c = 0; c < 4; ++c) {
          const int col = ((4 * hq + c) << 4) + lm;
          YYo[col] = 0.f;
          ZH[col] = (f16)(1.f / 256.f);
        }
      }
      #pragma unroll
      for (int c = 0; c < 4; ++c) zown[c] = 1.f / 256.f;
      __syncthreads();
      bufsel ^= 1;
    }
  }

  // ===== Phase 3: FISTA (2 barriers/iter; R12/R14/R17-verified projection) =====
  float wo4[4];
  #pragma unroll
  for (int c = 0; c < 4; ++c) wo4[c] = 1.f / 256.f;
  float tt = 1.f;
  float tauw = 1e30f;
  float kest = 32.f;

  #pragma unroll 1
  for (int it = 0; it < PGD_ITERS; ++it) {
    float* YYp = bufsel ? YY1 : YY0;
    float* YYo = bufsel ? YY0 : YY1;
    mfma_matvec(YYp);
    __syncthreads();

    float vq[4];
    #pragma unroll
    for (int c = 0; c < 4; ++c) {
      const float yv = YYp[((4 * hq + c) << 4) + lm] + dg4[c] * zown[c];
      vq[c] = zown[c] - step * (2.f * yv - rr4[c]);
    }

    // Projection onto {w: sum=1, 0<=w<=1} (verified): uniform-scalar secant
    // with early exit; own-cols partition -> redwave covers all 256 once.
    float lo = -1e30f, hi = 1e30f;
    float tau = tauw;
    float fprev = 0.f, tprev = 0.f;
    bool have = false;
    #pragma unroll 1
    for (int nit = 0; nit < 16; ++nit) {
      float sp = clamp01(vq[0] - tau) + clamp01(vq[1] - tau)
               + clamp01(vq[2] - tau) + clamp01(vq[3] - tau);
      const float s = redwave_add(sp);
      if (nit == 0) {
        const float pm = redwave_max(fmaxf(fmaxf(vq[0], vq[1]), fmaxf(vq[2], vq[3])));
        lo = pm - 1.0f; hi = pm;
        if (!(tau > lo && tau < hi)) { tau = 0.5f * (lo + hi); continue; }
      }
      const float f = s - 1.f;
      if (fabsf(f) <= 1e-5f) break;
      if (f > 0.f) lo = tau; else hi = tau;
      if (hi - lo < 1e-7f) break;
      float kc = have ? ((f - fprev) / (tprev - tau)) : kest;
      if (!(kc > 0.5f)) kc = kest;
      const float tn = tau + f / kc;
      fprev = f; tprev = tau; have = true;
      kest = fmaxf(kc, 1.f);
      const float tc = (tn > lo && tn < hi) ? tn : 0.5f * (lo + hi);
      if (tc == tau) break;
      tau = tc;
    }
    tauw = tau;

    const float tnew = 0.5f * (1.f + sqrtf(1.f + 4.f * tt * tt));
    const float coef = (tt - 1.f) / tnew;
    const bool last = (it == PGD_ITERS - 1);
    #pragma unroll
    for (int c = 0; c < 4; ++c) {
      const float wn = clamp01(vq[c] - tau);
      const float zn = wn + coef * (wn - wo4[c]);
      wo4[c] = wn;
      zown[c] = zn;
      const int col = ((4 * hq + c) << 4) + lm;
      if (last && w8 == 0) out[(size_t)b * NA + col] = wn;
    }
    if (w8 == 0) {
      #pragma unroll
      for (int c = 0; c < 4; ++c) {
        const int col = ((4 * hq + c) << 4) + lm;
        YYo[col] = 0.f;
        ZH[col] = (f16)zown[c];
      }
    }
    tt = tnew;
    __syncthreads();
    bufsel ^= 1;
  }
}

extern "C" void kernel_launch(void* const* d_in, const int* in_sizes, int n_in,
                              void* d_out, int out_size, void* d_ws, size_t ws_size,
                              hipStream_t stream) {
  (void)in_sizes; (void)n_in; (void)out_size; (void)d_ws; (void)ws_size;
  const float* rets = (const float*)d_in[0];
  const float* cov  = (const float*)d_in[1];
  const float* gam  = (const float*)d_in[2];
  const float* alp  = (const float*)d_in[3];
  float* out = (float*)d_out;
  hipLaunchKernelGGL(markowitz_kernel, dim3(NS), dim3(512), 0, stream,
                     rets, cov, gam, alp, out);
}

// Round 19
// 1575.604 us; speedup vs baseline: 1.5783x; 1.5783x over previous
//
#include <hip/hip_runtime.h>

#define NS 512
#define NA 256
#define PGD_ITERS 300
#define POWER_ITERS 30

typedef _Float16 f16;
typedef __attribute__((ext_vector_type(2))) _Float16 f16x2;
typedef __attribute__((ext_vector_type(4))) _Float16 f16x4;
typedef __attribute__((ext_vector_type(8))) _Float16 f16x8;
typedef __attribute__((ext_vector_type(4))) float f32x4;

// LDS layout (bytes). STG/CH live only during the syrk; YY0/YY1 double-
// buffer the y-exchange. DTMP (512 f32 diag partials) overlays YY0+YY1.
#define CSTR 260            // f32 staging row stride (elems)
#define TSTR 24             // f16 C^T tile row stride (elems) = 48 B
#define OFF_CH  16640       // STG: 16*260*4
#define OFF_YY0 28928       // CH:  256*24*2
#define OFF_YY1 29952
#define LDS_BYTES 30976

// ---- cross-lane primitives (VALU DPP + fixed-pattern ds_swizzle) ----
// SAFETY: all call sites have FULL exec; branches only on wave-uniform
// scalars (readlane/readfirstlane results or wave-id comparisons).
template<int CTRL>
__device__ __forceinline__ float dpp_add(float x) {
  const int r = __builtin_amdgcn_update_dpp(0, __float_as_int(x), CTRL, 0xF, 0xF, true);
  return x + __int_as_float(r);
}
template<int CTRL>
__device__ __forceinline__ float dpp_max(float x) {
  const int r = __builtin_amdgcn_update_dpp(0, __float_as_int(x), CTRL, 0xF, 0xF, true);
  return fmaxf(x, __int_as_float(r));
}
template<int IMM>
__device__ __forceinline__ float swzf(float x) {   // fixed lane swizzle
  return __int_as_float(__builtin_amdgcn_ds_swizzle(__float_as_int(x), IMM));
}
__device__ __forceinline__ float red16(float x) {
  x = dpp_add<0x121>(x);  // row_ror:1
  x = dpp_add<0x122>(x);  // row_ror:2
  x = dpp_add<0x124>(x);  // row_ror:4
  x = dpp_add<0x128>(x);  // row_ror:8
  return x;
}
__device__ __forceinline__ float redwave_add(float x) {
  x = red16(x);
  {
    const int r = __builtin_amdgcn_update_dpp(0, __float_as_int(x), 0x142, 0xA, 0xF, true);
    x += __int_as_float(r);
  }
  {
    const int r = __builtin_amdgcn_update_dpp(0, __float_as_int(x), 0x143, 0xC, 0xF, true);
    x += __int_as_float(r);
  }
  return __int_as_float(__builtin_amdgcn_readlane(__float_as_int(x), 63));
}
__device__ __forceinline__ float redwave_max(float x) {
  x = dpp_max<0x121>(x);
  x = dpp_max<0x122>(x);
  x = dpp_max<0x124>(x);
  x = dpp_max<0x128>(x);
  {
    const int r = __builtin_amdgcn_update_dpp(__float_as_int(x), __float_as_int(x), 0x142, 0xA, 0xF, false);
    x = fmaxf(x, __int_as_float(r));
  }
  {
    const int r = __builtin_amdgcn_update_dpp(__float_as_int(x), __float_as_int(x), 0x143, 0xC, 0xF, false);
    x = fmaxf(x, __int_as_float(r));
  }
  return __int_as_float(__builtin_amdgcn_readlane(__float_as_int(x), 63));
}
__device__ __forceinline__ float rfl(float x) {
  return __int_as_float(__builtin_amdgcn_readfirstlane(__float_as_int(x)));
}
__device__ __forceinline__ float clamp01(float x) {
  return __builtin_amdgcn_fmed3f(x, 0.f, 1.f);
}
__device__ __forceinline__ f16x2 pk2(float a, float b) {
  return __builtin_bit_cast(f16x2, __builtin_amdgcn_cvt_pkrtz(a, b));
}
__device__ __forceinline__ float dot2f(f16x2 a, f16x2 b, float c) {
  return __builtin_amdgcn_fdot2(a, b, c, false);   // v_dot2_f32_f16
}
// select 1-of-4 f32 by 2-bit index (3 cndmask)
__device__ __forceinline__ float sel4f(float a0, float a1, float a2, float a3, int g) {
  const float ab = (g & 1) ? a1 : a0;
  const float cd = (g & 1) ? a3 : a2;
  return (g & 2) ? cd : ab;
}

__global__ __launch_bounds__(512, 4) void markowitz_kernel(
    const float* __restrict__ rets, const float* __restrict__ cov,
    const float* __restrict__ gam,  const float* __restrict__ alp,
    float* __restrict__ out)
{
  __shared__ char smem[LDS_BYTES] __attribute__((aligned(16)));
  float* STG  = (float*)smem;
  f16*   CH   = (f16*)(smem + OFF_CH);
  float* DTMP = (float*)(smem + OFF_YY0);   // 512 f32 overlay (YY0+YY1)

  const int t    = threadIdx.x;
  const int lane = t & 63;
  const int w8   = t >> 6;          // wave 0..7
  const int lm   = lane & 15;       // column-within-tile owner index
  const int hq   = lane >> 4;       // row-subgroup index

  const int b = blockIdx.x;
  const float g  = gam[b];
  const float aa = fabsf(alp[b]);
  const float* __restrict__ C = cov + (size_t)b * (NA * NA);

  const bool mk = ((lm >> 2) == hq);
  const int  cw = lm & 3;

  // ===== Phase 1: Q = (gC)^T(gC), f16-packed registers + exact f32 diag =====
  // ahP[ii][g][pb][c] = f16 pair of Q-tiles (2j2, 2j2+1) with j2 = 2*(g^hq)+pb
  // (pre-permuted so matvec consumes zrpk[g][pb] with NO per-iter selects).
  f16x2 ahP[2][4][2][4];
  float dacc = 0.f;

  #pragma unroll
  for (int pass = 0; pass < 2; ++pass) {
    f32x4 acc1[16];
    #pragma unroll
    for (int j = 0; j < 16; ++j) acc1[j] = f32x4{0.f, 0.f, 0.f, 0.f};

    #pragma unroll 1
    for (int kb = 0; kb < 16; ++kb) {
      { // stage 16x256 f32 (gamma-folded), coalesced
        const int kk = t >> 5;
        const int ib = (t & 31) << 3;
        const float* src = C + (size_t)(kb * 16 + kk) * NA + ib;
        float* dst = STG + kk * CSTR + ib;
        float4 c0 = *(const float4*)(src);
        float4 c1 = *(const float4*)(src + 4);
        *(float4*)(dst)     = make_float4(c0.x * g, c0.y * g, c0.z * g, c0.w * g);
        *(float4*)(dst + 4) = make_float4(c1.x * g, c1.y * g, c1.z * g, c1.w * g);
      }
      __syncthreads();
      { // transpose to f16 C^T tile; pass 0 also accumulates exact diag
        const int ti = t & 255;
        const int th = t >> 8;       // k-half 0/1
        f16x8 vh;
        #pragma unroll
        for (int s2 = 0; s2 < 8; ++s2) {
          const float x = STG[(8 * th + s2) * CSTR + ti];
          if (pass == 0) dacc += x * x;
          vh[s2] = (f16)x;
        }
        *(f16x8*)(CH + ti * TSTR + 8 * th) = vh;
      }
      __syncthreads();
      const int I = w8 + 8 * pass;
      const f16x4 aH = *(const f16x4*)(CH + (16 * I + lm) * TSTR + 4 * hq);
      #pragma unroll
      for (int J = 0; J < 16; ++J) {
        const f16x4 bH = *(const f16x4*)(CH + (16 * J + lm) * TSTR + 4 * hq);
        acc1[J] = __builtin_amdgcn_mfma_f32_16x16x16f16(aH, bH, acc1[J], 0, 0, 0);
      }
    }
    // pack to f16 pairs, PRE-PERMUTED by hq (one-time cndmask gather);
    // zero diag slot (handled exactly via dgv)
    const int dj = w8 + 8 * pass;
    const int dt = dj >> 2, dr = dj & 3;
    #pragma unroll
    for (int gg = 0; gg < 4; ++gg) {
      #pragma unroll
      for (int pb = 0; pb < 2; ++pb) {
        #pragma unroll
        for (int c = 0; c < 4; ++c) {
          // tiles t0 = 4*(gg^hq)+2*pb, t1 = t0+1 (static-index gather by hq)
          float a0 = sel4f(acc1[4 * (gg ^ 0) + 2 * pb][c], acc1[4 * (gg ^ 1) + 2 * pb][c],
                           acc1[4 * (gg ^ 2) + 2 * pb][c], acc1[4 * (gg ^ 3) + 2 * pb][c], hq);
          float a1 = sel4f(acc1[4 * (gg ^ 0) + 2 * pb + 1][c], acc1[4 * (gg ^ 1) + 2 * pb + 1][c],
                           acc1[4 * (gg ^ 2) + 2 * pb + 1][c], acc1[4 * (gg ^ 3) + 2 * pb + 1][c], hq);
          if ((gg ^ hq) == dt && (2 * pb)     == dr && lm == 4 * hq + c) a0 = 0.f;
          if ((gg ^ hq) == dt && (2 * pb + 1) == dr && lm == 4 * hq + c) a1 = 0.f;
          ahP[pass][gg][pb][c] = pk2(a0, a1);
        }
      }
    }
  }

  // exact diag sums -> LDS overlay
  {
    const int ti = t & 255;
    const int th = t >> 8;
    DTMP[th * 256 + ti] = dacc;
  }
  __syncthreads();
  float dg0 = 0.f, dg1 = 0.f;
  if (mk) {
    const int c0 = 16 * w8 + lm, c1 = 16 * (w8 + 8) + lm;
    dg0 = DTMP[c0] + DTMP[256 + c0] + aa;
    dg1 = DTMP[c1] + DTMP[256 + c1] + aa;
  }
  f32x4 dgv0, dgv1;
  #pragma unroll
  for (int p = 0; p < 4; ++p) {
    dgv0[p] = (lm == 4 * hq + p) ? dg0 : 0.f;
    dgv1[p] = (lm == 4 * hq + p) ? dg1 : 0.f;
  }
  __syncthreads();   // DTMP dead

  float* const YY0 = (float*)(smem + OFF_YY0);
  float* const YY1 = (float*)(smem + OFF_YY1);

  // Row-relative z storage: zr[g][c] = z[16*(4*(hq^g)+c) + lm]. All static.
  float zr[4][4];
  #pragma unroll
  for (int gg = 0; gg < 4; ++gg)
    #pragma unroll
    for (int c = 0; c < 4; ++c) zr[gg][c] = 1.f;   // power b0 = ones

  // matvec: zrpk consumed directly (packing pre-permuted) — no selects.
  auto matvec = [&](f32x4& y0, f32x4& y1) {
    f16x2 zrpk[4][2];
    #pragma unroll
    for (int gg = 0; gg < 4; ++gg) {
      zrpk[gg][0] = pk2(zr[gg][0], zr[gg][1]);
      zrpk[gg][1] = pk2(zr[gg][2], zr[gg][3]);
    }
    // exact f32 diag z: zd0 = z[16*w8+lm], zd1 = z[16*(w8+8)+lm]
    float zd0 = 0.f, zd1 = 0.f;
    {
      const int g0 = (w8 >> 2) ^ hq;      // zd1 uses g0^2
      const int cc0 = w8 & 3;             // wave-uniform
      #pragma unroll
      for (int cc = 0; cc < 4; ++cc)
        if (cc0 == cc) {
          const float ab = (g0 & 1) ? zr[1][cc] : zr[0][cc];
          const float cd = (g0 & 1) ? zr[3][cc] : zr[2][cc];
          zd0 = (g0 & 2) ? cd : ab;
          zd1 = (g0 & 2) ? ab : cd;
        }
    }
    y0 = dgv0 * zd0;
    y1 = dgv1 * zd1;
    #pragma unroll
    for (int gg = 0; gg < 4; ++gg)
      #pragma unroll
      for (int pb = 0; pb < 2; ++pb)
        #pragma unroll
        for (int c = 0; c < 4; ++c) {
          y0[c] = dot2f(ahP[0][gg][pb][c], zrpk[gg][pb], y0[c]);
          y1[c] = dot2f(ahP[1][gg][pb][c], zrpk[gg][pb], y1[c]);
        }
    #pragma unroll
    for (int c = 0; c < 4; ++c) { y0[c] = red16(y0[c]); y1[c] = red16(y1[c]); }
  };
  auto publish = [&](float* YYp, const f32x4& y0, const f32x4& y1) {
    if (mk) {
      const float ya = (cw == 0) ? y0[0] : (cw == 1) ? y0[1] : (cw == 2) ? y0[2] : y0[3];
      const float yb = (cw == 0) ? y1[0] : (cw == 1) ? y1[1] : (cw == 2) ? y1[2] : y1[3];
      YYp[16 * w8 + lm]       = ya;
      YYp[16 * (w8 + 8) + lm] = yb;
    }
  };

  // ===== Phase 2: power iteration + Rayleigh step (1 barrier/iter) =====
  float step;
  {
    #pragma unroll 1
    for (int pi = 0; pi < POWER_ITERS; ++pi) {
      f32x4 y0, y1; matvec(y0, y1);
      float* YYp = (pi & 1) ? YY1 : YY0;
      publish(YYp, y0, y1);
      __syncthreads();
      float nrm = 0.f;
      #pragma unroll
      for (int gg = 0; gg < 4; ++gg)
        #pragma unroll
        for (int c = 0; c < 4; ++c) {
          const float tv = YYp[(((hq ^ gg) * 4 + c) << 4) + lm];
          nrm += tv * tv;
          zr[gg][c] = tv;
        }
      nrm = rfl(red16(nrm));
      const float rb = 1.f / (sqrtf(nrm) + 1e-12f);
      #pragma unroll
      for (int gg = 0; gg < 4; ++gg)
        #pragma unroll
        for (int c = 0; c < 4; ++c) zr[gg][c] *= rb;
    }
    f32x4 y0, y1; matvec(y0, y1);             // lambda = b^T Q b
    publish(YY0, y0, y1);
    __syncthreads();
    float lam = 0.f;
    #pragma unroll
    for (int gg = 0; gg < 4; ++gg)
      #pragma unroll
      for (int c = 0; c < 4; ++c)
        lam += zr[gg][c] * YY0[(((hq ^ gg) * 4 + c) << 4) + lm];
    lam = rfl(red16(lam));
    step = 1.f / (2.f * lam + 1e-6f);
  }

  // ===== Phase 3: FISTA — quarter-split state, 1 barrier/iter =====
  float wo4[4], rr4[4];
  #pragma unroll
  for (int c = 0; c < 4; ++c) {
    rr4[c] = rets[b * NA + ((4 * hq + c) << 4) + lm];
    wo4[c] = 1.f / 256.f;
  }
  #pragma unroll
  for (int gg = 0; gg < 4; ++gg)
    #pragma unroll
    for (int c = 0; c < 4; ++c) zr[gg][c] = 1.f / 256.f;
  float tt = 1.f;
  float tauw = 1e30f;
  float kest = 32.f;

  #pragma unroll 1
  for (int it = 0; it < PGD_ITERS; ++it) {
    f32x4 y0, y1; matvec(y0, y1);
    float* YYp = (it & 1) ? YY0 : YY1;
    publish(YYp, y0, y1);
    __syncthreads();

    // own columns only: v = z - step*(2y - r)
    float vq[4];
    #pragma unroll
    for (int c = 0; c < 4; ++c) {
      const float yv = YYp[((4 * hq + c) << 4) + lm];
      vq[c] = zr[0][c] - step * (2.f * yv - rr4[c]);
    }

    // Projection (verified R10/R12/R14/R17): uniform-scalar secant w/ early exit
    float lo = -1e30f, hi = 1e30f;
    float tau = tauw;
    float fprev = 0.f, tprev = 0.f;
    bool have = false;
    #pragma unroll 1
    for (int nit = 0; nit < 16; ++nit) {
      float sp = clamp01(vq[0] - tau) + clamp01(vq[1] - tau)
               + clamp01(vq[2] - tau) + clamp01(vq[3] - tau);
      const float s = redwave_add(sp);
      if (nit == 0) {
        const float pm = redwave_max(fmaxf(fmaxf(vq[0], vq[1]), fmaxf(vq[2], vq[3])));
        lo = pm - 1.0f; hi = pm;              // root always in [max-1, max]
        if (!(tau > lo && tau < hi)) { tau = 0.5f * (lo + hi); continue; }
      }
      const float f = s - 1.f;
      if (fabsf(f) <= 1e-5f) break;
      if (f > 0.f) lo = tau; else hi = tau;
      if (hi - lo < 1e-7f) break;
      float kc = have ? ((f - fprev) / (tprev - tau)) : kest;
      if (!(kc > 0.5f)) kc = kest;
      const float tn = tau + f / kc;
      fprev = f; tprev = tau; have = true;
      kest = fmaxf(kc, 1.f);
      const float tc = (tn > lo && tn < hi) ? tn : 0.5f * (lo + hi);
      if (tc == tau) break;
      tau = tc;
    }
    tauw = tau;

    const float tnew = 0.5f * (1.f + sqrtf(1.f + 4.f * tt * tt));
    const float coef = (tt - 1.f) / tnew;
    const bool last = (it == PGD_ITERS - 1);
    float zn[4];
    #pragma unroll
    for (int c = 0; c < 4; ++c) {
      const float wn = clamp01(vq[c] - tau);
      zn[c] = wn + coef * (wn - wo4[c]);
      wo4[c] = wn;
      if (last && w8 == 0) out[(size_t)b * NA + ((4 * hq + c) << 4) + lm] = wn;
    }
    tt = tnew;

    // f32-exact replica refill: swz16 (fixed pattern) + one bpermute + swz16
    #pragma unroll
    for (int c = 0; c < 4; ++c) {
      zr[0][c] = zn[c];
      zr[1][c] = swzf<0x401F>(zn[c]);         // lane^16
      zr[2][c] = __shfl_xor(zn[c], 32);       // lane^32
      zr[3][c] = swzf<0x401F>(zr[2][c]);      // lane^48
    }
  }
}

extern "C" void kernel_launch(void* const* d_in, const int* in_sizes, int n_in,
                              void* d_out, int out_size, void* d_ws, size_t ws_size,
                              hipStream_t stream) {
  (void)in_sizes; (void)n_in; (void)out_size; (void)d_ws; (void)ws_size;
  const float* rets = (const float*)d_in[0];
  const float* cov  = (const float*)d_in[1];
  const float* gam  = (const float*)d_in[2];
  const float* alp  = (const float*)d_in[3];
  float* out = (float*)d_out;
  hipLaunchKernelGGL(markowitz_kernel, dim3(NS), dim3(512), 0, stream,
                     rets, cov, gam, alp, out);
}

// Round 20
// 850.100 us; speedup vs baseline: 2.9252x; 1.8534x over previous
//
#include <hip/hip_runtime.h>

#define NS 512
#define NA 256
#define PGD_ITERS 300
#define POWER_ITERS 30

typedef _Float16 f16;
typedef __attribute__((ext_vector_type(2))) _Float16 f16x2;
typedef __attribute__((ext_vector_type(4))) _Float16 f16x4;
typedef __attribute__((ext_vector_type(8))) _Float16 f16x8;
typedef __attribute__((ext_vector_type(4))) float f32x4;

// LDS layout (bytes). STG/CH live only during the syrk; YY0/YY1 double-
// buffer the y-exchange. DTMP (512 f32 diag partials) overlays YY0+YY1.
#define CSTR 260            // f32 staging row stride (elems)
#define TSTR 24             // f16 C^T tile row stride (elems) = 48 B
#define OFF_CH  16640       // STG: 16*260*4
#define OFF_YY0 28928       // CH:  256*24*2
#define OFF_YY1 29952
#define LDS_BYTES 30976

// ---- cross-lane primitives (VALU DPP; minimal DS-pipe traffic) ----
// SAFETY: all call sites have FULL exec; branches only on wave-uniform
// scalars (readlane/readfirstlane results or wave-id comparisons).
template<int CTRL>
__device__ __forceinline__ float dpp_add(float x) {
  const int r = __builtin_amdgcn_update_dpp(0, __float_as_int(x), CTRL, 0xF, 0xF, true);
  return x + __int_as_float(r);
}
template<int CTRL>
__device__ __forceinline__ float dpp_max(float x) {
  const int r = __builtin_amdgcn_update_dpp(0, __float_as_int(x), CTRL, 0xF, 0xF, true);
  return fmaxf(x, __int_as_float(r));
}
__device__ __forceinline__ float red16(float x) {
  x = dpp_add<0x121>(x);  // row_ror:1
  x = dpp_add<0x122>(x);  // row_ror:2
  x = dpp_add<0x124>(x);  // row_ror:4
  x = dpp_add<0x128>(x);  // row_ror:8
  return x;
}
__device__ __forceinline__ float redwave_add(float x) {
  x = red16(x);
  {
    const int r = __builtin_amdgcn_update_dpp(0, __float_as_int(x), 0x142, 0xA, 0xF, true);
    x += __int_as_float(r);
  }
  {
    const int r = __builtin_amdgcn_update_dpp(0, __float_as_int(x), 0x143, 0xC, 0xF, true);
    x += __int_as_float(r);
  }
  return __int_as_float(__builtin_amdgcn_readlane(__float_as_int(x), 63));
}
__device__ __forceinline__ float redwave_max(float x) {
  x = dpp_max<0x121>(x);
  x = dpp_max<0x122>(x);
  x = dpp_max<0x124>(x);
  x = dpp_max<0x128>(x);
  {
    const int r = __builtin_amdgcn_update_dpp(__float_as_int(x), __float_as_int(x), 0x142, 0xA, 0xF, false);
    x = fmaxf(x, __int_as_float(r));
  }
  {
    const int r = __builtin_amdgcn_update_dpp(__float_as_int(x), __float_as_int(x), 0x143, 0xC, 0xF, false);
    x = fmaxf(x, __int_as_float(r));
  }
  return __int_as_float(__builtin_amdgcn_readlane(__float_as_int(x), 63));
}
__device__ __forceinline__ float rfl(float x) {
  return __int_as_float(__builtin_amdgcn_readfirstlane(__float_as_int(x)));
}
__device__ __forceinline__ float clamp01(float x) {
  return __builtin_amdgcn_fmed3f(x, 0.f, 1.f);
}
__device__ __forceinline__ f16x2 pk2(float a, float b) {
  return __builtin_bit_cast(f16x2, __builtin_amdgcn_cvt_pkrtz(a, b));
}
__device__ __forceinline__ float dot2f(f16x2 a, f16x2 b, float c) {
  return __builtin_amdgcn_fdot2(a, b, c, false);   // v_dot2_f32_f16
}
// select 1-of-4 packed f16x2 by 2-bit index (3 cndmask)
__device__ __forceinline__ f16x2 selg2(f16x2 a0, f16x2 a1, f16x2 a2, f16x2 a3, int g) {
  const int i0 = __builtin_bit_cast(int, a0);
  const int i1 = __builtin_bit_cast(int, a1);
  const int i2 = __builtin_bit_cast(int, a2);
  const int i3 = __builtin_bit_cast(int, a3);
  const int ab = (g & 1) ? i1 : i0;
  const int cd = (g & 1) ? i3 : i2;
  return __builtin_bit_cast(f16x2, (g & 2) ? cd : ab);
}

__global__ __launch_bounds__(512, 4) void markowitz_kernel(
    const float* __restrict__ rets, const float* __restrict__ cov,
    const float* __restrict__ gam,  const float* __restrict__ alp,
    float* __restrict__ out)
{
  __shared__ char smem[LDS_BYTES] __attribute__((aligned(16)));
  float* STG  = (float*)smem;
  f16*   CH   = (f16*)(smem + OFF_CH);
  float* DTMP = (float*)(smem + OFF_YY0);   // 512 f32 overlay (YY0+YY1)

  const int t    = threadIdx.x;
  const int lane = t & 63;
  const int w8   = t >> 6;          // wave 0..7
  const int lm   = lane & 15;       // column-within-tile owner index
  const int hq   = lane >> 4;       // row-subgroup index

  const int b = blockIdx.x;
  const float g  = gam[b];
  const float aa = fabsf(alp[b]);
  const float* __restrict__ C = cov + (size_t)b * (NA * NA);

  const bool mk = ((lm >> 2) == hq);
  const int  cw = lm & 3;

  // ===== Phase 1: Q = (gC)^T(gC), f16-packed registers + exact f32 diag =====
  // ah[ii][j2][c] packs Q[16*(w8+8ii)+4hq+c][16*(2j2)+lm | 16*(2j2+1)+lm]
  f16x2 ah[2][8][4];
  float dacc = 0.f;

  #pragma unroll
  for (int pass = 0; pass < 2; ++pass) {
    f32x4 acc1[16];
    #pragma unroll
    for (int j = 0; j < 16; ++j) acc1[j] = f32x4{0.f, 0.f, 0.f, 0.f};

    #pragma unroll 1
    for (int kb = 0; kb < 16; ++kb) {
      { // stage 16x256 f32 (gamma-folded), coalesced
        const int kk = t >> 5;
        const int ib = (t & 31) << 3;
        const float* src = C + (size_t)(kb * 16 + kk) * NA + ib;
        float* dst = STG + kk * CSTR + ib;
        float4 c0 = *(const float4*)(src);
        float4 c1 = *(const float4*)(src + 4);
        *(float4*)(dst)     = make_float4(c0.x * g, c0.y * g, c0.z * g, c0.w * g);
        *(float4*)(dst + 4) = make_float4(c1.x * g, c1.y * g, c1.z * g, c1.w * g);
      }
      __syncthreads();
      { // transpose to f16 C^T tile; pass 0 also accumulates exact diag
        const int ti = t & 255;
        const int th = t >> 8;       // k-half 0/1
        f16x8 vh;
        #pragma unroll
        for (int s2 = 0; s2 < 8; ++s2) {
          const float x = STG[(8 * th + s2) * CSTR + ti];
          if (pass == 0) dacc += x * x;
          vh[s2] = (f16)x;
        }
        *(f16x8*)(CH + ti * TSTR + 8 * th) = vh;
      }
      __syncthreads();
      const int I = w8 + 8 * pass;
      const f16x4 aH = *(const f16x4*)(CH + (16 * I + lm) * TSTR + 4 * hq);
      #pragma unroll
      for (int J = 0; J < 16; ++J) {
        const f16x4 bH = *(const f16x4*)(CH + (16 * J + lm) * TSTR + 4 * hq);
        acc1[J] = __builtin_amdgcn_mfma_f32_16x16x16f16(aH, bH, acc1[J], 0, 0, 0);
      }
    }
    // pack to f16 pairs (canonical); zero diag slot (handled exactly via dgv)
    const int dj = w8 + 8 * pass;
    #pragma unroll
    for (int j2 = 0; j2 < 8; ++j2) {
      #pragma unroll
      for (int c = 0; c < 4; ++c) {
        float a0 = acc1[2 * j2][c];
        float a1 = acc1[2 * j2 + 1][c];
        if (2 * j2     == dj && lm == 4 * hq + c) a0 = 0.f;
        if (2 * j2 + 1 == dj && lm == 4 * hq + c) a1 = 0.f;
        ah[pass][j2][c] = pk2(a0, a1);
      }
    }
  }

  // exact diag sums -> LDS overlay
  {
    const int ti = t & 255;
    const int th = t >> 8;
    DTMP[th * 256 + ti] = dacc;
  }
  __syncthreads();
  float dg0 = 0.f, dg1 = 0.f;
  if (mk) {
    const int c0 = 16 * w8 + lm, c1 = 16 * (w8 + 8) + lm;
    dg0 = DTMP[c0] + DTMP[256 + c0] + aa;
    dg1 = DTMP[c1] + DTMP[256 + c1] + aa;
  }
  f32x4 dgv0, dgv1;
  #pragma unroll
  for (int p = 0; p < 4; ++p) {
    dgv0[p] = (lm == 4 * hq + p) ? dg0 : 0.f;
    dgv1[p] = (lm == 4 * hq + p) ? dg1 : 0.f;
  }
  __syncthreads();   // DTMP dead

  float* const YY0 = (float*)(smem + OFF_YY0);
  float* const YY1 = (float*)(smem + OFF_YY1);

  // Row-relative z storage: zr[g][c] = z[16*(4*(hq^g)+c) + lm]. All static.
  float zr[4][4];
  #pragma unroll
  for (int gg = 0; gg < 4; ++gg)
    #pragma unroll
    for (int c = 0; c < 4; ++c) zr[gg][c] = 1.f;   // power b0 = ones

  // matvec: canonical zpk assembled from zr via selg2 (g = q^hq).
  auto matvec = [&](f32x4& y0, f32x4& y1) {
    f16x2 zrpk[4][2];
    #pragma unroll
    for (int gg = 0; gg < 4; ++gg) {
      zrpk[gg][0] = pk2(zr[gg][0], zr[gg][1]);
      zrpk[gg][1] = pk2(zr[gg][2], zr[gg][3]);
    }
    f16x2 zpk[8];
    #pragma unroll
    for (int j2 = 0; j2 < 8; ++j2) {
      const int q = j2 >> 1, pb = j2 & 1;
      zpk[j2] = selg2(zrpk[0][pb], zrpk[1][pb], zrpk[2][pb], zrpk[3][pb], q ^ hq);
    }
    // exact f32 diag z: zd0 = z[16*w8+lm], zd1 = z[16*(w8+8)+lm]
    float zd0 = 0.f, zd1 = 0.f;
    {
      const int g0 = (w8 >> 2) ^ hq;      // zd1 uses g0^2
      const int cc0 = w8 & 3;             // wave-uniform
      #pragma unroll
      for (int cc = 0; cc < 4; ++cc)
        if (cc0 == cc) {
          const float ab = (g0 & 1) ? zr[1][cc] : zr[0][cc];
          const float cd = (g0 & 1) ? zr[3][cc] : zr[2][cc];
          zd0 = (g0 & 2) ? cd : ab;
          zd1 = (g0 & 2) ? ab : cd;
        }
    }
    y0 = dgv0 * zd0;
    y1 = dgv1 * zd1;
    #pragma unroll
    for (int j2 = 0; j2 < 8; ++j2) {
      #pragma unroll
      for (int c = 0; c < 4; ++c) {
        y0[c] = dot2f(ah[0][j2][c], zpk[j2], y0[c]);
        y1[c] = dot2f(ah[1][j2][c], zpk[j2], y1[c]);
      }
    }
    #pragma unroll
    for (int c = 0; c < 4; ++c) { y0[c] = red16(y0[c]); y1[c] = red16(y1[c]); }
  };
  auto publish = [&](float* YYp, const f32x4& y0, const f32x4& y1) {
    if (mk) {
      const float ya = (cw == 0) ? y0[0] : (cw == 1) ? y0[1] : (cw == 2) ? y0[2] : y0[3];
      const float yb = (cw == 0) ? y1[0] : (cw == 1) ? y1[1] : (cw == 2) ? y1[2] : y1[3];
      YYp[16 * w8 + lm]       = ya;
      YYp[16 * (w8 + 8) + lm] = yb;
    }
  };

  // ===== Phase 2: power iteration + Rayleigh step (1 barrier/iter) =====
  float step;
  {
    #pragma unroll 1
    for (int pi = 0; pi < POWER_ITERS; ++pi) {
      f32x4 y0, y1; matvec(y0, y1);
      float* YYp = (pi & 1) ? YY1 : YY0;
      publish(YYp, y0, y1);
      __syncthreads();
      float nrm = 0.f;
      #pragma unroll
      for (int gg = 0; gg < 4; ++gg)
        #pragma unroll
        for (int c = 0; c < 4; ++c) {
          const float tv = YYp[(((hq ^ gg) * 4 + c) << 4) + lm];
          nrm += tv * tv;
          zr[gg][c] = tv;
        }
      nrm = rfl(red16(nrm));
      const float rb = 1.f / (sqrtf(nrm) + 1e-12f);
      #pragma unroll
      for (int gg = 0; gg < 4; ++gg)
        #pragma unroll
        for (int c = 0; c < 4; ++c) zr[gg][c] *= rb;
    }
    f32x4 y0, y1; matvec(y0, y1);             // lambda = b^T Q b
    publish(YY0, y0, y1);
    __syncthreads();
    float lam = 0.f;
    #pragma unroll
    for (int gg = 0; gg < 4; ++gg)
      #pragma unroll
      for (int c = 0; c < 4; ++c)
        lam += zr[gg][c] * YY0[(((hq ^ gg) * 4 + c) << 4) + lm];
    lam = rfl(red16(lam));
    step = 1.f / (2.f * lam + 1e-6f);
  }

  // ===== Phase 3: FISTA — quarter-split state, 1 barrier/iter,
  // exact-fixed-point early exit (bit-compatible with full 300 iters) =====
  float wo4[4], rr4[4];
  #pragma unroll
  for (int c = 0; c < 4; ++c) {
    rr4[c] = rets[b * NA + ((4 * hq + c) << 4) + lm];
    wo4[c] = 1.f / 256.f;
  }
  #pragma unroll
  for (int gg = 0; gg < 4; ++gg)
    #pragma unroll
    for (int c = 0; c < 4; ++c) zr[gg][c] = 1.f / 256.f;
  float tt = 1.f;
  float tauw = 1e30f;
  float kest = 32.f;

  #pragma unroll 1
  for (int it = 0; it < PGD_ITERS; ++it) {
    f32x4 y0, y1; matvec(y0, y1);
    float* YYp = (it & 1) ? YY0 : YY1;
    publish(YYp, y0, y1);
    __syncthreads();

    // own columns only: v = z - step*(2y - r)
    float vq[4];
    #pragma unroll
    for (int c = 0; c < 4; ++c) {
      const float yv = YYp[((4 * hq + c) << 4) + lm];
      vq[c] = zr[0][c] - step * (2.f * yv - rr4[c]);
    }

    // Projection (verified R10/R12/R14/R17): uniform-scalar secant w/ early exit
    float lo = -1e30f, hi = 1e30f;
    float tau = tauw;
    float fprev = 0.f, tprev = 0.f;
    bool have = false;
    #pragma unroll 1
    for (int nit = 0; nit < 16; ++nit) {
      float sp = clamp01(vq[0] - tau) + clamp01(vq[1] - tau)
               + clamp01(vq[2] - tau) + clamp01(vq[3] - tau);
      const float s = redwave_add(sp);
      if (nit == 0) {
        const float pm = redwave_max(fmaxf(fmaxf(vq[0], vq[1]), fmaxf(vq[2], vq[3])));
        lo = pm - 1.0f; hi = pm;              // root always in [max-1, max]
        if (!(tau > lo && tau < hi)) { tau = 0.5f * (lo + hi); continue; }
      }
      const float f = s - 1.f;
      if (fabsf(f) <= 1e-5f) break;
      if (f > 0.f) lo = tau; else hi = tau;
      if (hi - lo < 1e-7f) break;
      float kc = have ? ((f - fprev) / (tprev - tau)) : kest;
      if (!(kc > 0.5f)) kc = kest;
      const float tn = tau + f / kc;
      fprev = f; tprev = tau; have = true;
      kest = fmaxf(kc, 1.f);
      const float tc = (tn > lo && tn < hi) ? tn : 0.5f * (lo + hi);
      if (tc == tau) break;
      tau = tc;
    }
    tauw = tau;

    const float tnew = 0.5f * (1.f + sqrtf(1.f + 4.f * tt * tt));
    const float coef = (tt - 1.f) / tnew;
    float zn[4];
    float dsum = 0.f;
    #pragma unroll
    for (int c = 0; c < 4; ++c) {
      const float wn = clamp01(vq[c] - tau);
      dsum += fabsf(wn - wo4[c]);
      zn[c] = wn + coef * (wn - wo4[c]);
      wo4[c] = wn;
    }
    tt = tnew;

    // Exact fixed point: if w is bitwise unchanged across ALL 256 columns,
    // every subsequent iterate is identical (z=wn; v, tau-path, clamp all
    // deterministic) -> exiting now yields the same output as 300 iters.
    // dsum reduce is wave-uniform (all waves replicate the same columns).
    const float dtot = redwave_add(dsum);
    const bool fin = (it == PGD_ITERS - 1) || (dtot == 0.f);
    if (fin) {
      if (w8 == 0) {
        #pragma unroll
        for (int c = 0; c < 4; ++c)
          out[(size_t)b * NA + ((4 * hq + c) << 4) + lm] = wo4[c];
      }
      break;
    }

    // f32-exact 3-way exchange refills the row-relative replicas
    #pragma unroll
    for (int c = 0; c < 4; ++c) {
      zr[0][c] = zn[c];
      zr[1][c] = __shfl_xor(zn[c], 16);
      zr[2][c] = __shfl_xor(zn[c], 32);
      zr[3][c] = __shfl_xor(zn[c], 48);
    }
  }
}

extern "C" void kernel_launch(void* const* d_in, const int* in_sizes, int n_in,
                              void* d_out, int out_size, void* d_ws, size_t ws_size,
                              hipStream_t stream) {
  (void)in_sizes; (void)n_in; (void)out_size; (void)d_ws; (void)ws_size;
  const float* rets = (const float*)d_in[0];
  const float* cov  = (const float*)d_in[1];
  const float* gam  = (const float*)d_in[2];
  const float* alp  = (const float*)d_in[3];
  float* out = (float*)d_out;
  hipLaunchKernelGGL(markowitz_kernel, dim3(NS), dim3(512), 0, stream,
                     rets, cov, gam, alp, out);
}

// Round 21
// 654.921 us; speedup vs baseline: 3.7970x; 1.2980x over previous
//
#include <hip/hip_runtime.h>

#define NS 512
#define NA 256
#define PGD_ITERS 300
#define POWER_ITERS 30

typedef _Float16 f16;
typedef __attribute__((ext_vector_type(2))) _Float16 f16x2;
typedef __attribute__((ext_vector_type(4))) _Float16 f16x4;
typedef __attribute__((ext_vector_type(8))) _Float16 f16x8;
typedef __attribute__((ext_vector_type(4))) float f32x4;

// LDS layout (bytes). STG/CH live only during the syrk; YY0/YY1 double-
// buffer the y-exchange. DTMP (512 f32 diag partials) overlays YY0+YY1.
#define CSTR 260            // f32 staging row stride (elems)
#define TSTR 24             // f16 C^T tile row stride (elems) = 48 B
#define OFF_CH  16640       // STG: 16*260*4
#define OFF_YY0 28928       // CH:  256*24*2
#define OFF_YY1 29952
#define LDS_BYTES 30976

// ---- cross-lane primitives (VALU DPP; minimal DS-pipe traffic) ----
// SAFETY: all call sites have FULL exec; branches only on wave-uniform
// scalars (readlane/readfirstlane results or wave-id comparisons).
template<int CTRL>
__device__ __forceinline__ float dpp_add(float x) {
  const int r = __builtin_amdgcn_update_dpp(0, __float_as_int(x), CTRL, 0xF, 0xF, true);
  return x + __int_as_float(r);
}
template<int CTRL>
__device__ __forceinline__ float dpp_max(float x) {
  const int r = __builtin_amdgcn_update_dpp(0, __float_as_int(x), CTRL, 0xF, 0xF, true);
  return fmaxf(x, __int_as_float(r));
}
__device__ __forceinline__ float red16(float x) {
  x = dpp_add<0x121>(x);  // row_ror:1
  x = dpp_add<0x122>(x);  // row_ror:2
  x = dpp_add<0x124>(x);  // row_ror:4
  x = dpp_add<0x128>(x);  // row_ror:8
  return x;
}
__device__ __forceinline__ float redwave_add(float x) {
  x = red16(x);
  {
    const int r = __builtin_amdgcn_update_dpp(0, __float_as_int(x), 0x142, 0xA, 0xF, true);
    x += __int_as_float(r);
  }
  {
    const int r = __builtin_amdgcn_update_dpp(0, __float_as_int(x), 0x143, 0xC, 0xF, true);
    x += __int_as_float(r);
  }
  return __int_as_float(__builtin_amdgcn_readlane(__float_as_int(x), 63));
}
__device__ __forceinline__ float redwave_max(float x) {
  x = dpp_max<0x121>(x);
  x = dpp_max<0x122>(x);
  x = dpp_max<0x124>(x);
  x = dpp_max<0x128>(x);
  {
    const int r = __builtin_amdgcn_update_dpp(__float_as_int(x), __float_as_int(x), 0x142, 0xA, 0xF, false);
    x = fmaxf(x, __int_as_float(r));
  }
  {
    const int r = __builtin_amdgcn_update_dpp(__float_as_int(x), __float_as_int(x), 0x143, 0xC, 0xF, false);
    x = fmaxf(x, __int_as_float(r));
  }
  return __int_as_float(__builtin_amdgcn_readlane(__float_as_int(x), 63));
}
__device__ __forceinline__ float rfl(float x) {
  return __int_as_float(__builtin_amdgcn_readfirstlane(__float_as_int(x)));
}
__device__ __forceinline__ float clamp01(float x) {
  return __builtin_amdgcn_fmed3f(x, 0.f, 1.f);
}
__device__ __forceinline__ f16x2 pk2(float a, float b) {
  return __builtin_bit_cast(f16x2, __builtin_amdgcn_cvt_pkrtz(a, b));
}
__device__ __forceinline__ float dot2f(f16x2 a, f16x2 b, float c) {
  return __builtin_amdgcn_fdot2(a, b, c, false);   // v_dot2_f32_f16
}
// select 1-of-4 packed f16x2 by 2-bit index (3 cndmask)
__device__ __forceinline__ f16x2 selg2(f16x2 a0, f16x2 a1, f16x2 a2, f16x2 a3, int g) {
  const int i0 = __builtin_bit_cast(int, a0);
  const int i1 = __builtin_bit_cast(int, a1);
  const int i2 = __builtin_bit_cast(int, a2);
  const int i3 = __builtin_bit_cast(int, a3);
  const int ab = (g & 1) ? i1 : i0;
  const int cd = (g & 1) ? i3 : i2;
  return __builtin_bit_cast(f16x2, (g & 2) ? cd : ab);
}

__global__ __launch_bounds__(512, 4) void markowitz_kernel(
    const float* __restrict__ rets, const float* __restrict__ cov,
    const float* __restrict__ gam,  const float* __restrict__ alp,
    float* __restrict__ out)
{
  __shared__ char smem[LDS_BYTES] __attribute__((aligned(16)));
  float* STG  = (float*)smem;
  f16*   CH   = (f16*)(smem + OFF_CH);
  float* DTMP = (float*)(smem + OFF_YY0);   // 512 f32 overlay (YY0+YY1)

  const int t    = threadIdx.x;
  const int lane = t & 63;
  const int w8   = t >> 6;          // wave 0..7
  const int lm   = lane & 15;       // column-within-tile owner index
  const int hq   = lane >> 4;       // row-subgroup index

  const int b = blockIdx.x;
  const float g  = gam[b];
  const float aa = fabsf(alp[b]);
  const float* __restrict__ C = cov + (size_t)b * (NA * NA);

  const bool mk = ((lm >> 2) == hq);
  const int  cw = lm & 3;

  // ===== Phase 1: Q = (gC)^T(gC), f16-packed registers + exact f32 diag =====
  // ah[ii][j2][c] packs Q[16*(w8+8ii)+4hq+c][16*(2j2)+lm | 16*(2j2+1)+lm]
  f16x2 ah[2][8][4];
  float dacc = 0.f;

  #pragma unroll
  for (int pass = 0; pass < 2; ++pass) {
    f32x4 acc1[16];
    #pragma unroll
    for (int j = 0; j < 16; ++j) acc1[j] = f32x4{0.f, 0.f, 0.f, 0.f};

    #pragma unroll 1
    for (int kb = 0; kb < 16; ++kb) {
      { // stage 16x256 f32 (gamma-folded), coalesced
        const int kk = t >> 5;
        const int ib = (t & 31) << 3;
        const float* src = C + (size_t)(kb * 16 + kk) * NA + ib;
        float* dst = STG + kk * CSTR + ib;
        float4 c0 = *(const float4*)(src);
        float4 c1 = *(const float4*)(src + 4);
        *(float4*)(dst)     = make_float4(c0.x * g, c0.y * g, c0.z * g, c0.w * g);
        *(float4*)(dst + 4) = make_float4(c1.x * g, c1.y * g, c1.z * g, c1.w * g);
      }
      __syncthreads();
      { // transpose to f16 C^T tile; pass 0 also accumulates exact diag
        const int ti = t & 255;
        const int th = t >> 8;       // k-half 0/1
        f16x8 vh;
        #pragma unroll
        for (int s2 = 0; s2 < 8; ++s2) {
          const float x = STG[(8 * th + s2) * CSTR + ti];
          if (pass == 0) dacc += x * x;
          vh[s2] = (f16)x;
        }
        *(f16x8*)(CH + ti * TSTR + 8 * th) = vh;
      }
      __syncthreads();
      const int I = w8 + 8 * pass;
      const f16x4 aH = *(const f16x4*)(CH + (16 * I + lm) * TSTR + 4 * hq);
      #pragma unroll
      for (int J = 0; J < 16; ++J) {
        const f16x4 bH = *(const f16x4*)(CH + (16 * J + lm) * TSTR + 4 * hq);
        acc1[J] = __builtin_amdgcn_mfma_f32_16x16x16f16(aH, bH, acc1[J], 0, 0, 0);
      }
    }
    // pack to f16 pairs (canonical); zero diag slot (handled exactly via dgv)
    const int dj = w8 + 8 * pass;
    #pragma unroll
    for (int j2 = 0; j2 < 8; ++j2) {
      #pragma unroll
      for (int c = 0; c < 4; ++c) {
        float a0 = acc1[2 * j2][c];
        float a1 = acc1[2 * j2 + 1][c];
        if (2 * j2     == dj && lm == 4 * hq + c) a0 = 0.f;
        if (2 * j2 + 1 == dj && lm == 4 * hq + c) a1 = 0.f;
        ah[pass][j2][c] = pk2(a0, a1);
      }
    }
  }

  // exact diag sums -> LDS overlay
  {
    const int ti = t & 255;
    const int th = t >> 8;
    DTMP[th * 256 + ti] = dacc;
  }
  __syncthreads();
  float dg0 = 0.f, dg1 = 0.f;
  if (mk) {
    const int c0 = 16 * w8 + lm, c1 = 16 * (w8 + 8) + lm;
    dg0 = DTMP[c0] + DTMP[256 + c0] + aa;
    dg1 = DTMP[c1] + DTMP[256 + c1] + aa;
  }
  f32x4 dgv0, dgv1;
  #pragma unroll
  for (int p = 0; p < 4; ++p) {
    dgv0[p] = (lm == 4 * hq + p) ? dg0 : 0.f;
    dgv1[p] = (lm == 4 * hq + p) ? dg1 : 0.f;
  }
  __syncthreads();   // DTMP dead

  float* const YY0 = (float*)(smem + OFF_YY0);
  float* const YY1 = (float*)(smem + OFF_YY1);

  // Row-relative z storage: zr[g][c] = z[16*(4*(hq^g)+c) + lm]. All static.
  float zr[4][4];
  #pragma unroll
  for (int gg = 0; gg < 4; ++gg)
    #pragma unroll
    for (int c = 0; c < 4; ++c) zr[gg][c] = 1.f;   // power b0 = ones

  // matvec: canonical zpk assembled from zr via selg2 (g = q^hq).
  auto matvec = [&](f32x4& y0, f32x4& y1) {
    f16x2 zrpk[4][2];
    #pragma unroll
    for (int gg = 0; gg < 4; ++gg) {
      zrpk[gg][0] = pk2(zr[gg][0], zr[gg][1]);
      zrpk[gg][1] = pk2(zr[gg][2], zr[gg][3]);
    }
    f16x2 zpk[8];
    #pragma unroll
    for (int j2 = 0; j2 < 8; ++j2) {
      const int q = j2 >> 1, pb = j2 & 1;
      zpk[j2] = selg2(zrpk[0][pb], zrpk[1][pb], zrpk[2][pb], zrpk[3][pb], q ^ hq);
    }
    // exact f32 diag z: zd0 = z[16*w8+lm], zd1 = z[16*(w8+8)+lm]
    float zd0 = 0.f, zd1 = 0.f;
    {
      const int g0 = (w8 >> 2) ^ hq;      // zd1 uses g0^2
      const int cc0 = w8 & 3;             // wave-uniform
      #pragma unroll
      for (int cc = 0; cc < 4; ++cc)
        if (cc0 == cc) {
          const float ab = (g0 & 1) ? zr[1][cc] : zr[0][cc];
          const float cd = (g0 & 1) ? zr[3][cc] : zr[2][cc];
          zd0 = (g0 & 2) ? cd : ab;
          zd1 = (g0 & 2) ? ab : cd;
        }
    }
    y0 = dgv0 * zd0;
    y1 = dgv1 * zd1;
    #pragma unroll
    for (int j2 = 0; j2 < 8; ++j2) {
      #pragma unroll
      for (int c = 0; c < 4; ++c) {
        y0[c] = dot2f(ah[0][j2][c], zpk[j2], y0[c]);
        y1[c] = dot2f(ah[1][j2][c], zpk[j2], y1[c]);
      }
    }
    #pragma unroll
    for (int c = 0; c < 4; ++c) { y0[c] = red16(y0[c]); y1[c] = red16(y1[c]); }
  };
  auto publish = [&](float* YYp, const f32x4& y0, const f32x4& y1) {
    if (mk) {
      const float ya = (cw == 0) ? y0[0] : (cw == 1) ? y0[1] : (cw == 2) ? y0[2] : y0[3];
      const float yb = (cw == 0) ? y1[0] : (cw == 1) ? y1[1] : (cw == 2) ? y1[2] : y1[3];
      YYp[16 * w8 + lm]       = ya;
      YYp[16 * (w8 + 8) + lm] = yb;
    }
  };

  // ===== Phase 2: power iteration + Rayleigh step (1 barrier/iter) =====
  float step;
  {
    #pragma unroll 1
    for (int pi = 0; pi < POWER_ITERS; ++pi) {
      f32x4 y0, y1; matvec(y0, y1);
      float* YYp = (pi & 1) ? YY1 : YY0;
      publish(YYp, y0, y1);
      __syncthreads();
      float nrm = 0.f;
      #pragma unroll
      for (int gg = 0; gg < 4; ++gg)
        #pragma unroll
        for (int c = 0; c < 4; ++c) {
          const float tv = YYp[(((hq ^ gg) * 4 + c) << 4) + lm];
          nrm += tv * tv;
          zr[gg][c] = tv;
        }
      nrm = rfl(red16(nrm));
      const float rb = 1.f / (sqrtf(nrm) + 1e-12f);
      #pragma unroll
      for (int gg = 0; gg < 4; ++gg)
        #pragma unroll
        for (int c = 0; c < 4; ++c) zr[gg][c] *= rb;
    }
    f32x4 y0, y1; matvec(y0, y1);             // lambda = b^T Q b
    publish(YY0, y0, y1);
    __syncthreads();
    float lam = 0.f;
    #pragma unroll
    for (int gg = 0; gg < 4; ++gg)
      #pragma unroll
      for (int c = 0; c < 4; ++c)
        lam += zr[gg][c] * YY0[(((hq ^ gg) * 4 + c) << 4) + lm];
    lam = rfl(red16(lam));
    step = 1.f / (2.f * lam + 1e-6f);
  }

  // ===== Phase 3: FISTA — quarter-split state, 1 barrier/iter,
  // tolerance early exit (remaining drift << threshold; see analysis) =====
  float wo4[4], rr4[4];
  #pragma unroll
  for (int c = 0; c < 4; ++c) {
    rr4[c] = rets[b * NA + ((4 * hq + c) << 4) + lm];
    wo4[c] = 1.f / 256.f;
  }
  #pragma unroll
  for (int gg = 0; gg < 4; ++gg)
    #pragma unroll
    for (int c = 0; c < 4; ++c) zr[gg][c] = 1.f / 256.f;
  float tt = 1.f;
  float tauw = 1e30f;
  float kest = 32.f;

  #pragma unroll 1
  for (int it = 0; it < PGD_ITERS; ++it) {
    f32x4 y0, y1; matvec(y0, y1);
    float* YYp = (it & 1) ? YY0 : YY1;
    publish(YYp, y0, y1);
    __syncthreads();

    // own columns only: v = z - step*(2y - r)
    float vq[4];
    #pragma unroll
    for (int c = 0; c < 4; ++c) {
      const float yv = YYp[((4 * hq + c) << 4) + lm];
      vq[c] = zr[0][c] - step * (2.f * yv - rr4[c]);
    }

    // Projection (verified R10/R12/R14/R17): uniform-scalar secant w/ early exit
    float lo = -1e30f, hi = 1e30f;
    float tau = tauw;
    float fprev = 0.f, tprev = 0.f;
    bool have = false;
    #pragma unroll 1
    for (int nit = 0; nit < 16; ++nit) {
      float sp = clamp01(vq[0] - tau) + clamp01(vq[1] - tau)
               + clamp01(vq[2] - tau) + clamp01(vq[3] - tau);
      const float s = redwave_add(sp);
      if (nit == 0) {
        const float pm = redwave_max(fmaxf(fmaxf(vq[0], vq[1]), fmaxf(vq[2], vq[3])));
        lo = pm - 1.0f; hi = pm;              // root always in [max-1, max]
        if (!(tau > lo && tau < hi)) { tau = 0.5f * (lo + hi); continue; }
      }
      const float f = s - 1.f;
      if (fabsf(f) <= 1e-5f) break;
      if (f > 0.f) lo = tau; else hi = tau;
      if (hi - lo < 1e-7f) break;
      float kc = have ? ((f - fprev) / (tprev - tau)) : kest;
      if (!(kc > 0.5f)) kc = kest;
      const float tn = tau + f / kc;
      fprev = f; tprev = tau; have = true;
      kest = fmaxf(kc, 1.f);
      const float tc = (tn > lo && tn < hi) ? tn : 0.5f * (lo + hi);
      if (tc == tau) break;
      tau = tc;
    }
    tauw = tau;

    const float tnew = 0.5f * (1.f + sqrtf(1.f + 4.f * tt * tt));
    const float coef = (tt - 1.f) / tnew;
    float zn[4];
    float dsum = 0.f;
    #pragma unroll
    for (int c = 0; c < 4; ++c) {
      const float wn = clamp01(vq[c] - tau);
      dsum += fabsf(wn - wo4[c]);
      zn[c] = wn + coef * (wn - wo4[c]);
      wo4[c] = wn;
    }
    tt = tnew;

    // Early exit: dtot = sum_256 |Δw|. At dtot <= 1e-5 (~4e-8/elem, ~80 ulps
    // summed) the iterate is at the fixed point to within f32 granularity;
    // remaining drift <= dtot/(1-q) ~ 1e-3 worst case << 2e-2 threshold.
    // dsum reduce is wave-uniform (all waves replicate the same columns).
    const float dtot = redwave_add(dsum);
    const bool fin = (it == PGD_ITERS - 1) || (dtot <= 1e-5f);
    if (fin) {
      if (w8 == 0) {
        #pragma unroll
        for (int c = 0; c < 4; ++c)
          out[(size_t)b * NA + ((4 * hq + c) << 4) + lm] = wo4[c];
      }
      break;
    }

    // f32-exact 3-way exchange refills the row-relative replicas
    #pragma unroll
    for (int c = 0; c < 4; ++c) {
      zr[0][c] = zn[c];
      zr[1][c] = __shfl_xor(zn[c], 16);
      zr[2][c] = __shfl_xor(zn[c], 32);
      zr[3][c] = __shfl_xor(zn[c], 48);
    }
  }
}

extern "C" void kernel_launch(void* const* d_in, const int* in_sizes, int n_in,
                              void* d_out, int out_size, void* d_ws, size_t ws_size,
                              hipStream_t stream) {
  (void)in_sizes; (void)n_in; (void)out_size; (void)d_ws; (void)ws_size;
  const float* rets = (const float*)d_in[0];
  const float* cov  = (const float*)d_in[1];
  const float* gam  = (const float*)d_in[2];
  const float* alp  = (const float*)d_in[3];
  float* out = (float*)d_out;
  hipLaunchKernelGGL(markowitz_kernel, dim3(NS), dim3(512), 0, stream,
                     rets, cov, gam, alp, out);
}

// Round 22
// 634.121 us; speedup vs baseline: 3.9215x; 1.0328x over previous
//
#include <hip/hip_runtime.h>

#define NS 512
#define NA 256
#define PGD_ITERS 300
#define POWER_ITERS 12

typedef _Float16 f16;
typedef __attribute__((ext_vector_type(2))) _Float16 f16x2;
typedef __attribute__((ext_vector_type(4))) _Float16 f16x4;
typedef __attribute__((ext_vector_type(8))) _Float16 f16x8;
typedef __attribute__((ext_vector_type(4))) float f32x4;

// LDS layout (bytes). STG/CH live only during the syrk; YY0/YY1 double-
// buffer the y-exchange. DTMP (512 f32 diag partials) overlays YY0+YY1.
#define CSTR 260            // f32 staging row stride (elems)
#define TSTR 24             // f16 C^T tile row stride (elems) = 48 B
#define OFF_CH  16640       // STG: 16*260*4
#define OFF_YY0 28928       // CH:  256*24*2
#define OFF_YY1 29952
#define LDS_BYTES 30976

// ---- cross-lane primitives (VALU DPP; minimal DS-pipe traffic) ----
// SAFETY: all call sites have FULL exec; branches only on wave-uniform
// scalars (readlane/readfirstlane results or wave-id comparisons).
template<int CTRL>
__device__ __forceinline__ float dpp_add(float x) {
  const int r = __builtin_amdgcn_update_dpp(0, __float_as_int(x), CTRL, 0xF, 0xF, true);
  return x + __int_as_float(r);
}
template<int CTRL>
__device__ __forceinline__ float dpp_max(float x) {
  const int r = __builtin_amdgcn_update_dpp(0, __float_as_int(x), CTRL, 0xF, 0xF, true);
  return fmaxf(x, __int_as_float(r));
}
__device__ __forceinline__ float red16(float x) {
  x = dpp_add<0x121>(x);  // row_ror:1
  x = dpp_add<0x122>(x);  // row_ror:2
  x = dpp_add<0x124>(x);  // row_ror:4
  x = dpp_add<0x128>(x);  // row_ror:8
  return x;
}
__device__ __forceinline__ float redwave_add(float x) {
  x = red16(x);
  {
    const int r = __builtin_amdgcn_update_dpp(0, __float_as_int(x), 0x142, 0xA, 0xF, true);
    x += __int_as_float(r);
  }
  {
    const int r = __builtin_amdgcn_update_dpp(0, __float_as_int(x), 0x143, 0xC, 0xF, true);
    x += __int_as_float(r);
  }
  return __int_as_float(__builtin_amdgcn_readlane(__float_as_int(x), 63));
}
__device__ __forceinline__ float redwave_max(float x) {
  x = dpp_max<0x121>(x);
  x = dpp_max<0x122>(x);
  x = dpp_max<0x124>(x);
  x = dpp_max<0x128>(x);
  {
    const int r = __builtin_amdgcn_update_dpp(__float_as_int(x), __float_as_int(x), 0x142, 0xA, 0xF, false);
    x = fmaxf(x, __int_as_float(r));
  }
  {
    const int r = __builtin_amdgcn_update_dpp(__float_as_int(x), __float_as_int(x), 0x143, 0xC, 0xF, false);
    x = fmaxf(x, __int_as_float(r));
  }
  return __int_as_float(__builtin_amdgcn_readlane(__float_as_int(x), 63));
}
__device__ __forceinline__ float rfl(float x) {
  return __int_as_float(__builtin_amdgcn_readfirstlane(__float_as_int(x)));
}
__device__ __forceinline__ float clamp01(float x) {
  return __builtin_amdgcn_fmed3f(x, 0.f, 1.f);
}
__device__ __forceinline__ f16x2 pk2(float a, float b) {
  return __builtin_bit_cast(f16x2, __builtin_amdgcn_cvt_pkrtz(a, b));
}
__device__ __forceinline__ float dot2f(f16x2 a, f16x2 b, float c) {
  return __builtin_amdgcn_fdot2(a, b, c, false);   // v_dot2_f32_f16
}
// select 1-of-4 packed f16x2 by 2-bit index (3 cndmask)
__device__ __forceinline__ f16x2 selg2(f16x2 a0, f16x2 a1, f16x2 a2, f16x2 a3, int g) {
  const int i0 = __builtin_bit_cast(int, a0);
  const int i1 = __builtin_bit_cast(int, a1);
  const int i2 = __builtin_bit_cast(int, a2);
  const int i3 = __builtin_bit_cast(int, a3);
  const int ab = (g & 1) ? i1 : i0;
  const int cd = (g & 1) ? i3 : i2;
  return __builtin_bit_cast(f16x2, (g & 2) ? cd : ab);
}

__global__ __launch_bounds__(512, 4) void markowitz_kernel(
    const float* __restrict__ rets, const float* __restrict__ cov,
    const float* __restrict__ gam,  const float* __restrict__ alp,
    float* __restrict__ out)
{
  __shared__ char smem[LDS_BYTES] __attribute__((aligned(16)));
  float* STG  = (float*)smem;
  f16*   CH   = (f16*)(smem + OFF_CH);
  float* DTMP = (float*)(smem + OFF_YY0);   // 512 f32 overlay (YY0+YY1)

  const int t    = threadIdx.x;
  const int lane = t & 63;
  const int w8   = t >> 6;          // wave 0..7
  const int lm   = lane & 15;       // column-within-tile owner index
  const int hq   = lane >> 4;       // row-subgroup index

  const int b = blockIdx.x;
  const float g  = gam[b];
  const float aa = fabsf(alp[b]);
  const float* __restrict__ C = cov + (size_t)b * (NA * NA);

  const bool mk = ((lm >> 2) == hq);
  const int  cw = lm & 3;

  // ===== Phase 1: Q = (gC)^T(gC), f16-packed registers + exact f32 diag =====
  // ah[ii][j2][c] packs Q[16*(w8+8ii)+4hq+c][16*(2j2)+lm | 16*(2j2+1)+lm]
  f16x2 ah[2][8][4];
  float dacc = 0.f;

  #pragma unroll
  for (int pass = 0; pass < 2; ++pass) {
    f32x4 acc1[16];
    #pragma unroll
    for (int j = 0; j < 16; ++j) acc1[j] = f32x4{0.f, 0.f, 0.f, 0.f};

    #pragma unroll 1
    for (int kb = 0; kb < 16; ++kb) {
      { // stage 16x256 f32 (gamma-folded), coalesced
        const int kk = t >> 5;
        const int ib = (t & 31) << 3;
        const float* src = C + (size_t)(kb * 16 + kk) * NA + ib;
        float* dst = STG + kk * CSTR + ib;
        float4 c0 = *(const float4*)(src);
        float4 c1 = *(const float4*)(src + 4);
        *(float4*)(dst)     = make_float4(c0.x * g, c0.y * g, c0.z * g, c0.w * g);
        *(float4*)(dst + 4) = make_float4(c1.x * g, c1.y * g, c1.z * g, c1.w * g);
      }
      __syncthreads();
      { // transpose to f16 C^T tile; pass 0 also accumulates exact diag
        const int ti = t & 255;
        const int th = t >> 8;       // k-half 0/1
        f16x8 vh;
        #pragma unroll
        for (int s2 = 0; s2 < 8; ++s2) {
          const float x = STG[(8 * th + s2) * CSTR + ti];
          if (pass == 0) dacc += x * x;
          vh[s2] = (f16)x;
        }
        *(f16x8*)(CH + ti * TSTR + 8 * th) = vh;
      }
      __syncthreads();
      const int I = w8 + 8 * pass;
      const f16x4 aH = *(const f16x4*)(CH + (16 * I + lm) * TSTR + 4 * hq);
      #pragma unroll
      for (int J = 0; J < 16; ++J) {
        const f16x4 bH = *(const f16x4*)(CH + (16 * J + lm) * TSTR + 4 * hq);
        acc1[J] = __builtin_amdgcn_mfma_f32_16x16x16f16(aH, bH, acc1[J], 0, 0, 0);
      }
    }
    // pack to f16 pairs (canonical); zero diag slot (handled exactly via dgv)
    const int dj = w8 + 8 * pass;
    #pragma unroll
    for (int j2 = 0; j2 < 8; ++j2) {
      #pragma unroll
      for (int c = 0; c < 4; ++c) {
        float a0 = acc1[2 * j2][c];
        float a1 = acc1[2 * j2 + 1][c];
        if (2 * j2     == dj && lm == 4 * hq + c) a0 = 0.f;
        if (2 * j2 + 1 == dj && lm == 4 * hq + c) a1 = 0.f;
        ah[pass][j2][c] = pk2(a0, a1);
      }
    }
  }

  // exact diag sums -> LDS overlay
  {
    const int ti = t & 255;
    const int th = t >> 8;
    DTMP[th * 256 + ti] = dacc;
  }
  __syncthreads();
  float dg0 = 0.f, dg1 = 0.f;
  if (mk) {
    const int c0 = 16 * w8 + lm, c1 = 16 * (w8 + 8) + lm;
    dg0 = DTMP[c0] + DTMP[256 + c0] + aa;
    dg1 = DTMP[c1] + DTMP[256 + c1] + aa;
  }
  f32x4 dgv0, dgv1;
  #pragma unroll
  for (int p = 0; p < 4; ++p) {
    dgv0[p] = (lm == 4 * hq + p) ? dg0 : 0.f;
    dgv1[p] = (lm == 4 * hq + p) ? dg1 : 0.f;
  }
  __syncthreads();   // DTMP dead

  float* const YY0 = (float*)(smem + OFF_YY0);
  float* const YY1 = (float*)(smem + OFF_YY1);

  // Row-relative z storage: zr[g][c] = z[16*(4*(hq^g)+c) + lm]. All static.
  float zr[4][4];
  #pragma unroll
  for (int gg = 0; gg < 4; ++gg)
    #pragma unroll
    for (int c = 0; c < 4; ++c) zr[gg][c] = 1.f;   // power b0 = ones

  // matvec: canonical zpk assembled from zr via selg2 (g = q^hq).
  auto matvec = [&](f32x4& y0, f32x4& y1) {
    f16x2 zrpk[4][2];
    #pragma unroll
    for (int gg = 0; gg < 4; ++gg) {
      zrpk[gg][0] = pk2(zr[gg][0], zr[gg][1]);
      zrpk[gg][1] = pk2(zr[gg][2], zr[gg][3]);
    }
    f16x2 zpk[8];
    #pragma unroll
    for (int j2 = 0; j2 < 8; ++j2) {
      const int q = j2 >> 1, pb = j2 & 1;
      zpk[j2] = selg2(zrpk[0][pb], zrpk[1][pb], zrpk[2][pb], zrpk[3][pb], q ^ hq);
    }
    // exact f32 diag z: zd0 = z[16*w8+lm], zd1 = z[16*(w8+8)+lm]
    float zd0 = 0.f, zd1 = 0.f;
    {
      const int g0 = (w8 >> 2) ^ hq;      // zd1 uses g0^2
      const int cc0 = w8 & 3;             // wave-uniform
      #pragma unroll
      for (int cc = 0; cc < 4; ++cc)
        if (cc0 == cc) {
          const float ab = (g0 & 1) ? zr[1][cc] : zr[0][cc];
          const float cd = (g0 & 1) ? zr[3][cc] : zr[2][cc];
          zd0 = (g0 & 2) ? cd : ab;
          zd1 = (g0 & 2) ? ab : cd;
        }
    }
    y0 = dgv0 * zd0;
    y1 = dgv1 * zd1;
    #pragma unroll
    for (int j2 = 0; j2 < 8; ++j2) {
      #pragma unroll
      for (int c = 0; c < 4; ++c) {
        y0[c] = dot2f(ah[0][j2][c], zpk[j2], y0[c]);
        y1[c] = dot2f(ah[1][j2][c], zpk[j2], y1[c]);
      }
    }
    #pragma unroll
    for (int c = 0; c < 4; ++c) { y0[c] = red16(y0[c]); y1[c] = red16(y1[c]); }
  };
  auto publish = [&](float* YYp, const f32x4& y0, const f32x4& y1) {
    if (mk) {
      const float ya = (cw == 0) ? y0[0] : (cw == 1) ? y0[1] : (cw == 2) ? y0[2] : y0[3];
      const float yb = (cw == 0) ? y1[0] : (cw == 1) ? y1[1] : (cw == 2) ? y1[2] : y1[3];
      YYp[16 * w8 + lm]       = ya;
      YYp[16 * (w8 + 8) + lm] = yb;
    }
  };

  // ===== Phase 2: power iteration; step from ||Qb|| with safety margin =====
  // With the fixed-point early exit, the FISTA limit is the unique QP
  // minimizer for ANY step <= 1/L, so lambda need not match the reference's
  // Rayleigh estimate — it only needs lambda >= lambda_max for convergence.
  // ||Qb|| after normalization >= Rayleigh(b); x1.08 inflation covers the
  // 12-vs-30-iteration estimation gap (typ. lambda_est ~ 0.93-0.97 lmax).
  float step;
  {
    float lam = 0.f;
    #pragma unroll 1
    for (int pi = 0; pi < POWER_ITERS; ++pi) {
      f32x4 y0, y1; matvec(y0, y1);
      float* YYp = (pi & 1) ? YY1 : YY0;
      publish(YYp, y0, y1);
      __syncthreads();
      float nrm = 0.f;
      #pragma unroll
      for (int gg = 0; gg < 4; ++gg)
        #pragma unroll
        for (int c = 0; c < 4; ++c) {
          const float tv = YYp[(((hq ^ gg) * 4 + c) << 4) + lm];
          nrm += tv * tv;
          zr[gg][c] = tv;
        }
      nrm = rfl(red16(nrm));
      const float nn = sqrtf(nrm);
      lam = nn;                               // ||Q b_{k-1}|| (b normalized)
      const float rb = 1.f / (nn + 1e-12f);
      #pragma unroll
      for (int gg = 0; gg < 4; ++gg)
        #pragma unroll
        for (int c = 0; c < 4; ++c) zr[gg][c] *= rb;
    }
    step = 1.f / (2.f * (1.08f * lam) + 1e-6f);
  }

  // ===== Phase 3: FISTA — quarter-split state, 1 barrier/iter,
  // tolerance early exit (remaining drift << threshold; see R20/R21) =====
  float wo4[4], rr4[4];
  #pragma unroll
  for (int c = 0; c < 4; ++c) {
    rr4[c] = rets[b * NA + ((4 * hq + c) << 4) + lm];
    wo4[c] = 1.f / 256.f;
  }
  #pragma unroll
  for (int gg = 0; gg < 4; ++gg)
    #pragma unroll
    for (int c = 0; c < 4; ++c) zr[gg][c] = 1.f / 256.f;
  float tt = 1.f;
  float tauw = 1e30f;
  float kest = 32.f;

  #pragma unroll 1
  for (int it = 0; it < PGD_ITERS; ++it) {
    f32x4 y0, y1; matvec(y0, y1);
    float* YYp = (it & 1) ? YY0 : YY1;
    publish(YYp, y0, y1);
    __syncthreads();

    // own columns only: v = z - step*(2y - r)
    float vq[4];
    #pragma unroll
    for (int c = 0; c < 4; ++c) {
      const float yv = YYp[((4 * hq + c) << 4) + lm];
      vq[c] = zr[0][c] - step * (2.f * yv - rr4[c]);
    }

    // Projection (verified R10/R12/R14/R17): uniform-scalar secant w/ early exit
    float lo = -1e30f, hi = 1e30f;
    float tau = tauw;
    float fprev = 0.f, tprev = 0.f;
    bool have = false;
    #pragma unroll 1
    for (int nit = 0; nit < 16; ++nit) {
      float sp = clamp01(vq[0] - tau) + clamp01(vq[1] - tau)
               + clamp01(vq[2] - tau) + clamp01(vq[3] - tau);
      const float s = redwave_add(sp);
      if (nit == 0) {
        const float pm = redwave_max(fmaxf(fmaxf(vq[0], vq[1]), fmaxf(vq[2], vq[3])));
        lo = pm - 1.0f; hi = pm;              // root always in [max-1, max]
        if (!(tau > lo && tau < hi)) { tau = 0.5f * (lo + hi); continue; }
      }
      const float f = s - 1.f;
      if (fabsf(f) <= 1e-5f) break;
      if (f > 0.f) lo = tau; else hi = tau;
      if (hi - lo < 1e-7f) break;
      float kc = have ? ((f - fprev) / (tprev - tau)) : kest;
      if (!(kc > 0.5f)) kc = kest;
      const float tn = tau + f / kc;
      fprev = f; tprev = tau; have = true;
      kest = fmaxf(kc, 1.f);
      const float tc = (tn > lo && tn < hi) ? tn : 0.5f * (lo + hi);
      if (tc == tau) break;
      tau = tc;
    }
    tauw = tau;

    const float tnew = 0.5f * (1.f + sqrtf(1.f + 4.f * tt * tt));
    const float coef = (tt - 1.f) / tnew;
    float zn[4];
    float dsum = 0.f;
    #pragma unroll
    for (int c = 0; c < 4; ++c) {
      const float wn = clamp01(vq[c] - tau);
      dsum += fabsf(wn - wo4[c]);
      zn[c] = wn + coef * (wn - wo4[c]);
      wo4[c] = wn;
    }
    tt = tnew;

    // Early exit: dtot = sum_256 |Δw| <= 1e-5 -> at fixed point to f32
    // granularity; remaining drift << 2e-2 threshold (R21-verified).
    const float dtot = redwave_add(dsum);
    const bool fin = (it == PGD_ITERS - 1) || (dtot <= 1e-5f);
    if (fin) {
      if (w8 == 0) {
        #pragma unroll
        for (int c = 0; c < 4; ++c)
          out[(size_t)b * NA + ((4 * hq + c) << 4) + lm] = wo4[c];
      }
      break;
    }

    // f32-exact 3-way exchange refills the row-relative replicas
    #pragma unroll
    for (int c = 0; c < 4; ++c) {
      zr[0][c] = zn[c];
      zr[1][c] = __shfl_xor(zn[c], 16);
      zr[2][c] = __shfl_xor(zn[c], 32);
      zr[3][c] = __shfl_xor(zn[c], 48);
    }
  }
}

extern "C" void kernel_launch(void* const* d_in, const int* in_sizes, int n_in,
                              void* d_out, int out_size, void* d_ws, size_t ws_size,
                              hipStream_t stream) {
  (void)in_sizes; (void)n_in; (void)out_size; (void)d_ws; (void)ws_size;
  const float* rets = (const float*)d_in[0];
  const float* cov  = (const float*)d_in[1];
  const float* gam  = (const float*)d_in[2];
  const float* alp  = (const float*)d_in[3];
  float* out = (float*)d_out;
  hipLaunchKernelGGL(markowitz_kernel, dim3(NS), dim3(512), 0, stream,
                     rets, cov, gam, alp, out);
}

// Round 23
// 410.268 us; speedup vs baseline: 6.0612x; 1.5456x over previous
//
#include <hip/hip_runtime.h>

#define NS 512
#define NA 256
#define PGD_ITERS 300
#define POWER_ITERS 12

typedef _Float16 f16;
typedef __attribute__((ext_vector_type(2))) _Float16 f16x2;
typedef __attribute__((ext_vector_type(4))) _Float16 f16x4;
typedef __attribute__((ext_vector_type(8))) _Float16 f16x8;
typedef __attribute__((ext_vector_type(4))) float f32x4;

// LDS layout (bytes). STG/CH live only during the syrk; YY0/YY1 double-
// buffer the y-exchange. DTMP (512 f32 diag partials) overlays YY0+YY1.
#define CSTR 260            // f32 staging row stride (elems)
#define TSTR 24             // f16 C^T tile row stride (elems) = 48 B
#define OFF_CH  16640       // STG: 16*260*4
#define OFF_YY0 28928       // CH:  256*24*2
#define OFF_YY1 29952
#define LDS_BYTES 30976

// ---- cross-lane primitives (VALU DPP; minimal DS-pipe traffic) ----
// SAFETY: all call sites have FULL exec; branches only on wave-uniform
// scalars (readlane/readfirstlane results or wave-id comparisons).
template<int CTRL>
__device__ __forceinline__ float dpp_add(float x) {
  const int r = __builtin_amdgcn_update_dpp(0, __float_as_int(x), CTRL, 0xF, 0xF, true);
  return x + __int_as_float(r);
}
template<int CTRL>
__device__ __forceinline__ float dpp_max(float x) {
  const int r = __builtin_amdgcn_update_dpp(0, __float_as_int(x), CTRL, 0xF, 0xF, true);
  return fmaxf(x, __int_as_float(r));
}
__device__ __forceinline__ float red16(float x) {
  x = dpp_add<0x121>(x);  // row_ror:1
  x = dpp_add<0x122>(x);  // row_ror:2
  x = dpp_add<0x124>(x);  // row_ror:4
  x = dpp_add<0x128>(x);  // row_ror:8
  return x;
}
__device__ __forceinline__ float redwave_add(float x) {
  x = red16(x);
  {
    const int r = __builtin_amdgcn_update_dpp(0, __float_as_int(x), 0x142, 0xA, 0xF, true);
    x += __int_as_float(r);
  }
  {
    const int r = __builtin_amdgcn_update_dpp(0, __float_as_int(x), 0x143, 0xC, 0xF, true);
    x += __int_as_float(r);
  }
  return __int_as_float(__builtin_amdgcn_readlane(__float_as_int(x), 63));
}
__device__ __forceinline__ float redwave_max(float x) {
  x = dpp_max<0x121>(x);
  x = dpp_max<0x122>(x);
  x = dpp_max<0x124>(x);
  x = dpp_max<0x128>(x);
  {
    const int r = __builtin_amdgcn_update_dpp(__float_as_int(x), __float_as_int(x), 0x142, 0xA, 0xF, false);
    x = fmaxf(x, __int_as_float(r));
  }
  {
    const int r = __builtin_amdgcn_update_dpp(__float_as_int(x), __float_as_int(x), 0x143, 0xC, 0xF, false);
    x = fmaxf(x, __int_as_float(r));
  }
  return __int_as_float(__builtin_amdgcn_readlane(__float_as_int(x), 63));
}
__device__ __forceinline__ float rfl(float x) {
  return __int_as_float(__builtin_amdgcn_readfirstlane(__float_as_int(x)));
}
__device__ __forceinline__ float clamp01(float x) {
  return __builtin_amdgcn_fmed3f(x, 0.f, 1.f);
}
__device__ __forceinline__ f16x2 pk2(float a, float b) {
  return __builtin_bit_cast(f16x2, __builtin_amdgcn_cvt_pkrtz(a, b));
}
__device__ __forceinline__ float dot2f(f16x2 a, f16x2 b, float c) {
  return __builtin_amdgcn_fdot2(a, b, c, false);   // v_dot2_f32_f16
}
// select 1-of-4 packed f16x2 by 2-bit index (3 cndmask)
__device__ __forceinline__ f16x2 selg2(f16x2 a0, f16x2 a1, f16x2 a2, f16x2 a3, int g) {
  const int i0 = __builtin_bit_cast(int, a0);
  const int i1 = __builtin_bit_cast(int, a1);
  const int i2 = __builtin_bit_cast(int, a2);
  const int i3 = __builtin_bit_cast(int, a3);
  const int ab = (g & 1) ? i1 : i0;
  const int cd = (g & 1) ? i3 : i2;
  return __builtin_bit_cast(f16x2, (g & 2) ? cd : ab);
}

__global__ __launch_bounds__(512, 4) void markowitz_kernel(
    const float* __restrict__ rets, const float* __restrict__ cov,
    const float* __restrict__ gam,  const float* __restrict__ alp,
    float* __restrict__ out)
{
  __shared__ char smem[LDS_BYTES] __attribute__((aligned(16)));
  float* STG  = (float*)smem;
  f16*   CH   = (f16*)(smem + OFF_CH);
  float* DTMP = (float*)(smem + OFF_YY0);   // 512 f32 overlay (YY0+YY1)

  const int t    = threadIdx.x;
  const int lane = t & 63;
  const int w8   = t >> 6;          // wave 0..7
  const int lm   = lane & 15;       // column-within-tile owner index
  const int hq   = lane >> 4;       // row-subgroup index

  const int b = blockIdx.x;
  const float g  = gam[b];
  const float aa = fabsf(alp[b]);
  const float* __restrict__ C = cov + (size_t)b * (NA * NA);

  const bool mk = ((lm >> 2) == hq);
  const int  cw = lm & 3;

  // ===== Phase 1: Q = (gC)^T(gC), f16-packed registers + exact f32 diag =====
  // ah[ii][j2][c] packs Q[16*(w8+8ii)+4hq+c][16*(2j2)+lm | 16*(2j2+1)+lm]
  f16x2 ah[2][8][4];
  float dacc = 0.f;

  #pragma unroll
  for (int pass = 0; pass < 2; ++pass) {
    f32x4 acc1[16];
    #pragma unroll
    for (int j = 0; j < 16; ++j) acc1[j] = f32x4{0.f, 0.f, 0.f, 0.f};

    #pragma unroll 1
    for (int kb = 0; kb < 16; ++kb) {
      { // stage 16x256 f32 (gamma-folded), coalesced
        const int kk = t >> 5;
        const int ib = (t & 31) << 3;
        const float* src = C + (size_t)(kb * 16 + kk) * NA + ib;
        float* dst = STG + kk * CSTR + ib;
        float4 c0 = *(const float4*)(src);
        float4 c1 = *(const float4*)(src + 4);
        *(float4*)(dst)     = make_float4(c0.x * g, c0.y * g, c0.z * g, c0.w * g);
        *(float4*)(dst + 4) = make_float4(c1.x * g, c1.y * g, c1.z * g, c1.w * g);
      }
      __syncthreads();
      { // transpose to f16 C^T tile; pass 0 also accumulates exact diag
        const int ti = t & 255;
        const int th = t >> 8;       // k-half 0/1
        f16x8 vh;
        #pragma unroll
        for (int s2 = 0; s2 < 8; ++s2) {
          const float x = STG[(8 * th + s2) * CSTR + ti];
          if (pass == 0) dacc += x * x;
          vh[s2] = (f16)x;
        }
        *(f16x8*)(CH + ti * TSTR + 8 * th) = vh;
      }
      __syncthreads();
      const int I = w8 + 8 * pass;
      const f16x4 aH = *(const f16x4*)(CH + (16 * I + lm) * TSTR + 4 * hq);
      #pragma unroll
      for (int J = 0; J < 16; ++J) {
        const f16x4 bH = *(const f16x4*)(CH + (16 * J + lm) * TSTR + 4 * hq);
        acc1[J] = __builtin_amdgcn_mfma_f32_16x16x16f16(aH, bH, acc1[J], 0, 0, 0);
      }
    }
    // pack to f16 pairs (canonical); zero diag slot (handled exactly via dgv)
    const int dj = w8 + 8 * pass;
    #pragma unroll
    for (int j2 = 0; j2 < 8; ++j2) {
      #pragma unroll
      for (int c = 0; c < 4; ++c) {
        float a0 = acc1[2 * j2][c];
        float a1 = acc1[2 * j2 + 1][c];
        if (2 * j2     == dj && lm == 4 * hq + c) a0 = 0.f;
        if (2 * j2 + 1 == dj && lm == 4 * hq + c) a1 = 0.f;
        ah[pass][j2][c] = pk2(a0, a1);
      }
    }
  }

  // exact diag sums -> LDS overlay
  {
    const int ti = t & 255;
    const int th = t >> 8;
    DTMP[th * 256 + ti] = dacc;
  }
  __syncthreads();
  float dg0 = 0.f, dg1 = 0.f;
  if (mk) {
    const int c0 = 16 * w8 + lm, c1 = 16 * (w8 + 8) + lm;
    dg0 = DTMP[c0] + DTMP[256 + c0] + aa;
    dg1 = DTMP[c1] + DTMP[256 + c1] + aa;
  }
  f32x4 dgv0, dgv1;
  #pragma unroll
  for (int p = 0; p < 4; ++p) {
    dgv0[p] = (lm == 4 * hq + p) ? dg0 : 0.f;
    dgv1[p] = (lm == 4 * hq + p) ? dg1 : 0.f;
  }
  __syncthreads();   // DTMP dead

  float* const YY0 = (float*)(smem + OFF_YY0);
  float* const YY1 = (float*)(smem + OFF_YY1);

  // Row-relative z storage: zr[g][c] = z[16*(4*(hq^g)+c) + lm]. All static.
  float zr[4][4];
  #pragma unroll
  for (int gg = 0; gg < 4; ++gg)
    #pragma unroll
    for (int c = 0; c < 4; ++c) zr[gg][c] = 1.f;   // power b0 = ones

  // matvec: canonical zpk assembled from zr via selg2 (g = q^hq).
  auto matvec = [&](f32x4& y0, f32x4& y1) {
    f16x2 zrpk[4][2];
    #pragma unroll
    for (int gg = 0; gg < 4; ++gg) {
      zrpk[gg][0] = pk2(zr[gg][0], zr[gg][1]);
      zrpk[gg][1] = pk2(zr[gg][2], zr[gg][3]);
    }
    f16x2 zpk[8];
    #pragma unroll
    for (int j2 = 0; j2 < 8; ++j2) {
      const int q = j2 >> 1, pb = j2 & 1;
      zpk[j2] = selg2(zrpk[0][pb], zrpk[1][pb], zrpk[2][pb], zrpk[3][pb], q ^ hq);
    }
    // exact f32 diag z: zd0 = z[16*w8+lm], zd1 = z[16*(w8+8)+lm]
    float zd0 = 0.f, zd1 = 0.f;
    {
      const int g0 = (w8 >> 2) ^ hq;      // zd1 uses g0^2
      const int cc0 = w8 & 3;             // wave-uniform
      #pragma unroll
      for (int cc = 0; cc < 4; ++cc)
        if (cc0 == cc) {
          const float ab = (g0 & 1) ? zr[1][cc] : zr[0][cc];
          const float cd = (g0 & 1) ? zr[3][cc] : zr[2][cc];
          zd0 = (g0 & 2) ? cd : ab;
          zd1 = (g0 & 2) ? ab : cd;
        }
    }
    y0 = dgv0 * zd0;
    y1 = dgv1 * zd1;
    #pragma unroll
    for (int j2 = 0; j2 < 8; ++j2) {
      #pragma unroll
      for (int c = 0; c < 4; ++c) {
        y0[c] = dot2f(ah[0][j2][c], zpk[j2], y0[c]);
        y1[c] = dot2f(ah[1][j2][c], zpk[j2], y1[c]);
      }
    }
    #pragma unroll
    for (int c = 0; c < 4; ++c) { y0[c] = red16(y0[c]); y1[c] = red16(y1[c]); }
  };
  auto publish = [&](float* YYp, const f32x4& y0, const f32x4& y1) {
    if (mk) {
      const float ya = (cw == 0) ? y0[0] : (cw == 1) ? y0[1] : (cw == 2) ? y0[2] : y0[3];
      const float yb = (cw == 0) ? y1[0] : (cw == 1) ? y1[1] : (cw == 2) ? y1[2] : y1[3];
      YYp[16 * w8 + lm]       = ya;
      YYp[16 * (w8 + 8) + lm] = yb;
    }
  };

  // ===== Phase 2: power iteration; step from ||Qb|| with safety margin =====
  float step;
  {
    float lam = 0.f;
    #pragma unroll 1
    for (int pi = 0; pi < POWER_ITERS; ++pi) {
      f32x4 y0, y1; matvec(y0, y1);
      float* YYp = (pi & 1) ? YY1 : YY0;
      publish(YYp, y0, y1);
      __syncthreads();
      float nrm = 0.f;
      #pragma unroll
      for (int gg = 0; gg < 4; ++gg)
        #pragma unroll
        for (int c = 0; c < 4; ++c) {
          const float tv = YYp[(((hq ^ gg) * 4 + c) << 4) + lm];
          nrm += tv * tv;
          zr[gg][c] = tv;
        }
      nrm = rfl(red16(nrm));
      const float nn = sqrtf(nrm);
      lam = nn;                               // ||Q b_{k-1}|| (b normalized)
      const float rb = 1.f / (nn + 1e-12f);
      #pragma unroll
      for (int gg = 0; gg < 4; ++gg)
        #pragma unroll
        for (int c = 0; c < 4; ++c) zr[gg][c] *= rb;
    }
    step = 1.f / (2.f * (1.08f * lam) + 1e-6f);
  }

  // ===== Phase 3: FISTA + gradient-based adaptive restart (O'Donoghue-
  // Candes) — quarter-split state, 1 barrier/iter, tolerance early exit.
  // Restart (tt=1 when <z - w+, w+ - w> > 0) never changes the fixed point;
  // it only accelerates convergence on strongly convex problems. =====
  float wo4[4], rr4[4];
  #pragma unroll
  for (int c = 0; c < 4; ++c) {
    rr4[c] = rets[b * NA + ((4 * hq + c) << 4) + lm];
    wo4[c] = 1.f / 256.f;
  }
  #pragma unroll
  for (int gg = 0; gg < 4; ++gg)
    #pragma unroll
    for (int c = 0; c < 4; ++c) zr[gg][c] = 1.f / 256.f;
  float tt = 1.f;
  float tauw = 1e30f;
  float kest = 32.f;

  #pragma unroll 1
  for (int it = 0; it < PGD_ITERS; ++it) {
    f32x4 y0, y1; matvec(y0, y1);
    float* YYp = (it & 1) ? YY0 : YY1;
    publish(YYp, y0, y1);
    __syncthreads();

    // own columns only: v = z - step*(2y - r)
    float vq[4];
    #pragma unroll
    for (int c = 0; c < 4; ++c) {
      const float yv = YYp[((4 * hq + c) << 4) + lm];
      vq[c] = zr[0][c] - step * (2.f * yv - rr4[c]);
    }

    // Projection (verified R10/R12/R14/R17): uniform-scalar secant w/ early exit
    float lo = -1e30f, hi = 1e30f;
    float tau = tauw;
    float fprev = 0.f, tprev = 0.f;
    bool have = false;
    #pragma unroll 1
    for (int nit = 0; nit < 16; ++nit) {
      float sp = clamp01(vq[0] - tau) + clamp01(vq[1] - tau)
               + clamp01(vq[2] - tau) + clamp01(vq[3] - tau);
      const float s = redwave_add(sp);
      if (nit == 0) {
        const float pm = redwave_max(fmaxf(fmaxf(vq[0], vq[1]), fmaxf(vq[2], vq[3])));
        lo = pm - 1.0f; hi = pm;              // root always in [max-1, max]
        if (!(tau > lo && tau < hi)) { tau = 0.5f * (lo + hi); continue; }
      }
      const float f = s - 1.f;
      if (fabsf(f) <= 1e-5f) break;
      if (f > 0.f) lo = tau; else hi = tau;
      if (hi - lo < 1e-7f) break;
      float kc = have ? ((f - fprev) / (tprev - tau)) : kest;
      if (!(kc > 0.5f)) kc = kest;
      const float tn = tau + f / kc;
      fprev = f; tprev = tau; have = true;
      kest = fmaxf(kc, 1.f);
      const float tc = (tn > lo && tn < hi) ? tn : 0.5f * (lo + hi);
      if (tc == tau) break;
      tau = tc;
    }
    tauw = tau;

    // w+ = clamp(v - tau); accumulate exit metric and restart test
    float wn4[4];
    float dsum = 0.f, rs = 0.f;
    #pragma unroll
    for (int c = 0; c < 4; ++c) {
      wn4[c] = clamp01(vq[c] - tau);
      dsum += fabsf(wn4[c] - wo4[c]);
      rs   += (zr[0][c] - wn4[c]) * (wn4[c] - wo4[c]);
    }
    const float dtot = redwave_add(dsum);
    const float rtot = redwave_add(rs);

    // Early exit: dtot <= 1e-5 -> at fixed point to f32 granularity
    // (R21/R22-verified; drift << 2e-2 threshold).
    const bool fin = (it == PGD_ITERS - 1) || (dtot <= 1e-5f);
    if (fin) {
      if (w8 == 0) {
        #pragma unroll
        for (int c = 0; c < 4; ++c)
          out[(size_t)b * NA + ((4 * hq + c) << 4) + lm] = wn4[c];
      }
      break;
    }

    // gradient restart: momentum opposes the step -> reset tt (coef -> 0)
    if (rtot > 0.f) tt = 1.f;
    const float tnew = 0.5f * (1.f + sqrtf(1.f + 4.f * tt * tt));
    const float coef = (tt - 1.f) / tnew;
    float zn[4];
    #pragma unroll
    for (int c = 0; c < 4; ++c) {
      zn[c] = wn4[c] + coef * (wn4[c] - wo4[c]);
      wo4[c] = wn4[c];
    }
    tt = tnew;

    // f32-exact 3-way exchange refills the row-relative replicas
    #pragma unroll
    for (int c = 0; c < 4; ++c) {
      zr[0][c] = zn[c];
      zr[1][c] = __shfl_xor(zn[c], 16);
      zr[2][c] = __shfl_xor(zn[c], 32);
      zr[3][c] = __shfl_xor(zn[c], 48);
    }
  }
}

extern "C" void kernel_launch(void* const* d_in, const int* in_sizes, int n_in,
                              void* d_out, int out_size, void* d_ws, size_t ws_size,
                              hipStream_t stream) {
  (void)in_sizes; (void)n_in; (void)out_size; (void)d_ws; (void)ws_size;
  const float* rets = (const float*)d_in[0];
  const float* cov  = (const float*)d_in[1];
  const float* gam  = (const float*)d_in[2];
  const float* alp  = (const float*)d_in[3];
  float* out = (float*)d_out;
  hipLaunchKernelGGL(markowitz_kernel, dim3(NS), dim3(512), 0, stream,
                     rets, cov, gam, alp, out);
}

// Round 24
// 295.872 us; speedup vs baseline: 8.4047x; 1.3866x over previous
//
#include <hip/hip_runtime.h>

#define NS 512
#define NA 256
#define PGD_ITERS 300
#define POWER_ITERS 10

typedef _Float16 f16;
typedef __attribute__((ext_vector_type(2))) _Float16 f16x2;
typedef __attribute__((ext_vector_type(4))) _Float16 f16x4;
typedef __attribute__((ext_vector_type(8))) _Float16 f16x8;
typedef __attribute__((ext_vector_type(4))) float f32x4;

// LDS layout (bytes). STG (32x260 f32) / CH (256x40 f16) live only during
// the syrk; YY0/YY1 double-buffer the y-exchange. DTMP overlays YY0+YY1.
#define CSTR 260            // f32 staging row stride (elems)
#define TSTR 40             // f16 C^T tile row stride (elems) = 80 B (32k+pad)
#define OFF_CH  33280       // STG: 32*260*4
#define OFF_YY0 53760       // CH:  256*40*2 = 20480
#define OFF_YY1 54784
#define LDS_BYTES 55808     // 2 blocks/CU by LDS (111.6 KB < 160 KB)

// ---- cross-lane primitives (VALU DPP; minimal DS-pipe traffic) ----
// SAFETY: all call sites have FULL exec; branches only on wave-uniform
// scalars (readlane/readfirstlane results or wave-id comparisons).
template<int CTRL>
__device__ __forceinline__ float dpp_add(float x) {
  const int r = __builtin_amdgcn_update_dpp(0, __float_as_int(x), CTRL, 0xF, 0xF, true);
  return x + __int_as_float(r);
}
template<int CTRL>
__device__ __forceinline__ float dpp_max(float x) {
  const int r = __builtin_amdgcn_update_dpp(0, __float_as_int(x), CTRL, 0xF, 0xF, true);
  return fmaxf(x, __int_as_float(r));
}
__device__ __forceinline__ float red16(float x) {
  x = dpp_add<0x121>(x);  // row_ror:1
  x = dpp_add<0x122>(x);  // row_ror:2
  x = dpp_add<0x124>(x);  // row_ror:4
  x = dpp_add<0x128>(x);  // row_ror:8
  return x;
}
__device__ __forceinline__ float redwave_add(float x) {
  x = red16(x);
  {
    const int r = __builtin_amdgcn_update_dpp(0, __float_as_int(x), 0x142, 0xA, 0xF, true);
    x += __int_as_float(r);
  }
  {
    const int r = __builtin_amdgcn_update_dpp(0, __float_as_int(x), 0x143, 0xC, 0xF, true);
    x += __int_as_float(r);
  }
  return __int_as_float(__builtin_amdgcn_readlane(__float_as_int(x), 63));
}
__device__ __forceinline__ float redwave_max(float x) {
  x = dpp_max<0x121>(x);
  x = dpp_max<0x122>(x);
  x = dpp_max<0x124>(x);
  x = dpp_max<0x128>(x);
  {
    const int r = __builtin_amdgcn_update_dpp(__float_as_int(x), __float_as_int(x), 0x142, 0xA, 0xF, false);
    x = fmaxf(x, __int_as_float(r));
  }
  {
    const int r = __builtin_amdgcn_update_dpp(__float_as_int(x), __float_as_int(x), 0x143, 0xC, 0xF, false);
    x = fmaxf(x, __int_as_float(r));
  }
  return __int_as_float(__builtin_amdgcn_readlane(__float_as_int(x), 63));
}
__device__ __forceinline__ float rfl(float x) {
  return __int_as_float(__builtin_amdgcn_readfirstlane(__float_as_int(x)));
}
__device__ __forceinline__ float clamp01(float x) {
  return __builtin_amdgcn_fmed3f(x, 0.f, 1.f);
}
__device__ __forceinline__ f16x2 pk2(float a, float b) {
  return __builtin_bit_cast(f16x2, __builtin_amdgcn_cvt_pkrtz(a, b));
}
__device__ __forceinline__ float dot2f(f16x2 a, f16x2 b, float c) {
  return __builtin_amdgcn_fdot2(a, b, c, false);   // v_dot2_f32_f16
}
// select 1-of-4 packed f16x2 by 2-bit index (3 cndmask)
__device__ __forceinline__ f16x2 selg2(f16x2 a0, f16x2 a1, f16x2 a2, f16x2 a3, int g) {
  const int i0 = __builtin_bit_cast(int, a0);
  const int i1 = __builtin_bit_cast(int, a1);
  const int i2 = __builtin_bit_cast(int, a2);
  const int i3 = __builtin_bit_cast(int, a3);
  const int ab = (g & 1) ? i1 : i0;
  const int cd = (g & 1) ? i3 : i2;
  return __builtin_bit_cast(f16x2, (g & 2) ? cd : ab);
}

__global__ __launch_bounds__(512, 4) void markowitz_kernel(
    const float* __restrict__ rets, const float* __restrict__ cov,
    const float* __restrict__ gam,  const float* __restrict__ alp,
    float* __restrict__ out)
{
  __shared__ char smem[LDS_BYTES] __attribute__((aligned(16)));
  float* STG  = (float*)smem;
  f16*   CH   = (f16*)(smem + OFF_CH);
  float* DTMP = (float*)(smem + OFF_YY0);   // 512 f32 overlay (YY0+YY1)

  const int t    = threadIdx.x;
  const int lane = t & 63;
  const int w8   = t >> 6;          // wave 0..7
  const int lm   = lane & 15;       // column-within-tile owner index
  const int hq   = lane >> 4;       // row-subgroup index

  const int b = blockIdx.x;
  const float g  = gam[b];
  const float aa = fabsf(alp[b]);
  const float* __restrict__ C = cov + (size_t)b * (NA * NA);

  const bool mk = ((lm >> 2) == hq);
  const int  cw = lm & 3;

  // ===== Phase 1: Q = (gC)^T(gC), f16-packed registers + exact f32 diag.
  // 32 k-rows staged per round (8 rounds/pass, half the barriers of R23).
  // ah[ii][j2][c] packs Q[16*(w8+8ii)+4hq+c][16*(2j2)+lm | 16*(2j2+1)+lm]
  f16x2 ah[2][8][4];
  float dacc = 0.f;

  #pragma unroll
  for (int pass = 0; pass < 2; ++pass) {
    f32x4 acc1[16];
    #pragma unroll
    for (int j = 0; j < 16; ++j) acc1[j] = f32x4{0.f, 0.f, 0.f, 0.f};

    #pragma unroll 1
    for (int kb = 0; kb < 8; ++kb) {
      { // stage 32x256 f32 (gamma-folded), coalesced: 4 float4/thread
        const int kk = t >> 4;          // 0..31
        const int ib = (t & 15) << 4;   // 0,16,...,240
        const float* src = C + (size_t)(kb * 32 + kk) * NA + ib;
        float* dst = STG + kk * CSTR + ib;
        #pragma unroll
        for (int j4 = 0; j4 < 4; ++j4) {
          float4 cv = *(const float4*)(src + 4 * j4);
          *(float4*)(dst + 4 * j4) =
              make_float4(cv.x * g, cv.y * g, cv.z * g, cv.w * g);
        }
      }
      __syncthreads();
      { // transpose to f16 C^T tile (k=0..31); pass 0 also exact diag
        const int ti = t & 255;
        const int th = t >> 8;          // k-half 0/1 (16 k each)
        f16x8 v0, v1;
        #pragma unroll
        for (int s2 = 0; s2 < 8; ++s2) {
          const float x0 = STG[(16 * th + s2) * CSTR + ti];
          const float x1 = STG[(16 * th + 8 + s2) * CSTR + ti];
          if (pass == 0) dacc += x0 * x0 + x1 * x1;
          v0[s2] = (f16)x0;
          v1[s2] = (f16)x1;
        }
        *(f16x8*)(CH + ti * TSTR + 16 * th)     = v0;
        *(f16x8*)(CH + ti * TSTR + 16 * th + 8) = v1;
      }
      __syncthreads();
      const int I = w8 + 8 * pass;
      const f16x4 aH0 = *(const f16x4*)(CH + (16 * I + lm) * TSTR + 4 * hq);
      const f16x4 aH1 = *(const f16x4*)(CH + (16 * I + lm) * TSTR + 16 + 4 * hq);
      #pragma unroll
      for (int J = 0; J < 16; ++J) {
        const f16x4 bH0 = *(const f16x4*)(CH + (16 * J + lm) * TSTR + 4 * hq);
        const f16x4 bH1 = *(const f16x4*)(CH + (16 * J + lm) * TSTR + 16 + 4 * hq);
        acc1[J] = __builtin_amdgcn_mfma_f32_16x16x16f16(aH0, bH0, acc1[J], 0, 0, 0);
        acc1[J] = __builtin_amdgcn_mfma_f32_16x16x16f16(aH1, bH1, acc1[J], 0, 0, 0);
      }
    }
    // pack to f16 pairs (canonical); zero diag slot (handled exactly via dgv)
    const int dj = w8 + 8 * pass;
    #pragma unroll
    for (int j2 = 0; j2 < 8; ++j2) {
      #pragma unroll
      for (int c = 0; c < 4; ++c) {
        float a0 = acc1[2 * j2][c];
        float a1 = acc1[2 * j2 + 1][c];
        if (2 * j2     == dj && lm == 4 * hq + c) a0 = 0.f;
        if (2 * j2 + 1 == dj && lm == 4 * hq + c) a1 = 0.f;
        ah[pass][j2][c] = pk2(a0, a1);
      }
    }
  }

  // exact diag sums -> LDS overlay
  {
    const int ti = t & 255;
    const int th = t >> 8;
    DTMP[th * 256 + ti] = dacc;
  }
  __syncthreads();
  float dg0 = 0.f, dg1 = 0.f;
  if (mk) {
    const int c0 = 16 * w8 + lm, c1 = 16 * (w8 + 8) + lm;
    dg0 = DTMP[c0] + DTMP[256 + c0] + aa;
    dg1 = DTMP[c1] + DTMP[256 + c1] + aa;
  }
  f32x4 dgv0, dgv1;
  #pragma unroll
  for (int p = 0; p < 4; ++p) {
    dgv0[p] = (lm == 4 * hq + p) ? dg0 : 0.f;
    dgv1[p] = (lm == 4 * hq + p) ? dg1 : 0.f;
  }
  __syncthreads();   // DTMP dead

  float* const YY0 = (float*)(smem + OFF_YY0);
  float* const YY1 = (float*)(smem + OFF_YY1);

  // Row-relative z storage: zr[g][c] = z[16*(4*(hq^g)+c) + lm]. All static.
  float zr[4][4];
  #pragma unroll
  for (int gg = 0; gg < 4; ++gg)
    #pragma unroll
    for (int c = 0; c < 4; ++c) zr[gg][c] = 1.f;   // power b0 = ones

  // matvec: canonical zpk assembled from zr via selg2 (g = q^hq).
  auto matvec = [&](f32x4& y0, f32x4& y1) {
    f16x2 zrpk[4][2];
    #pragma unroll
    for (int gg = 0; gg < 4; ++gg) {
      zrpk[gg][0] = pk2(zr[gg][0], zr[gg][1]);
      zrpk[gg][1] = pk2(zr[gg][2], zr[gg][3]);
    }
    f16x2 zpk[8];
    #pragma unroll
    for (int j2 = 0; j2 < 8; ++j2) {
      const int q = j2 >> 1, pb = j2 & 1;
      zpk[j2] = selg2(zrpk[0][pb], zrpk[1][pb], zrpk[2][pb], zrpk[3][pb], q ^ hq);
    }
    // exact f32 diag z: zd0 = z[16*w8+lm], zd1 = z[16*(w8+8)+lm]
    float zd0 = 0.f, zd1 = 0.f;
    {
      const int g0 = (w8 >> 2) ^ hq;      // zd1 uses g0^2
      const int cc0 = w8 & 3;             // wave-uniform
      #pragma unroll
      for (int cc = 0; cc < 4; ++cc)
        if (cc0 == cc) {
          const float ab = (g0 & 1) ? zr[1][cc] : zr[0][cc];
          const float cd = (g0 & 1) ? zr[3][cc] : zr[2][cc];
          zd0 = (g0 & 2) ? cd : ab;
          zd1 = (g0 & 2) ? ab : cd;
        }
    }
    y0 = dgv0 * zd0;
    y1 = dgv1 * zd1;
    #pragma unroll
    for (int j2 = 0; j2 < 8; ++j2) {
      #pragma unroll
      for (int c = 0; c < 4; ++c) {
        y0[c] = dot2f(ah[0][j2][c], zpk[j2], y0[c]);
        y1[c] = dot2f(ah[1][j2][c], zpk[j2], y1[c]);
      }
    }
    #pragma unroll
    for (int c = 0; c < 4; ++c) { y0[c] = red16(y0[c]); y1[c] = red16(y1[c]); }
  };
  auto publish = [&](float* YYp, const f32x4& y0, const f32x4& y1) {
    if (mk) {
      const float ya = (cw == 0) ? y0[0] : (cw == 1) ? y0[1] : (cw == 2) ? y0[2] : y0[3];
      const float yb = (cw == 0) ? y1[0] : (cw == 1) ? y1[1] : (cw == 2) ? y1[2] : y1[3];
      YYp[16 * w8 + lm]       = ya;
      YYp[16 * (w8 + 8) + lm] = yb;
    }
  };

  // ===== Phase 2: power iteration; step from ||Qb|| with safety margin =====
  float step;
  {
    float lam = 0.f;
    #pragma unroll 1
    for (int pi = 0; pi < POWER_ITERS; ++pi) {
      f32x4 y0, y1; matvec(y0, y1);
      float* YYp = (pi & 1) ? YY1 : YY0;
      publish(YYp, y0, y1);
      __syncthreads();
      float nrm = 0.f;
      #pragma unroll
      for (int gg = 0; gg < 4; ++gg)
        #pragma unroll
        for (int c = 0; c < 4; ++c) {
          const float tv = YYp[(((hq ^ gg) * 4 + c) << 4) + lm];
          nrm += tv * tv;
          zr[gg][c] = tv;
        }
      nrm = rfl(red16(nrm));
      const float nn = sqrtf(nrm);
      lam = nn;                               // ||Q b_{k-1}|| (b normalized)
      const float rb = 1.f / (nn + 1e-12f);
      #pragma unroll
      for (int gg = 0; gg < 4; ++gg)
        #pragma unroll
        for (int c = 0; c < 4; ++c) zr[gg][c] *= rb;
    }
    step = 1.f / (2.f * (1.10f * lam) + 1e-6f);
  }

  // ===== Phase 3: FISTA + gradient-based adaptive restart (O'Donoghue-
  // Candes) — quarter-split state, 1 barrier/iter, tolerance early exit. =====
  float wo4[4], rr4[4];
  #pragma unroll
  for (int c = 0; c < 4; ++c) {
    rr4[c] = rets[b * NA + ((4 * hq + c) << 4) + lm];
    wo4[c] = 1.f / 256.f;
  }
  #pragma unroll
  for (int gg = 0; gg < 4; ++gg)
    #pragma unroll
    for (int c = 0; c < 4; ++c) zr[gg][c] = 1.f / 256.f;
  float tt = 1.f;
  float tauw = 1e30f;
  float kest = 32.f;

  #pragma unroll 1
  for (int it = 0; it < PGD_ITERS; ++it) {
    f32x4 y0, y1; matvec(y0, y1);
    float* YYp = (it & 1) ? YY0 : YY1;
    publish(YYp, y0, y1);
    __syncthreads();

    // own columns only: v = z - step*(2y - r)
    float vq[4];
    #pragma unroll
    for (int c = 0; c < 4; ++c) {
      const float yv = YYp[((4 * hq + c) << 4) + lm];
      vq[c] = zr[0][c] - step * (2.f * yv - rr4[c]);
    }

    // Projection (verified R10/R12/R14/R17): uniform-scalar secant w/ early exit
    float lo = -1e30f, hi = 1e30f;
    float tau = tauw;
    float fprev = 0.f, tprev = 0.f;
    bool have = false;
    #pragma unroll 1
    for (int nit = 0; nit < 16; ++nit) {
      float sp = clamp01(vq[0] - tau) + clamp01(vq[1] - tau)
               + clamp01(vq[2] - tau) + clamp01(vq[3] - tau);
      const float s = redwave_add(sp);
      if (nit == 0) {
        const float pm = redwave_max(fmaxf(fmaxf(vq[0], vq[1]), fmaxf(vq[2], vq[3])));
        lo = pm - 1.0f; hi = pm;              // root always in [max-1, max]
        if (!(tau > lo && tau < hi)) { tau = 0.5f * (lo + hi); continue; }
      }
      const float f = s - 1.f;
      if (fabsf(f) <= 1e-5f) break;
      if (f > 0.f) lo = tau; else hi = tau;
      if (hi - lo < 1e-7f) break;
      float kc = have ? ((f - fprev) / (tprev - tau)) : kest;
      if (!(kc > 0.5f)) kc = kest;
      const float tn = tau + f / kc;
      fprev = f; tprev = tau; have = true;
      kest = fmaxf(kc, 1.f);
      const float tc = (tn > lo && tn < hi) ? tn : 0.5f * (lo + hi);
      if (tc == tau) break;
      tau = tc;
    }
    tauw = tau;

    // w+ = clamp(v - tau); accumulate exit metric and restart test
    float wn4[4];
    float dsum = 0.f, rs = 0.f;
    #pragma unroll
    for (int c = 0; c < 4; ++c) {
      wn4[c] = clamp01(vq[c] - tau);
      dsum += fabsf(wn4[c] - wo4[c]);
      rs   += (zr[0][c] - wn4[c]) * (wn4[c] - wo4[c]);
    }
    const float dtot = redwave_add(dsum);
    const float rtot = redwave_add(rs);

    // Early exit: dtot <= 1e-4. Linear tail (restart, rho~0.85-0.9) bounds
    // post-exit drift by dtot*rho/(1-rho) ~ 6e-4 — total error ~2e-3,
    // 10x under the 2e-2 threshold (R21-23 measured 9.8e-4 at 1e-5).
    const bool fin = (it == PGD_ITERS - 1) || (dtot <= 1e-4f);
    if (fin) {
      if (w8 == 0) {
        #pragma unroll
        for (int c = 0; c < 4; ++c)
          out[(size_t)b * NA + ((4 * hq + c) << 4) + lm] = wn4[c];
      }
      break;
    }

    // gradient restart: momentum opposes the step -> reset tt (coef -> 0)
    if (rtot > 0.f) tt = 1.f;
    const float tnew = 0.5f * (1.f + sqrtf(1.f + 4.f * tt * tt));
    const float coef = (tt - 1.f) / tnew;
    float zn[4];
    #pragma unroll
    for (int c = 0; c < 4; ++c) {
      zn[c] = wn4[c] + coef * (wn4[c] - wo4[c]);
      wo4[c] = wn4[c];
    }
    tt = tnew;

    // f32-exact 3-way exchange refills the row-relative replicas
    #pragma unroll
    for (int c = 0; c < 4; ++c) {
      zr[0][c] = zn[c];
      zr[1][c] = __shfl_xor(zn[c], 16);
      zr[2][c] = __shfl_xor(zn[c], 32);
      zr[3][c] = __shfl_xor(zn[c], 48);
    }
  }
}

extern "C" void kernel_launch(void* const* d_in, const int* in_sizes, int n_in,
                              void* d_out, int out_size, void* d_ws, size_t ws_size,
                              hipStream_t stream) {
  (void)in_sizes; (void)n_in; (void)out_size; (void)d_ws; (void)ws_size;
  const float* rets = (const float*)d_in[0];
  const float* cov  = (const float*)d_in[1];
  const float* gam  = (const float*)d_in[2];
  const float* alp  = (const float*)d_in[3];
  float* out = (float*)d_out;
  hipLaunchKernelGGL(markowitz_kernel, dim3(NS), dim3(512), 0, stream,
                     rets, cov, gam, alp, out);
}

// Round 25
// 287.340 us; speedup vs baseline: 8.6542x; 1.0297x over previous
//
#include <hip/hip_runtime.h>

#define NS 512
#define NA 256
#define PGD_ITERS 300
#define POWER_ITERS 8

typedef _Float16 f16;
typedef __attribute__((ext_vector_type(2))) _Float16 f16x2;
typedef __attribute__((ext_vector_type(4))) _Float16 f16x4;
typedef __attribute__((ext_vector_type(8))) _Float16 f16x8;
typedef __attribute__((ext_vector_type(4))) float f32x4;

// LDS layout (bytes). STG (32x260 f32) / CH (256x40 f16) live only during
// the syrk; YY0/YY1 double-buffer the y-exchange. DTMP overlays YY0+YY1.
#define CSTR 260            // f32 staging row stride (elems)
#define TSTR 40             // f16 C^T tile row stride (elems) = 80 B (32k+pad)
#define OFF_CH  33280       // STG: 32*260*4
#define OFF_YY0 53760       // CH:  256*40*2 = 20480
#define OFF_YY1 54784
#define LDS_BYTES 55808     // 2 blocks/CU by LDS (111.6 KB < 160 KB)

// ---- cross-lane primitives (VALU DPP; minimal DS-pipe traffic) ----
// SAFETY: all call sites have FULL exec; branches only on wave-uniform
// scalars (readlane/readfirstlane results or wave-id comparisons).
template<int CTRL>
__device__ __forceinline__ float dpp_add(float x) {
  const int r = __builtin_amdgcn_update_dpp(0, __float_as_int(x), CTRL, 0xF, 0xF, true);
  return x + __int_as_float(r);
}
template<int CTRL>
__device__ __forceinline__ float dpp_max(float x) {
  const int r = __builtin_amdgcn_update_dpp(0, __float_as_int(x), CTRL, 0xF, 0xF, true);
  return fmaxf(x, __int_as_float(r));
}
__device__ __forceinline__ float red16(float x) {
  x = dpp_add<0x121>(x);  // row_ror:1
  x = dpp_add<0x122>(x);  // row_ror:2
  x = dpp_add<0x124>(x);  // row_ror:4
  x = dpp_add<0x128>(x);  // row_ror:8
  return x;
}
__device__ __forceinline__ float redwave_add(float x) {
  x = red16(x);
  {
    const int r = __builtin_amdgcn_update_dpp(0, __float_as_int(x), 0x142, 0xA, 0xF, true);
    x += __int_as_float(r);
  }
  {
    const int r = __builtin_amdgcn_update_dpp(0, __float_as_int(x), 0x143, 0xC, 0xF, true);
    x += __int_as_float(r);
  }
  return __int_as_float(__builtin_amdgcn_readlane(__float_as_int(x), 63));
}
__device__ __forceinline__ float redwave_max(float x) {
  x = dpp_max<0x121>(x);
  x = dpp_max<0x122>(x);
  x = dpp_max<0x124>(x);
  x = dpp_max<0x128>(x);
  {
    const int r = __builtin_amdgcn_update_dpp(__float_as_int(x), __float_as_int(x), 0x142, 0xA, 0xF, false);
    x = fmaxf(x, __int_as_float(r));
  }
  {
    const int r = __builtin_amdgcn_update_dpp(__float_as_int(x), __float_as_int(x), 0x143, 0xC, 0xF, false);
    x = fmaxf(x, __int_as_float(r));
  }
  return __int_as_float(__builtin_amdgcn_readlane(__float_as_int(x), 63));
}
__device__ __forceinline__ float rfl(float x) {
  return __int_as_float(__builtin_amdgcn_readfirstlane(__float_as_int(x)));
}
__device__ __forceinline__ float clamp01(float x) {
  return __builtin_amdgcn_fmed3f(x, 0.f, 1.f);
}
__device__ __forceinline__ f16x2 pk2(float a, float b) {
  return __builtin_bit_cast(f16x2, __builtin_amdgcn_cvt_pkrtz(a, b));
}
__device__ __forceinline__ float dot2f(f16x2 a, f16x2 b, float c) {
  return __builtin_amdgcn_fdot2(a, b, c, false);   // v_dot2_f32_f16
}
// select 1-of-4 packed f16x2 by 2-bit index (3 cndmask)
__device__ __forceinline__ f16x2 selg2(f16x2 a0, f16x2 a1, f16x2 a2, f16x2 a3, int g) {
  const int i0 = __builtin_bit_cast(int, a0);
  const int i1 = __builtin_bit_cast(int, a1);
  const int i2 = __builtin_bit_cast(int, a2);
  const int i3 = __builtin_bit_cast(int, a3);
  const int ab = (g & 1) ? i1 : i0;
  const int cd = (g & 1) ? i3 : i2;
  return __builtin_bit_cast(f16x2, (g & 2) ? cd : ab);
}

__global__ __launch_bounds__(512, 4) void markowitz_kernel(
    const float* __restrict__ rets, const float* __restrict__ cov,
    const float* __restrict__ gam,  const float* __restrict__ alp,
    float* __restrict__ out)
{
  __shared__ char smem[LDS_BYTES] __attribute__((aligned(16)));
  float* STG  = (float*)smem;
  f16*   CH   = (f16*)(smem + OFF_CH);
  float* DTMP = (float*)(smem + OFF_YY0);   // 512 f32 overlay (YY0+YY1)

  const int t    = threadIdx.x;
  const int lane = t & 63;
  const int w8   = t >> 6;          // wave 0..7
  const int lm   = lane & 15;       // column-within-tile owner index
  const int hq   = lane >> 4;       // row-subgroup index

  const int b = blockIdx.x;
  const float g  = gam[b];
  const float aa = fabsf(alp[b]);
  const float* __restrict__ C = cov + (size_t)b * (NA * NA);

  const bool mk = ((lm >> 2) == hq);
  const int  cw = lm & 3;

  // ===== Phase 1: Q = (gC)^T(gC), f16-packed registers + exact f32 diag.
  // 32 k-rows/round, software-prefetched (round kb+1's loads issued before
  // round kb's transpose+MFMA -> HBM latency hidden under compute).
  // ah[ii][j2][c] packs Q[16*(w8+8ii)+4hq+c][16*(2j2)+lm | 16*(2j2+1)+lm]
  f16x2 ah[2][8][4];
  float dacc = 0.f;

  const int kk_s = t >> 4;          // staging row 0..31
  const int ib_s = (t & 15) << 4;   // staging col 0,16,...,240
  float4 pf[4];

  #pragma unroll
  for (int pass = 0; pass < 2; ++pass) {
    f32x4 acc1[16];
    #pragma unroll
    for (int j = 0; j < 16; ++j) acc1[j] = f32x4{0.f, 0.f, 0.f, 0.f};

    { // prefetch round 0
      const float* src = C + (size_t)kk_s * NA + ib_s;
      #pragma unroll
      for (int j4 = 0; j4 < 4; ++j4) pf[j4] = *(const float4*)(src + 4 * j4);
    }

    #pragma unroll 1
    for (int kb = 0; kb < 8; ++kb) {
      { // stage 32x256 f32 from prefetch regs (gamma-folded)
        float* dst = STG + kk_s * CSTR + ib_s;
        #pragma unroll
        for (int j4 = 0; j4 < 4; ++j4)
          *(float4*)(dst + 4 * j4) = make_float4(pf[j4].x * g, pf[j4].y * g,
                                                 pf[j4].z * g, pf[j4].w * g);
      }
      __syncthreads();
      if (kb < 7) { // issue next round's loads; latency hides under below
        const float* src = C + (size_t)((kb + 1) * 32 + kk_s) * NA + ib_s;
        #pragma unroll
        for (int j4 = 0; j4 < 4; ++j4) pf[j4] = *(const float4*)(src + 4 * j4);
      }
      { // transpose to f16 C^T tile (k=0..31); pass 0 also exact diag
        const int ti = t & 255;
        const int th = t >> 8;          // k-half 0/1 (16 k each)
        f16x8 v0, v1;
        #pragma unroll
        for (int s2 = 0; s2 < 8; ++s2) {
          const float x0 = STG[(16 * th + s2) * CSTR + ti];
          const float x1 = STG[(16 * th + 8 + s2) * CSTR + ti];
          if (pass == 0) dacc += x0 * x0 + x1 * x1;
          v0[s2] = (f16)x0;
          v1[s2] = (f16)x1;
        }
        *(f16x8*)(CH + ti * TSTR + 16 * th)     = v0;
        *(f16x8*)(CH + ti * TSTR + 16 * th + 8) = v1;
      }
      __syncthreads();
      const int I = w8 + 8 * pass;
      const f16x4 aH0 = *(const f16x4*)(CH + (16 * I + lm) * TSTR + 4 * hq);
      const f16x4 aH1 = *(const f16x4*)(CH + (16 * I + lm) * TSTR + 16 + 4 * hq);
      #pragma unroll
      for (int J = 0; J < 16; ++J) {
        const f16x4 bH0 = *(const f16x4*)(CH + (16 * J + lm) * TSTR + 4 * hq);
        const f16x4 bH1 = *(const f16x4*)(CH + (16 * J + lm) * TSTR + 16 + 4 * hq);
        acc1[J] = __builtin_amdgcn_mfma_f32_16x16x16f16(aH0, bH0, acc1[J], 0, 0, 0);
        acc1[J] = __builtin_amdgcn_mfma_f32_16x16x16f16(aH1, bH1, acc1[J], 0, 0, 0);
      }
    }
    // pack to f16 pairs (canonical); zero diag slot (handled exactly via dgv)
    const int dj = w8 + 8 * pass;
    #pragma unroll
    for (int j2 = 0; j2 < 8; ++j2) {
      #pragma unroll
      for (int c = 0; c < 4; ++c) {
        float a0 = acc1[2 * j2][c];
        float a1 = acc1[2 * j2 + 1][c];
        if (2 * j2     == dj && lm == 4 * hq + c) a0 = 0.f;
        if (2 * j2 + 1 == dj && lm == 4 * hq + c) a1 = 0.f;
        ah[pass][j2][c] = pk2(a0, a1);
      }
    }
  }

  // exact diag sums -> LDS overlay
  {
    const int ti = t & 255;
    const int th = t >> 8;
    DTMP[th * 256 + ti] = dacc;
  }
  __syncthreads();
  float dg0 = 0.f, dg1 = 0.f;
  if (mk) {
    const int c0 = 16 * w8 + lm, c1 = 16 * (w8 + 8) + lm;
    dg0 = DTMP[c0] + DTMP[256 + c0] + aa;
    dg1 = DTMP[c1] + DTMP[256 + c1] + aa;
  }
  f32x4 dgv0, dgv1;
  #pragma unroll
  for (int p = 0; p < 4; ++p) {
    dgv0[p] = (lm == 4 * hq + p) ? dg0 : 0.f;
    dgv1[p] = (lm == 4 * hq + p) ? dg1 : 0.f;
  }
  __syncthreads();   // DTMP dead

  float* const YY0 = (float*)(smem + OFF_YY0);
  float* const YY1 = (float*)(smem + OFF_YY1);

  // Row-relative z storage: zr[g][c] = z[16*(4*(hq^g)+c) + lm]. All static.
  float zr[4][4];
  #pragma unroll
  for (int gg = 0; gg < 4; ++gg)
    #pragma unroll
    for (int c = 0; c < 4; ++c) zr[gg][c] = 1.f;   // power b0 = ones

  // matvec: canonical zpk assembled from zr via selg2 (g = q^hq).
  auto matvec = [&](f32x4& y0, f32x4& y1) {
    f16x2 zrpk[4][2];
    #pragma unroll
    for (int gg = 0; gg < 4; ++gg) {
      zrpk[gg][0] = pk2(zr[gg][0], zr[gg][1]);
      zrpk[gg][1] = pk2(zr[gg][2], zr[gg][3]);
    }
    f16x2 zpk[8];
    #pragma unroll
    for (int j2 = 0; j2 < 8; ++j2) {
      const int q = j2 >> 1, pb = j2 & 1;
      zpk[j2] = selg2(zrpk[0][pb], zrpk[1][pb], zrpk[2][pb], zrpk[3][pb], q ^ hq);
    }
    // exact f32 diag z: zd0 = z[16*w8+lm], zd1 = z[16*(w8+8)+lm]
    float zd0 = 0.f, zd1 = 0.f;
    {
      const int g0 = (w8 >> 2) ^ hq;      // zd1 uses g0^2
      const int cc0 = w8 & 3;             // wave-uniform
      #pragma unroll
      for (int cc = 0; cc < 4; ++cc)
        if (cc0 == cc) {
          const float ab = (g0 & 1) ? zr[1][cc] : zr[0][cc];
          const float cd = (g0 & 1) ? zr[3][cc] : zr[2][cc];
          zd0 = (g0 & 2) ? cd : ab;
          zd1 = (g0 & 2) ? ab : cd;
        }
    }
    y0 = dgv0 * zd0;
    y1 = dgv1 * zd1;
    #pragma unroll
    for (int j2 = 0; j2 < 8; ++j2) {
      #pragma unroll
      for (int c = 0; c < 4; ++c) {
        y0[c] = dot2f(ah[0][j2][c], zpk[j2], y0[c]);
        y1[c] = dot2f(ah[1][j2][c], zpk[j2], y1[c]);
      }
    }
    #pragma unroll
    for (int c = 0; c < 4; ++c) { y0[c] = red16(y0[c]); y1[c] = red16(y1[c]); }
  };
  auto publish = [&](float* YYp, const f32x4& y0, const f32x4& y1) {
    if (mk) {
      const float ya = (cw == 0) ? y0[0] : (cw == 1) ? y0[1] : (cw == 2) ? y0[2] : y0[3];
      const float yb = (cw == 0) ? y1[0] : (cw == 1) ? y1[1] : (cw == 2) ? y1[2] : y1[3];
      YYp[16 * w8 + lm]       = ya;
      YYp[16 * (w8 + 8) + lm] = yb;
    }
  };

  // ===== Phase 2: power iteration; step from ||Qb|| with safety margin =====
  float step;
  {
    float lam = 0.f;
    #pragma unroll 1
    for (int pi = 0; pi < POWER_ITERS; ++pi) {
      f32x4 y0, y1; matvec(y0, y1);
      float* YYp = (pi & 1) ? YY1 : YY0;
      publish(YYp, y0, y1);
      __syncthreads();
      float nrm = 0.f;
      #pragma unroll
      for (int gg = 0; gg < 4; ++gg)
        #pragma unroll
        for (int c = 0; c < 4; ++c) {
          const float tv = YYp[(((hq ^ gg) * 4 + c) << 4) + lm];
          nrm += tv * tv;
          zr[gg][c] = tv;
        }
      nrm = rfl(red16(nrm));
      const float nn = sqrtf(nrm);
      lam = nn;                               // ||Q b_{k-1}|| (b normalized)
      const float rb = 1.f / (nn + 1e-12f);
      #pragma unroll
      for (int gg = 0; gg < 4; ++gg)
        #pragma unroll
        for (int c = 0; c < 4; ++c) zr[gg][c] *= rb;
    }
    step = 1.f / (2.f * (1.12f * lam) + 1e-6f);
  }

  // ===== Phase 3: FISTA + gradient-based adaptive restart (O'Donoghue-
  // Candes) — quarter-split state, 1 barrier/iter, tiered tolerance exit. =====
  float wo4[4], rr4[4];
  #pragma unroll
  for (int c = 0; c < 4; ++c) {
    rr4[c] = rets[b * NA + ((4 * hq + c) << 4) + lm];
    wo4[c] = 1.f / 256.f;
  }
  #pragma unroll
  for (int gg = 0; gg < 4; ++gg)
    #pragma unroll
    for (int c = 0; c < 4; ++c) zr[gg][c] = 1.f / 256.f;
  float tt = 1.f;
  float tauw = 1e30f;
  float kest = 32.f;

  #pragma unroll 1
  for (int it = 0; it < PGD_ITERS; ++it) {
    f32x4 y0, y1; matvec(y0, y1);
    float* YYp = (it & 1) ? YY0 : YY1;
    publish(YYp, y0, y1);
    __syncthreads();

    // own columns only: v = z - step*(2y - r)
    float vq[4];
    #pragma unroll
    for (int c = 0; c < 4; ++c) {
      const float yv = YYp[((4 * hq + c) << 4) + lm];
      vq[c] = zr[0][c] - step * (2.f * yv - rr4[c]);
    }

    // Projection (verified R10/R12/R14/R17): uniform-scalar secant w/ early exit
    float lo = -1e30f, hi = 1e30f;
    float tau = tauw;
    float fprev = 0.f, tprev = 0.f;
    bool have = false;
    #pragma unroll 1
    for (int nit = 0; nit < 16; ++nit) {
      float sp = clamp01(vq[0] - tau) + clamp01(vq[1] - tau)
               + clamp01(vq[2] - tau) + clamp01(vq[3] - tau);
      const float s = redwave_add(sp);
      if (nit == 0) {
        const float pm = redwave_max(fmaxf(fmaxf(vq[0], vq[1]), fmaxf(vq[2], vq[3])));
        lo = pm - 1.0f; hi = pm;              // root always in [max-1, max]
        if (!(tau > lo && tau < hi)) { tau = 0.5f * (lo + hi); continue; }
      }
      const float f = s - 1.f;
      if (fabsf(f) <= 1e-5f) break;
      if (f > 0.f) lo = tau; else hi = tau;
      if (hi - lo < 1e-7f) break;
      float kc = have ? ((f - fprev) / (tprev - tau)) : kest;
      if (!(kc > 0.5f)) kc = kest;
      const float tn = tau + f / kc;
      fprev = f; tprev = tau; have = true;
      kest = fmaxf(kc, 1.f);
      const float tc = (tn > lo && tn < hi) ? tn : 0.5f * (lo + hi);
      if (tc == tau) break;
      tau = tc;
    }
    tauw = tau;

    // w+ = clamp(v - tau); accumulate exit metric and restart test
    float wn4[4];
    float dsum = 0.f, rs = 0.f;
    #pragma unroll
    for (int c = 0; c < 4; ++c) {
      wn4[c] = clamp01(vq[c] - tau);
      dsum += fabsf(wn4[c] - wo4[c]);
      rs   += (zr[0][c] - wn4[c]) * (wn4[c] - wo4[c]);
    }
    const float dtot = redwave_add(dsum);
    const float rtot = redwave_add(rs);

    // Tiered early exit: base 1e-4 (R24-verified, drift ~1e-3); stragglers
    // past iter 128 accept 4e-4 (drift <= 4e-4*rho/(1-rho) ~ 3.6e-3 +
    // ~1e-3 f16-Q floor ~ 5e-3, 4x under the 2e-2 threshold).
    const float tol = (it >= 128) ? 4e-4f : 1e-4f;
    const bool fin = (it == PGD_ITERS - 1) || (dtot <= tol);
    if (fin) {
      if (w8 == 0) {
        #pragma unroll
        for (int c = 0; c < 4; ++c)
          out[(size_t)b * NA + ((4 * hq + c) << 4) + lm] = wn4[c];
      }
      break;
    }

    // gradient restart: momentum opposes the step -> reset tt (coef -> 0)
    if (rtot > 0.f) tt = 1.f;
    const float tnew = 0.5f * (1.f + sqrtf(1.f + 4.f * tt * tt));
    const float coef = (tt - 1.f) / tnew;
    float zn[4];
    #pragma unroll
    for (int c = 0; c < 4; ++c) {
      zn[c] = wn4[c] + coef * (wn4[c] - wo4[c]);
      wo4[c] = wn4[c];
    }
    tt = tnew;

    // f32-exact 3-way exchange refills the row-relative replicas
    #pragma unroll
    for (int c = 0; c < 4; ++c) {
      zr[0][c] = zn[c];
      zr[1][c] = __shfl_xor(zn[c], 16);
      zr[2][c] = __shfl_xor(zn[c], 32);
      zr[3][c] = __shfl_xor(zn[c], 48);
    }
  }
}

extern "C" void kernel_launch(void* const* d_in, const int* in_sizes, int n_in,
                              void* d_out, int out_size, void* d_ws, size_t ws_size,
                              hipStream_t stream) {
  (void)in_sizes; (void)n_in; (void)out_size; (void)d_ws; (void)ws_size;
  const float* rets = (const float*)d_in[0];
  const float* cov  = (const float*)d_in[1];
  const float* gam  = (const float*)d_in[2];
  const float* alp  = (const float*)d_in[3];
  float* out = (float*)d_out;
  hipLaunchKernelGGL(markowitz_kernel, dim3(NS), dim3(512), 0, stream,
                     rets, cov, gam, alp, out);
}

// Round 26
// 240.111 us; speedup vs baseline: 10.3565x; 1.1967x over previous
//
#include <hip/hip_runtime.h>

#define NS 512
#define NA 256
#define PGD_ITERS 300
#define POWER_ITERS 8

typedef _Float16 f16;
typedef __attribute__((ext_vector_type(2))) _Float16 f16x2;
typedef __attribute__((ext_vector_type(4))) _Float16 f16x4;
typedef __attribute__((ext_vector_type(8))) _Float16 f16x8;
typedef __attribute__((ext_vector_type(4))) float f32x4;

// LDS layout (bytes). STG (32x260 f32) / CH (256x40 f16) live only during
// the syrk; YY0/YY1 double-buffer the y-exchange. DTMP overlays YY0+YY1.
#define CSTR 260            // f32 staging row stride (elems)
#define TSTR 40             // f16 C^T tile row stride (elems) = 80 B (32k+pad)
#define OFF_CH  33280       // STG: 32*260*4
#define OFF_YY0 53760       // CH:  256*40*2 = 20480
#define OFF_YY1 54784
#define LDS_BYTES 55808     // 2 blocks/CU by LDS (111.6 KB < 160 KB)

// ---- cross-lane primitives (VALU DPP; minimal DS-pipe traffic) ----
// SAFETY: all call sites have FULL exec; branches only on wave-uniform
// scalars (readlane/readfirstlane results or wave-id comparisons).
template<int CTRL>
__device__ __forceinline__ float dpp_add(float x) {
  const int r = __builtin_amdgcn_update_dpp(0, __float_as_int(x), CTRL, 0xF, 0xF, true);
  return x + __int_as_float(r);
}
template<int CTRL>
__device__ __forceinline__ float dpp_max(float x) {
  const int r = __builtin_amdgcn_update_dpp(0, __float_as_int(x), CTRL, 0xF, 0xF, true);
  return fmaxf(x, __int_as_float(r));
}
__device__ __forceinline__ float red16(float x) {
  x = dpp_add<0x121>(x);  // row_ror:1
  x = dpp_add<0x122>(x);  // row_ror:2
  x = dpp_add<0x124>(x);  // row_ror:4
  x = dpp_add<0x128>(x);  // row_ror:8
  return x;
}
__device__ __forceinline__ float redwave_add(float x) {
  x = red16(x);
  {
    const int r = __builtin_amdgcn_update_dpp(0, __float_as_int(x), 0x142, 0xA, 0xF, true);
    x += __int_as_float(r);
  }
  {
    const int r = __builtin_amdgcn_update_dpp(0, __float_as_int(x), 0x143, 0xC, 0xF, true);
    x += __int_as_float(r);
  }
  return __int_as_float(__builtin_amdgcn_readlane(__float_as_int(x), 63));
}
__device__ __forceinline__ float redwave_max(float x) {
  x = dpp_max<0x121>(x);
  x = dpp_max<0x122>(x);
  x = dpp_max<0x124>(x);
  x = dpp_max<0x128>(x);
  {
    const int r = __builtin_amdgcn_update_dpp(__float_as_int(x), __float_as_int(x), 0x142, 0xA, 0xF, false);
    x = fmaxf(x, __int_as_float(r));
  }
  {
    const int r = __builtin_amdgcn_update_dpp(__float_as_int(x), __float_as_int(x), 0x143, 0xC, 0xF, false);
    x = fmaxf(x, __int_as_float(r));
  }
  return __int_as_float(__builtin_amdgcn_readlane(__float_as_int(x), 63));
}
__device__ __forceinline__ float rfl(float x) {
  return __int_as_float(__builtin_amdgcn_readfirstlane(__float_as_int(x)));
}
__device__ __forceinline__ float clamp01(float x) {
  return __builtin_amdgcn_fmed3f(x, 0.f, 1.f);
}
__device__ __forceinline__ f16x2 pk2(float a, float b) {
  return __builtin_bit_cast(f16x2, __builtin_amdgcn_cvt_pkrtz(a, b));
}
__device__ __forceinline__ float dot2f(f16x2 a, f16x2 b, float c) {
  return __builtin_amdgcn_fdot2(a, b, c, false);   // v_dot2_f32_f16
}
// select 1-of-4 packed f16x2 by 2-bit index (3 cndmask)
__device__ __forceinline__ f16x2 selg2(f16x2 a0, f16x2 a1, f16x2 a2, f16x2 a3, int g) {
  const int i0 = __builtin_bit_cast(int, a0);
  const int i1 = __builtin_bit_cast(int, a1);
  const int i2 = __builtin_bit_cast(int, a2);
  const int i3 = __builtin_bit_cast(int, a3);
  const int ab = (g & 1) ? i1 : i0;
  const int cd = (g & 1) ? i3 : i2;
  return __builtin_bit_cast(f16x2, (g & 2) ? cd : ab);
}

__global__ __launch_bounds__(512, 4) void markowitz_kernel(
    const float* __restrict__ rets, const float* __restrict__ cov,
    const float* __restrict__ gam,  const float* __restrict__ alp,
    float* __restrict__ out)
{
  __shared__ char smem[LDS_BYTES] __attribute__((aligned(16)));
  float* STG  = (float*)smem;
  f16*   CH   = (f16*)(smem + OFF_CH);
  float* DTMP = (float*)(smem + OFF_YY0);   // 512 f32 overlay (YY0+YY1)

  const int t    = threadIdx.x;
  const int lane = t & 63;
  const int w8   = t >> 6;          // wave 0..7
  const int lm   = lane & 15;       // column-within-tile owner index
  const int hq   = lane >> 4;       // row-subgroup index

  const int b = blockIdx.x;
  const float g  = gam[b];
  const float aa = fabsf(alp[b]);
  const float* __restrict__ C = cov + (size_t)b * (NA * NA);

  const bool mk = ((lm >> 2) == hq);
  const int  cw = lm & 3;

  // ===== Phase 1: Q = (gC)^T(gC), f16-packed registers + exact f32 diag.
  // 32 k-rows/round, software-prefetched.
  // ah[ii][j2][c] packs Q[16*(w8+8ii)+4hq+c][16*(2j2)+lm | 16*(2j2+1)+lm]
  f16x2 ah[2][8][4];
  float dacc = 0.f;

  const int kk_s = t >> 4;          // staging row 0..31
  const int ib_s = (t & 15) << 4;   // staging col 0,16,...,240
  float4 pf[4];

  #pragma unroll
  for (int pass = 0; pass < 2; ++pass) {
    f32x4 acc1[16];
    #pragma unroll
    for (int j = 0; j < 16; ++j) acc1[j] = f32x4{0.f, 0.f, 0.f, 0.f};

    { // prefetch round 0
      const float* src = C + (size_t)kk_s * NA + ib_s;
      #pragma unroll
      for (int j4 = 0; j4 < 4; ++j4) pf[j4] = *(const float4*)(src + 4 * j4);
    }

    #pragma unroll 1
    for (int kb = 0; kb < 8; ++kb) {
      { // stage 32x256 f32 from prefetch regs (gamma-folded)
        float* dst = STG + kk_s * CSTR + ib_s;
        #pragma unroll
        for (int j4 = 0; j4 < 4; ++j4)
          *(float4*)(dst + 4 * j4) = make_float4(pf[j4].x * g, pf[j4].y * g,
                                                 pf[j4].z * g, pf[j4].w * g);
      }
      __syncthreads();
      if (kb < 7) { // issue next round's loads; latency hides under below
        const float* src = C + (size_t)((kb + 1) * 32 + kk_s) * NA + ib_s;
        #pragma unroll
        for (int j4 = 0; j4 < 4; ++j4) pf[j4] = *(const float4*)(src + 4 * j4);
      }
      { // transpose to f16 C^T tile (k=0..31); pass 0 also exact diag
        const int ti = t & 255;
        const int th = t >> 8;          // k-half 0/1 (16 k each)
        f16x8 v0, v1;
        #pragma unroll
        for (int s2 = 0; s2 < 8; ++s2) {
          const float x0 = STG[(16 * th + s2) * CSTR + ti];
          const float x1 = STG[(16 * th + 8 + s2) * CSTR + ti];
          if (pass == 0) dacc += x0 * x0 + x1 * x1;
          v0[s2] = (f16)x0;
          v1[s2] = (f16)x1;
        }
        *(f16x8*)(CH + ti * TSTR + 16 * th)     = v0;
        *(f16x8*)(CH + ti * TSTR + 16 * th + 8) = v1;
      }
      __syncthreads();
      const int I = w8 + 8 * pass;
      const f16x4 aH0 = *(const f16x4*)(CH + (16 * I + lm) * TSTR + 4 * hq);
      const f16x4 aH1 = *(const f16x4*)(CH + (16 * I + lm) * TSTR + 16 + 4 * hq);
      #pragma unroll
      for (int J = 0; J < 16; ++J) {
        const f16x4 bH0 = *(const f16x4*)(CH + (16 * J + lm) * TSTR + 4 * hq);
        const f16x4 bH1 = *(const f16x4*)(CH + (16 * J + lm) * TSTR + 16 + 4 * hq);
        acc1[J] = __builtin_amdgcn_mfma_f32_16x16x16f16(aH0, bH0, acc1[J], 0, 0, 0);
        acc1[J] = __builtin_amdgcn_mfma_f32_16x16x16f16(aH1, bH1, acc1[J], 0, 0, 0);
      }
    }
    // pack to f16 pairs (canonical); zero diag slot (handled exactly via dgv)
    const int dj = w8 + 8 * pass;
    #pragma unroll
    for (int j2 = 0; j2 < 8; ++j2) {
      #pragma unroll
      for (int c = 0; c < 4; ++c) {
        float a0 = acc1[2 * j2][c];
        float a1 = acc1[2 * j2 + 1][c];
        if (2 * j2     == dj && lm == 4 * hq + c) a0 = 0.f;
        if (2 * j2 + 1 == dj && lm == 4 * hq + c) a1 = 0.f;
        ah[pass][j2][c] = pk2(a0, a1);
      }
    }
  }

  // exact diag sums -> LDS overlay
  {
    const int ti = t & 255;
    const int th = t >> 8;
    DTMP[th * 256 + ti] = dacc;
  }
  __syncthreads();
  float dg0 = 0.f, dg1 = 0.f;
  if (mk) {
    const int c0 = 16 * w8 + lm, c1 = 16 * (w8 + 8) + lm;
    dg0 = DTMP[c0] + DTMP[256 + c0] + aa;
    dg1 = DTMP[c1] + DTMP[256 + c1] + aa;
  }
  f32x4 dgv0, dgv1;
  #pragma unroll
  for (int p = 0; p < 4; ++p) {
    dgv0[p] = (lm == 4 * hq + p) ? dg0 : 0.f;
    dgv1[p] = (lm == 4 * hq + p) ? dg1 : 0.f;
  }
  __syncthreads();   // DTMP dead

  float* const YY0 = (float*)(smem + OFF_YY0);
  float* const YY1 = (float*)(smem + OFF_YY1);

  // Row-relative z storage: zr[g][c] = z[16*(4*(hq^g)+c) + lm]. All static.
  float zr[4][4];
  #pragma unroll
  for (int gg = 0; gg < 4; ++gg)
    #pragma unroll
    for (int c = 0; c < 4; ++c) zr[gg][c] = 1.f;   // power b0 = ones

  // matvec: canonical zpk assembled from zr via selg2 (g = q^hq).
  auto matvec = [&](f32x4& y0, f32x4& y1) {
    f16x2 zrpk[4][2];
    #pragma unroll
    for (int gg = 0; gg < 4; ++gg) {
      zrpk[gg][0] = pk2(zr[gg][0], zr[gg][1]);
      zrpk[gg][1] = pk2(zr[gg][2], zr[gg][3]);
    }
    f16x2 zpk[8];
    #pragma unroll
    for (int j2 = 0; j2 < 8; ++j2) {
      const int q = j2 >> 1, pb = j2 & 1;
      zpk[j2] = selg2(zrpk[0][pb], zrpk[1][pb], zrpk[2][pb], zrpk[3][pb], q ^ hq);
    }
    // exact f32 diag z: zd0 = z[16*w8+lm], zd1 = z[16*(w8+8)+lm]
    float zd0 = 0.f, zd1 = 0.f;
    {
      const int g0 = (w8 >> 2) ^ hq;      // zd1 uses g0^2
      const int cc0 = w8 & 3;             // wave-uniform
      #pragma unroll
      for (int cc = 0; cc < 4; ++cc)
        if (cc0 == cc) {
          const float ab = (g0 & 1) ? zr[1][cc] : zr[0][cc];
          const float cd = (g0 & 1) ? zr[3][cc] : zr[2][cc];
          zd0 = (g0 & 2) ? cd : ab;
          zd1 = (g0 & 2) ? ab : cd;
        }
    }
    y0 = dgv0 * zd0;
    y1 = dgv1 * zd1;
    #pragma unroll
    for (int j2 = 0; j2 < 8; ++j2) {
      #pragma unroll
      for (int c = 0; c < 4; ++c) {
        y0[c] = dot2f(ah[0][j2][c], zpk[j2], y0[c]);
        y1[c] = dot2f(ah[1][j2][c], zpk[j2], y1[c]);
      }
    }
    #pragma unroll
    for (int c = 0; c < 4; ++c) { y0[c] = red16(y0[c]); y1[c] = red16(y1[c]); }
  };
  auto publish = [&](float* YYp, const f32x4& y0, const f32x4& y1) {
    if (mk) {
      const float ya = (cw == 0) ? y0[0] : (cw == 1) ? y0[1] : (cw == 2) ? y0[2] : y0[3];
      const float yb = (cw == 0) ? y1[0] : (cw == 1) ? y1[1] : (cw == 2) ? y1[2] : y1[3];
      YYp[16 * w8 + lm]       = ya;
      YYp[16 * (w8 + 8) + lm] = yb;
    }
  };

  // ===== Phase 2: power iteration; step from ||Qb|| with safety margin =====
  float step;
  {
    float lam = 0.f;
    #pragma unroll 1
    for (int pi = 0; pi < POWER_ITERS; ++pi) {
      f32x4 y0, y1; matvec(y0, y1);
      float* YYp = (pi & 1) ? YY1 : YY0;
      publish(YYp, y0, y1);
      __syncthreads();
      float nrm = 0.f;
      #pragma unroll
      for (int gg = 0; gg < 4; ++gg)
        #pragma unroll
        for (int c = 0; c < 4; ++c) {
          const float tv = YYp[(((hq ^ gg) * 4 + c) << 4) + lm];
          nrm += tv * tv;
          zr[gg][c] = tv;
        }
      nrm = rfl(red16(nrm));
      const float nn = sqrtf(nrm);
      lam = nn;                               // ||Q b_{k-1}|| (b normalized)
      const float rb = 1.f / (nn + 1e-12f);
      #pragma unroll
      for (int gg = 0; gg < 4; ++gg)
        #pragma unroll
        for (int c = 0; c < 4; ++c) zr[gg][c] *= rb;
    }
    step = 1.f / (2.f * (1.12f * lam) + 1e-6f);
  }

  // ===== Phase 3: FISTA + gradient-based adaptive restart — quarter-split
  // state, 1 barrier/iter, tiered tolerance exit. =====
  float wo4[4], rr4[4];
  #pragma unroll
  for (int c = 0; c < 4; ++c) {
    rr4[c] = rets[b * NA + ((4 * hq + c) << 4) + lm];
    wo4[c] = 1.f / 256.f;
  }
  #pragma unroll
  for (int gg = 0; gg < 4; ++gg)
    #pragma unroll
    for (int c = 0; c < 4; ++c) zr[gg][c] = 1.f / 256.f;
  float tt = 1.f;
  float tauw = 1e30f;
  float kest = 32.f;

  #pragma unroll 1
  for (int it = 0; it < PGD_ITERS; ++it) {
    f32x4 y0, y1; matvec(y0, y1);
    float* YYp = (it & 1) ? YY0 : YY1;
    publish(YYp, y0, y1);
    __syncthreads();

    // own columns only: v = z - step*(2y - r)
    float vq[4];
    #pragma unroll
    for (int c = 0; c < 4; ++c) {
      const float yv = YYp[((4 * hq + c) << 4) + lm];
      vq[c] = zr[0][c] - step * (2.f * yv - rr4[c]);
    }

    // Projection (verified R10/R12/R14/R17): uniform-scalar secant w/ early
    // exit. f-tol 4e-5: tau error <= 4e-5 -> per-element w error <= 4e-5,
    // invisible at the ~1e-3 f16-Q floor; saves ~1 eval/iter.
    float lo = -1e30f, hi = 1e30f;
    float tau = tauw;
    float fprev = 0.f, tprev = 0.f;
    bool have = false;
    #pragma unroll 1
    for (int nit = 0; nit < 16; ++nit) {
      float sp = clamp01(vq[0] - tau) + clamp01(vq[1] - tau)
               + clamp01(vq[2] - tau) + clamp01(vq[3] - tau);
      const float s = redwave_add(sp);
      if (nit == 0) {
        const float pm = redwave_max(fmaxf(fmaxf(vq[0], vq[1]), fmaxf(vq[2], vq[3])));
        lo = pm - 1.0f; hi = pm;              // root always in [max-1, max]
        if (!(tau > lo && tau < hi)) { tau = 0.5f * (lo + hi); continue; }
      }
      const float f = s - 1.f;
      if (fabsf(f) <= 4e-5f) break;
      if (f > 0.f) lo = tau; else hi = tau;
      if (hi - lo < 1e-7f) break;
      float kc = have ? ((f - fprev) / (tprev - tau)) : kest;
      if (!(kc > 0.5f)) kc = kest;
      const float tn = tau + f / kc;
      fprev = f; tprev = tau; have = true;
      kest = fmaxf(kc, 1.f);
      const float tc = (tn > lo && tn < hi) ? tn : 0.5f * (lo + hi);
      if (tc == tau) break;
      tau = tc;
    }
    tauw = tau;

    // w+ = clamp(v - tau); accumulate exit metric and restart test
    float wn4[4];
    float dsum = 0.f, rs = 0.f;
    #pragma unroll
    for (int c = 0; c < 4; ++c) {
      wn4[c] = clamp01(vq[c] - tau);
      dsum += fabsf(wn4[c] - wo4[c]);
      rs   += (zr[0][c] - wn4[c]) * (wn4[c] - wo4[c]);
    }
    const float dtot = redwave_add(dsum);
    const float rtot = redwave_add(rs);

    // Tiered early exit. Measured: absmax pinned at 9.77e-4 for tolerances
    // 0 / 1e-5 / 1e-4 -> error is f16-Q-floor-dominated, tolerance slack.
    // base 3e-4 (drift ~2.7e-3); >=48 iters 6e-4 (~5.4e-3); >=96 1.2e-3
    // (~1.1e-2, rare kappa-extreme samples only) — all under 2e-2.
    const float tol = (it >= 96) ? 1.2e-3f : (it >= 48) ? 6e-4f : 3e-4f;
    const bool fin = (it == PGD_ITERS - 1) || (dtot <= tol);
    if (fin) {
      if (w8 == 0) {
        #pragma unroll
        for (int c = 0; c < 4; ++c)
          out[(size_t)b * NA + ((4 * hq + c) << 4) + lm] = wn4[c];
      }
      break;
    }

    // gradient restart: momentum opposes the step -> reset tt (coef -> 0)
    if (rtot > 0.f) tt = 1.f;
    const float tnew = 0.5f * (1.f + sqrtf(1.f + 4.f * tt * tt));
    const float coef = (tt - 1.f) / tnew;
    float zn[4];
    #pragma unroll
    for (int c = 0; c < 4; ++c) {
      zn[c] = wn4[c] + coef * (wn4[c] - wo4[c]);
      wo4[c] = wn4[c];
    }
    tt = tnew;

    // f32-exact 3-way exchange refills the row-relative replicas
    #pragma unroll
    for (int c = 0; c < 4; ++c) {
      zr[0][c] = zn[c];
      zr[1][c] = __shfl_xor(zn[c], 16);
      zr[2][c] = __shfl_xor(zn[c], 32);
      zr[3][c] = __shfl_xor(zn[c], 48);
    }
  }
}

extern "C" void kernel_launch(void* const* d_in, const int* in_sizes, int n_in,
                              void* d_out, int out_size, void* d_ws, size_t ws_size,
                              hipStream_t stream) {
  (void)in_sizes; (void)n_in; (void)out_size; (void)d_ws; (void)ws_size;
  const float* rets = (const float*)d_in[0];
  const float* cov  = (const float*)d_in[1];
  const float* gam  = (const float*)d_in[2];
  const float* alp  = (const float*)d_in[3];
  float* out = (float*)d_out;
  hipLaunchKernelGGL(markowitz_kernel, dim3(NS), dim3(512), 0, stream,
                     rets, cov, gam, alp, out);
}

// Round 27
// 217.298 us; speedup vs baseline: 11.4438x; 1.1050x over previous
//
#include <hip/hip_runtime.h>

#define NS 512
#define NA 256
#define PGD_ITERS 300
#define POWER_ITERS 6

typedef _Float16 f16;
typedef __attribute__((ext_vector_type(2))) _Float16 f16x2;
typedef __attribute__((ext_vector_type(4))) _Float16 f16x4;
typedef __attribute__((ext_vector_type(8))) _Float16 f16x8;
typedef __attribute__((ext_vector_type(4))) float f32x4;

// LDS layout (bytes). STG (32x260 f32) / CH (256x40 f16) live only during
// the syrk; YY0/YY1 double-buffer the y-exchange. DTMP overlays YY0+YY1.
#define CSTR 260            // f32 staging row stride (elems)
#define TSTR 40             // f16 C^T tile row stride (elems) = 80 B (32k+pad)
#define OFF_CH  33280       // STG: 32*260*4
#define OFF_YY0 53760       // CH:  256*40*2 = 20480
#define OFF_YY1 54784
#define LDS_BYTES 55808     // 2 blocks/CU by LDS (111.6 KB < 160 KB)

// ---- cross-lane primitives (VALU DPP; minimal DS-pipe traffic) ----
// SAFETY: all call sites have FULL exec; branches only on wave-uniform
// scalars (readlane/readfirstlane results or wave-id comparisons).
template<int CTRL>
__device__ __forceinline__ float dpp_add(float x) {
  const int r = __builtin_amdgcn_update_dpp(0, __float_as_int(x), CTRL, 0xF, 0xF, true);
  return x + __int_as_float(r);
}
template<int CTRL>
__device__ __forceinline__ float dpp_max(float x) {
  const int r = __builtin_amdgcn_update_dpp(0, __float_as_int(x), CTRL, 0xF, 0xF, true);
  return fmaxf(x, __int_as_float(r));
}
__device__ __forceinline__ float red16(float x) {
  x = dpp_add<0x121>(x);  // row_ror:1
  x = dpp_add<0x122>(x);  // row_ror:2
  x = dpp_add<0x124>(x);  // row_ror:4
  x = dpp_add<0x128>(x);  // row_ror:8
  return x;
}
__device__ __forceinline__ float redwave_add(float x) {
  x = red16(x);
  {
    const int r = __builtin_amdgcn_update_dpp(0, __float_as_int(x), 0x142, 0xA, 0xF, true);
    x += __int_as_float(r);
  }
  {
    const int r = __builtin_amdgcn_update_dpp(0, __float_as_int(x), 0x143, 0xC, 0xF, true);
    x += __int_as_float(r);
  }
  return __int_as_float(__builtin_amdgcn_readlane(__float_as_int(x), 63));
}
__device__ __forceinline__ float redwave_max(float x) {
  x = dpp_max<0x121>(x);
  x = dpp_max<0x122>(x);
  x = dpp_max<0x124>(x);
  x = dpp_max<0x128>(x);
  {
    const int r = __builtin_amdgcn_update_dpp(__float_as_int(x), __float_as_int(x), 0x142, 0xA, 0xF, false);
    x = fmaxf(x, __int_as_float(r));
  }
  {
    const int r = __builtin_amdgcn_update_dpp(__float_as_int(x), __float_as_int(x), 0x143, 0xC, 0xF, false);
    x = fmaxf(x, __int_as_float(r));
  }
  return __int_as_float(__builtin_amdgcn_readlane(__float_as_int(x), 63));
}
__device__ __forceinline__ float rfl(float x) {
  return __int_as_float(__builtin_amdgcn_readfirstlane(__float_as_int(x)));
}
__device__ __forceinline__ float clamp01(float x) {
  return __builtin_amdgcn_fmed3f(x, 0.f, 1.f);
}
__device__ __forceinline__ f16x2 pk2(float a, float b) {
  return __builtin_bit_cast(f16x2, __builtin_amdgcn_cvt_pkrtz(a, b));
}
__device__ __forceinline__ float dot2f(f16x2 a, f16x2 b, float c) {
  return __builtin_amdgcn_fdot2(a, b, c, false);   // v_dot2_f32_f16
}
// select 1-of-4 packed f16x2 by 2-bit index (3 cndmask)
__device__ __forceinline__ f16x2 selg2(f16x2 a0, f16x2 a1, f16x2 a2, f16x2 a3, int g) {
  const int i0 = __builtin_bit_cast(int, a0);
  const int i1 = __builtin_bit_cast(int, a1);
  const int i2 = __builtin_bit_cast(int, a2);
  const int i3 = __builtin_bit_cast(int, a3);
  const int ab = (g & 1) ? i1 : i0;
  const int cd = (g & 1) ? i3 : i2;
  return __builtin_bit_cast(f16x2, (g & 2) ? cd : ab);
}

__global__ __launch_bounds__(512, 4) void markowitz_kernel(
    const float* __restrict__ rets, const float* __restrict__ cov,
    const float* __restrict__ gam,  const float* __restrict__ alp,
    float* __restrict__ out)
{
  __shared__ char smem[LDS_BYTES] __attribute__((aligned(16)));
  float* STG  = (float*)smem;
  f16*   CH   = (f16*)(smem + OFF_CH);
  float* DTMP = (float*)(smem + OFF_YY0);   // 512 f32 overlay (YY0+YY1)

  const int t    = threadIdx.x;
  const int lane = t & 63;
  const int w8   = t >> 6;          // wave 0..7
  const int lm   = lane & 15;       // column-within-tile owner index
  const int hq   = lane >> 4;       // row-subgroup index

  const int b = blockIdx.x;
  const float g  = gam[b];
  const float aa = fabsf(alp[b]);
  const float* __restrict__ C = cov + (size_t)b * (NA * NA);

  const bool mk = ((lm >> 2) == hq);
  const int  cw = lm & 3;

  // ===== Phase 1: Q = (gC)^T(gC), f16-packed registers + exact f32 diag.
  // 32 k-rows/round, software-prefetched.
  // ah[ii][j2][c] packs Q[16*(w8+8ii)+4hq+c][16*(2j2)+lm | 16*(2j2+1)+lm]
  f16x2 ah[2][8][4];
  float dacc = 0.f;

  const int kk_s = t >> 4;          // staging row 0..31
  const int ib_s = (t & 15) << 4;   // staging col 0,16,...,240
  float4 pf[4];

  #pragma unroll
  for (int pass = 0; pass < 2; ++pass) {
    f32x4 acc1[16];
    #pragma unroll
    for (int j = 0; j < 16; ++j) acc1[j] = f32x4{0.f, 0.f, 0.f, 0.f};

    { // prefetch round 0
      const float* src = C + (size_t)kk_s * NA + ib_s;
      #pragma unroll
      for (int j4 = 0; j4 < 4; ++j4) pf[j4] = *(const float4*)(src + 4 * j4);
    }

    #pragma unroll 1
    for (int kb = 0; kb < 8; ++kb) {
      { // stage 32x256 f32 from prefetch regs (gamma-folded)
        float* dst = STG + kk_s * CSTR + ib_s;
        #pragma unroll
        for (int j4 = 0; j4 < 4; ++j4)
          *(float4*)(dst + 4 * j4) = make_float4(pf[j4].x * g, pf[j4].y * g,
                                                 pf[j4].z * g, pf[j4].w * g);
      }
      __syncthreads();
      if (kb < 7) { // issue next round's loads; latency hides under below
        const float* src = C + (size_t)((kb + 1) * 32 + kk_s) * NA + ib_s;
        #pragma unroll
        for (int j4 = 0; j4 < 4; ++j4) pf[j4] = *(const float4*)(src + 4 * j4);
      }
      { // transpose to f16 C^T tile (k=0..31); pass 0 also exact diag
        const int ti = t & 255;
        const int th = t >> 8;          // k-half 0/1 (16 k each)
        f16x8 v0, v1;
        #pragma unroll
        for (int s2 = 0; s2 < 8; ++s2) {
          const float x0 = STG[(16 * th + s2) * CSTR + ti];
          const float x1 = STG[(16 * th + 8 + s2) * CSTR + ti];
          if (pass == 0) dacc += x0 * x0 + x1 * x1;
          v0[s2] = (f16)x0;
          v1[s2] = (f16)x1;
        }
        *(f16x8*)(CH + ti * TSTR + 16 * th)     = v0;
        *(f16x8*)(CH + ti * TSTR + 16 * th + 8) = v1;
      }
      __syncthreads();
      const int I = w8 + 8 * pass;
      const f16x4 aH0 = *(const f16x4*)(CH + (16 * I + lm) * TSTR + 4 * hq);
      const f16x4 aH1 = *(const f16x4*)(CH + (16 * I + lm) * TSTR + 16 + 4 * hq);
      #pragma unroll
      for (int J = 0; J < 16; ++J) {
        const f16x4 bH0 = *(const f16x4*)(CH + (16 * J + lm) * TSTR + 4 * hq);
        const f16x4 bH1 = *(const f16x4*)(CH + (16 * J + lm) * TSTR + 16 + 4 * hq);
        acc1[J] = __builtin_amdgcn_mfma_f32_16x16x16f16(aH0, bH0, acc1[J], 0, 0, 0);
        acc1[J] = __builtin_amdgcn_mfma_f32_16x16x16f16(aH1, bH1, acc1[J], 0, 0, 0);
      }
    }
    // pack to f16 pairs (canonical); zero diag slot (handled exactly via dgv)
    const int dj = w8 + 8 * pass;
    #pragma unroll
    for (int j2 = 0; j2 < 8; ++j2) {
      #pragma unroll
      for (int c = 0; c < 4; ++c) {
        float a0 = acc1[2 * j2][c];
        float a1 = acc1[2 * j2 + 1][c];
        if (2 * j2     == dj && lm == 4 * hq + c) a0 = 0.f;
        if (2 * j2 + 1 == dj && lm == 4 * hq + c) a1 = 0.f;
        ah[pass][j2][c] = pk2(a0, a1);
      }
    }
  }

  // exact diag sums -> LDS overlay
  {
    const int ti = t & 255;
    const int th = t >> 8;
    DTMP[th * 256 + ti] = dacc;
  }
  __syncthreads();
  float dg0 = 0.f, dg1 = 0.f;
  if (mk) {
    const int c0 = 16 * w8 + lm, c1 = 16 * (w8 + 8) + lm;
    dg0 = DTMP[c0] + DTMP[256 + c0] + aa;
    dg1 = DTMP[c1] + DTMP[256 + c1] + aa;
  }
  f32x4 dgv0, dgv1;
  #pragma unroll
  for (int p = 0; p < 4; ++p) {
    dgv0[p] = (lm == 4 * hq + p) ? dg0 : 0.f;
    dgv1[p] = (lm == 4 * hq + p) ? dg1 : 0.f;
  }
  __syncthreads();   // DTMP dead

  float* const YY0 = (float*)(smem + OFF_YY0);
  float* const YY1 = (float*)(smem + OFF_YY1);

  // Row-relative z storage: zr[g][c] = z[16*(4*(hq^g)+c) + lm]. All static.
  float zr[4][4];
  #pragma unroll
  for (int gg = 0; gg < 4; ++gg)
    #pragma unroll
    for (int c = 0; c < 4; ++c) zr[gg][c] = 1.f;   // power b0 = ones

  // matvec: canonical zpk assembled from zr via selg2 (g = q^hq).
  auto matvec = [&](f32x4& y0, f32x4& y1) {
    f16x2 zrpk[4][2];
    #pragma unroll
    for (int gg = 0; gg < 4; ++gg) {
      zrpk[gg][0] = pk2(zr[gg][0], zr[gg][1]);
      zrpk[gg][1] = pk2(zr[gg][2], zr[gg][3]);
    }
    f16x2 zpk[8];
    #pragma unroll
    for (int j2 = 0; j2 < 8; ++j2) {
      const int q = j2 >> 1, pb = j2 & 1;
      zpk[j2] = selg2(zrpk[0][pb], zrpk[1][pb], zrpk[2][pb], zrpk[3][pb], q ^ hq);
    }
    // exact f32 diag z: zd0 = z[16*w8+lm], zd1 = z[16*(w8+8)+lm]
    float zd0 = 0.f, zd1 = 0.f;
    {
      const int g0 = (w8 >> 2) ^ hq;      // zd1 uses g0^2
      const int cc0 = w8 & 3;             // wave-uniform
      #pragma unroll
      for (int cc = 0; cc < 4; ++cc)
        if (cc0 == cc) {
          const float ab = (g0 & 1) ? zr[1][cc] : zr[0][cc];
          const float cd = (g0 & 1) ? zr[3][cc] : zr[2][cc];
          zd0 = (g0 & 2) ? cd : ab;
          zd1 = (g0 & 2) ? ab : cd;
        }
    }
    y0 = dgv0 * zd0;
    y1 = dgv1 * zd1;
    #pragma unroll
    for (int j2 = 0; j2 < 8; ++j2) {
      #pragma unroll
      for (int c = 0; c < 4; ++c) {
        y0[c] = dot2f(ah[0][j2][c], zpk[j2], y0[c]);
        y1[c] = dot2f(ah[1][j2][c], zpk[j2], y1[c]);
      }
    }
    #pragma unroll
    for (int c = 0; c < 4; ++c) { y0[c] = red16(y0[c]); y1[c] = red16(y1[c]); }
  };
  auto publish = [&](float* YYp, const f32x4& y0, const f32x4& y1) {
    if (mk) {
      const float ya = (cw == 0) ? y0[0] : (cw == 1) ? y0[1] : (cw == 2) ? y0[2] : y0[3];
      const float yb = (cw == 0) ? y1[0] : (cw == 1) ? y1[1] : (cw == 2) ? y1[2] : y1[3];
      YYp[16 * w8 + lm]       = ya;
      YYp[16 * (w8 + 8) + lm] = yb;
    }
  };

  // ===== Phase 2: power iteration; step from ||Qb|| with safety margin =====
  float step;
  {
    float lam = 0.f;
    #pragma unroll 1
    for (int pi = 0; pi < POWER_ITERS; ++pi) {
      f32x4 y0, y1; matvec(y0, y1);
      float* YYp = (pi & 1) ? YY1 : YY0;
      publish(YYp, y0, y1);
      __syncthreads();
      float nrm = 0.f;
      #pragma unroll
      for (int gg = 0; gg < 4; ++gg)
        #pragma unroll
        for (int c = 0; c < 4; ++c) {
          const float tv = YYp[(((hq ^ gg) * 4 + c) << 4) + lm];
          nrm += tv * tv;
          zr[gg][c] = tv;
        }
      nrm = rfl(red16(nrm));
      const float nn = sqrtf(nrm);
      lam = nn;                               // ||Q b_{k-1}|| (b normalized)
      const float rb = 1.f / (nn + 1e-12f);
      #pragma unroll
      for (int gg = 0; gg < 4; ++gg)
        #pragma unroll
        for (int c = 0; c < 4; ++c) zr[gg][c] *= rb;
    }
    step = 1.f / (2.f * (1.15f * lam) + 1e-6f);
  }

  // ===== Phase 3: FISTA + gradient-based adaptive restart — quarter-split
  // state, 1 barrier/iter, tiered tolerance exit. =====
  float wo4[4], rr4[4];
  #pragma unroll
  for (int c = 0; c < 4; ++c) {
    rr4[c] = rets[b * NA + ((4 * hq + c) << 4) + lm];
    wo4[c] = 1.f / 256.f;
  }
  #pragma unroll
  for (int gg = 0; gg < 4; ++gg)
    #pragma unroll
    for (int c = 0; c < 4; ++c) zr[gg][c] = 1.f / 256.f;
  float tt = 1.f;
  float tauw = 1e30f;
  float kest = 32.f;

  #pragma unroll 1
  for (int it = 0; it < PGD_ITERS; ++it) {
    f32x4 y0, y1; matvec(y0, y1);
    float* YYp = (it & 1) ? YY0 : YY1;
    publish(YYp, y0, y1);
    __syncthreads();

    // own columns only: v = z - step*(2y - r)
    float vq[4];
    #pragma unroll
    for (int c = 0; c < 4; ++c) {
      const float yv = YYp[((4 * hq + c) << 4) + lm];
      vq[c] = zr[0][c] - step * (2.f * yv - rr4[c]);
    }

    // Projection (verified R10/R12/R14/R17): uniform-scalar secant w/ early
    // exit; f-tol 4e-5 (tau error invisible at the f16-Q floor).
    float lo = -1e30f, hi = 1e30f;
    float tau = tauw;
    float fprev = 0.f, tprev = 0.f;
    bool have = false;
    #pragma unroll 1
    for (int nit = 0; nit < 16; ++nit) {
      float sp = clamp01(vq[0] - tau) + clamp01(vq[1] - tau)
               + clamp01(vq[2] - tau) + clamp01(vq[3] - tau);
      const float s = redwave_add(sp);
      if (nit == 0) {
        const float pm = redwave_max(fmaxf(fmaxf(vq[0], vq[1]), fmaxf(vq[2], vq[3])));
        lo = pm - 1.0f; hi = pm;              // root always in [max-1, max]
        if (!(tau > lo && tau < hi)) { tau = 0.5f * (lo + hi); continue; }
      }
      const float f = s - 1.f;
      if (fabsf(f) <= 4e-5f) break;
      if (f > 0.f) lo = tau; else hi = tau;
      if (hi - lo < 1e-7f) break;
      float kc = have ? ((f - fprev) / (tprev - tau)) : kest;
      if (!(kc > 0.5f)) kc = kest;
      const float tn = tau + f / kc;
      fprev = f; tprev = tau; have = true;
      kest = fmaxf(kc, 1.f);
      const float tc = (tn > lo && tn < hi) ? tn : 0.5f * (lo + hi);
      if (tc == tau) break;
      tau = tc;
    }
    tauw = tau;

    // w+ = clamp(v - tau); accumulate exit metric and restart test
    float wn4[4];
    float dsum = 0.f, rs = 0.f;
    #pragma unroll
    for (int c = 0; c < 4; ++c) {
      wn4[c] = clamp01(vq[c] - tau);
      dsum += fabsf(wn4[c] - wo4[c]);
      rs   += (zr[0][c] - wn4[c]) * (wn4[c] - wo4[c]);
    }
    const float dtot = redwave_add(dsum);
    const float rtot = redwave_add(rs);

    // Tiered early exit along the measured accuracy-time curve:
    // tol 1e-5/1e-4 -> absmax 9.8e-4; 3e-4-tiered -> 1.95e-3 (validated).
    // base 5e-4, >=40 iters 1e-3, >=80 iters 2e-3 -> predicted 3-5e-3,
    // 4-6x under the 2e-2 threshold.
    const float tol = (it >= 80) ? 2e-3f : (it >= 40) ? 1e-3f : 5e-4f;
    const bool fin = (it == PGD_ITERS - 1) || (dtot <= tol);
    if (fin) {
      if (w8 == 0) {
        #pragma unroll
        for (int c = 0; c < 4; ++c)
          out[(size_t)b * NA + ((4 * hq + c) << 4) + lm] = wn4[c];
      }
      break;
    }

    // gradient restart: momentum opposes the step -> reset tt (coef -> 0)
    if (rtot > 0.f) tt = 1.f;
    const float tnew = 0.5f * (1.f + sqrtf(1.f + 4.f * tt * tt));
    const float coef = (tt - 1.f) / tnew;
    float zn[4];
    #pragma unroll
    for (int c = 0; c < 4; ++c) {
      zn[c] = wn4[c] + coef * (wn4[c] - wo4[c]);
      wo4[c] = wn4[c];
    }
    tt = tnew;

    // f32-exact 3-way exchange refills the row-relative replicas
    #pragma unroll
    for (int c = 0; c < 4; ++c) {
      zr[0][c] = zn[c];
      zr[1][c] = __shfl_xor(zn[c], 16);
      zr[2][c] = __shfl_xor(zn[c], 32);
      zr[3][c] = __shfl_xor(zn[c], 48);
    }
  }
}

extern "C" void kernel_launch(void* const* d_in, const int* in_sizes, int n_in,
                              void* d_out, int out_size, void* d_ws, size_t ws_size,
                              hipStream_t stream) {
  (void)in_sizes; (void)n_in; (void)out_size; (void)d_ws; (void)ws_size;
  const float* rets = (const float*)d_in[0];
  const float* cov  = (const float*)d_in[1];
  const float* gam  = (const float*)d_in[2];
  const float* alp  = (const float*)d_in[3];
  float* out = (float*)d_out;
  hipLaunchKernelGGL(markowitz_kernel, dim3(NS), dim3(512), 0, stream,
                     rets, cov, gam, alp, out);
}

// Round 28
// 203.406 us; speedup vs baseline: 12.2254x; 1.0683x over previous
//
#include <hip/hip_runtime.h>

#define NS 512
#define NA 256
#define PGD_ITERS 300
#define POWER_ITERS 6

typedef _Float16 f16;
typedef __attribute__((ext_vector_type(2))) _Float16 f16x2;
typedef __attribute__((ext_vector_type(4))) _Float16 f16x4;
typedef __attribute__((ext_vector_type(8))) _Float16 f16x8;
typedef __attribute__((ext_vector_type(4))) float f32x4;

// LDS layout (bytes). STG (32x260 f32) / CH (256x40 f16) live only during
// the syrk; YY0/YY1 double-buffer the y-exchange. DTMP overlays YY0+YY1.
#define CSTR 260            // f32 staging row stride (elems)
#define TSTR 40             // f16 C^T tile row stride (elems) = 80 B (32k+pad)
#define OFF_CH  33280       // STG: 32*260*4
#define OFF_YY0 53760       // CH:  256*40*2 = 20480
#define OFF_YY1 54784
#define LDS_BYTES 55808     // 2 blocks/CU by LDS (111.6 KB < 160 KB)

// ---- cross-lane primitives (VALU DPP; minimal DS-pipe traffic) ----
// SAFETY: all call sites have FULL exec; branches only on wave-uniform
// scalars (readlane/readfirstlane results or wave-id comparisons).
template<int CTRL>
__device__ __forceinline__ float dpp_add(float x) {
  const int r = __builtin_amdgcn_update_dpp(0, __float_as_int(x), CTRL, 0xF, 0xF, true);
  return x + __int_as_float(r);
}
template<int CTRL>
__device__ __forceinline__ float dpp_max(float x) {
  const int r = __builtin_amdgcn_update_dpp(0, __float_as_int(x), CTRL, 0xF, 0xF, true);
  return fmaxf(x, __int_as_float(r));
}
__device__ __forceinline__ float red16(float x) {
  x = dpp_add<0x121>(x);  // row_ror:1
  x = dpp_add<0x122>(x);  // row_ror:2
  x = dpp_add<0x124>(x);  // row_ror:4
  x = dpp_add<0x128>(x);  // row_ror:8
  return x;
}
__device__ __forceinline__ float redwave_add(float x) {
  x = red16(x);
  {
    const int r = __builtin_amdgcn_update_dpp(0, __float_as_int(x), 0x142, 0xA, 0xF, true);
    x += __int_as_float(r);
  }
  {
    const int r = __builtin_amdgcn_update_dpp(0, __float_as_int(x), 0x143, 0xC, 0xF, true);
    x += __int_as_float(r);
  }
  return __int_as_float(__builtin_amdgcn_readlane(__float_as_int(x), 63));
}
__device__ __forceinline__ float redwave_max(float x) {
  x = dpp_max<0x121>(x);
  x = dpp_max<0x122>(x);
  x = dpp_max<0x124>(x);
  x = dpp_max<0x128>(x);
  {
    const int r = __builtin_amdgcn_update_dpp(__float_as_int(x), __float_as_int(x), 0x142, 0xA, 0xF, false);
    x = fmaxf(x, __int_as_float(r));
  }
  {
    const int r = __builtin_amdgcn_update_dpp(__float_as_int(x), __float_as_int(x), 0x143, 0xC, 0xF, false);
    x = fmaxf(x, __int_as_float(r));
  }
  return __int_as_float(__builtin_amdgcn_readlane(__float_as_int(x), 63));
}
__device__ __forceinline__ float rfl(float x) {
  return __int_as_float(__builtin_amdgcn_readfirstlane(__float_as_int(x)));
}
__device__ __forceinline__ float clamp01(float x) {
  return __builtin_amdgcn_fmed3f(x, 0.f, 1.f);
}
__device__ __forceinline__ f16x2 pk2(float a, float b) {
  return __builtin_bit_cast(f16x2, __builtin_amdgcn_cvt_pkrtz(a, b));
}
__device__ __forceinline__ float dot2f(f16x2 a, f16x2 b, float c) {
  return __builtin_amdgcn_fdot2(a, b, c, false);   // v_dot2_f32_f16
}
// select 1-of-4 packed f16x2 by 2-bit index (3 cndmask)
__device__ __forceinline__ f16x2 selg2(f16x2 a0, f16x2 a1, f16x2 a2, f16x2 a3, int g) {
  const int i0 = __builtin_bit_cast(int, a0);
  const int i1 = __builtin_bit_cast(int, a1);
  const int i2 = __builtin_bit_cast(int, a2);
  const int i3 = __builtin_bit_cast(int, a3);
  const int ab = (g & 1) ? i1 : i0;
  const int cd = (g & 1) ? i3 : i2;
  return __builtin_bit_cast(f16x2, (g & 2) ? cd : ab);
}

__global__ __launch_bounds__(512, 4) void markowitz_kernel(
    const float* __restrict__ rets, const float* __restrict__ cov,
    const float* __restrict__ gam,  const float* __restrict__ alp,
    float* __restrict__ out)
{
  __shared__ char smem[LDS_BYTES] __attribute__((aligned(16)));
  float* STG  = (float*)smem;
  f16*   CH   = (f16*)(smem + OFF_CH);
  float* DTMP = (float*)(smem + OFF_YY0);   // 512 f32 overlay (YY0+YY1)

  const int t    = threadIdx.x;
  const int lane = t & 63;
  const int w8   = t >> 6;          // wave 0..7
  const int lm   = lane & 15;       // column-within-tile owner index
  const int hq   = lane >> 4;       // row-subgroup index

  const int b = blockIdx.x;
  const float g  = gam[b];
  const float aa = fabsf(alp[b]);
  const float* __restrict__ C = cov + (size_t)b * (NA * NA);

  const bool mk = ((lm >> 2) == hq);
  const int  cw = lm & 3;

  // ===== Phase 1: Q = (gC)^T(gC), f16-packed registers + exact f32 diag.
  // 32 k-rows/round, software-prefetched.
  // ah[ii][j2][c] packs Q[16*(w8+8ii)+4hq+c][16*(2j2)+lm | 16*(2j2+1)+lm]
  f16x2 ah[2][8][4];
  float dacc = 0.f;

  const int kk_s = t >> 4;          // staging row 0..31
  const int ib_s = (t & 15) << 4;   // staging col 0,16,...,240
  float4 pf[4];

  #pragma unroll
  for (int pass = 0; pass < 2; ++pass) {
    f32x4 acc1[16];
    #pragma unroll
    for (int j = 0; j < 16; ++j) acc1[j] = f32x4{0.f, 0.f, 0.f, 0.f};

    { // prefetch round 0
      const float* src = C + (size_t)kk_s * NA + ib_s;
      #pragma unroll
      for (int j4 = 0; j4 < 4; ++j4) pf[j4] = *(const float4*)(src + 4 * j4);
    }

    #pragma unroll 1
    for (int kb = 0; kb < 8; ++kb) {
      { // stage 32x256 f32 from prefetch regs (gamma-folded)
        float* dst = STG + kk_s * CSTR + ib_s;
        #pragma unroll
        for (int j4 = 0; j4 < 4; ++j4)
          *(float4*)(dst + 4 * j4) = make_float4(pf[j4].x * g, pf[j4].y * g,
                                                 pf[j4].z * g, pf[j4].w * g);
      }
      __syncthreads();
      if (kb < 7) { // issue next round's loads; latency hides under below
        const float* src = C + (size_t)((kb + 1) * 32 + kk_s) * NA + ib_s;
        #pragma unroll
        for (int j4 = 0; j4 < 4; ++j4) pf[j4] = *(const float4*)(src + 4 * j4);
      }
      { // transpose to f16 C^T tile (k=0..31); pass 0 also exact diag
        const int ti = t & 255;
        const int th = t >> 8;          // k-half 0/1 (16 k each)
        f16x8 v0, v1;
        #pragma unroll
        for (int s2 = 0; s2 < 8; ++s2) {
          const float x0 = STG[(16 * th + s2) * CSTR + ti];
          const float x1 = STG[(16 * th + 8 + s2) * CSTR + ti];
          if (pass == 0) dacc += x0 * x0 + x1 * x1;
          v0[s2] = (f16)x0;
          v1[s2] = (f16)x1;
        }
        *(f16x8*)(CH + ti * TSTR + 16 * th)     = v0;
        *(f16x8*)(CH + ti * TSTR + 16 * th + 8) = v1;
      }
      __syncthreads();
      const int I = w8 + 8 * pass;
      const f16x4 aH0 = *(const f16x4*)(CH + (16 * I + lm) * TSTR + 4 * hq);
      const f16x4 aH1 = *(const f16x4*)(CH + (16 * I + lm) * TSTR + 16 + 4 * hq);
      #pragma unroll
      for (int J = 0; J < 16; ++J) {
        const f16x4 bH0 = *(const f16x4*)(CH + (16 * J + lm) * TSTR + 4 * hq);
        const f16x4 bH1 = *(const f16x4*)(CH + (16 * J + lm) * TSTR + 16 + 4 * hq);
        acc1[J] = __builtin_amdgcn_mfma_f32_16x16x16f16(aH0, bH0, acc1[J], 0, 0, 0);
        acc1[J] = __builtin_amdgcn_mfma_f32_16x16x16f16(aH1, bH1, acc1[J], 0, 0, 0);
      }
    }
    // pack to f16 pairs (canonical); zero diag slot (handled exactly via dgv)
    const int dj = w8 + 8 * pass;
    #pragma unroll
    for (int j2 = 0; j2 < 8; ++j2) {
      #pragma unroll
      for (int c = 0; c < 4; ++c) {
        float a0 = acc1[2 * j2][c];
        float a1 = acc1[2 * j2 + 1][c];
        if (2 * j2     == dj && lm == 4 * hq + c) a0 = 0.f;
        if (2 * j2 + 1 == dj && lm == 4 * hq + c) a1 = 0.f;
        ah[pass][j2][c] = pk2(a0, a1);
      }
    }
  }

  // exact diag sums -> LDS overlay
  {
    const int ti = t & 255;
    const int th = t >> 8;
    DTMP[th * 256 + ti] = dacc;
  }
  __syncthreads();
  float dg0 = 0.f, dg1 = 0.f;
  if (mk) {
    const int c0 = 16 * w8 + lm, c1 = 16 * (w8 + 8) + lm;
    dg0 = DTMP[c0] + DTMP[256 + c0] + aa;
    dg1 = DTMP[c1] + DTMP[256 + c1] + aa;
  }
  f32x4 dgv0, dgv1;
  #pragma unroll
  for (int p = 0; p < 4; ++p) {
    dgv0[p] = (lm == 4 * hq + p) ? dg0 : 0.f;
    dgv1[p] = (lm == 4 * hq + p) ? dg1 : 0.f;
  }
  __syncthreads();   // DTMP dead

  float* const YY0 = (float*)(smem + OFF_YY0);
  float* const YY1 = (float*)(smem + OFF_YY1);

  // Row-relative z storage: zr[g][c] = z[16*(4*(hq^g)+c) + lm]. All static.
  float zr[4][4];
  #pragma unroll
  for (int gg = 0; gg < 4; ++gg)
    #pragma unroll
    for (int c = 0; c < 4; ++c) zr[gg][c] = 1.f;   // power b0 = ones

  // matvec: canonical zpk assembled from zr via selg2 (g = q^hq).
  auto matvec = [&](f32x4& y0, f32x4& y1) {
    f16x2 zrpk[4][2];
    #pragma unroll
    for (int gg = 0; gg < 4; ++gg) {
      zrpk[gg][0] = pk2(zr[gg][0], zr[gg][1]);
      zrpk[gg][1] = pk2(zr[gg][2], zr[gg][3]);
    }
    f16x2 zpk[8];
    #pragma unroll
    for (int j2 = 0; j2 < 8; ++j2) {
      const int q = j2 >> 1, pb = j2 & 1;
      zpk[j2] = selg2(zrpk[0][pb], zrpk[1][pb], zrpk[2][pb], zrpk[3][pb], q ^ hq);
    }
    // exact f32 diag z: zd0 = z[16*w8+lm], zd1 = z[16*(w8+8)+lm]
    float zd0 = 0.f, zd1 = 0.f;
    {
      const int g0 = (w8 >> 2) ^ hq;      // zd1 uses g0^2
      const int cc0 = w8 & 3;             // wave-uniform
      #pragma unroll
      for (int cc = 0; cc < 4; ++cc)
        if (cc0 == cc) {
          const float ab = (g0 & 1) ? zr[1][cc] : zr[0][cc];
          const float cd = (g0 & 1) ? zr[3][cc] : zr[2][cc];
          zd0 = (g0 & 2) ? cd : ab;
          zd1 = (g0 & 2) ? ab : cd;
        }
    }
    y0 = dgv0 * zd0;
    y1 = dgv1 * zd1;
    #pragma unroll
    for (int j2 = 0; j2 < 8; ++j2) {
      #pragma unroll
      for (int c = 0; c < 4; ++c) {
        y0[c] = dot2f(ah[0][j2][c], zpk[j2], y0[c]);
        y1[c] = dot2f(ah[1][j2][c], zpk[j2], y1[c]);
      }
    }
    #pragma unroll
    for (int c = 0; c < 4; ++c) { y0[c] = red16(y0[c]); y1[c] = red16(y1[c]); }
  };
  auto publish = [&](float* YYp, const f32x4& y0, const f32x4& y1) {
    if (mk) {
      const float ya = (cw == 0) ? y0[0] : (cw == 1) ? y0[1] : (cw == 2) ? y0[2] : y0[3];
      const float yb = (cw == 0) ? y1[0] : (cw == 1) ? y1[1] : (cw == 2) ? y1[2] : y1[3];
      YYp[16 * w8 + lm]       = ya;
      YYp[16 * (w8 + 8) + lm] = yb;
    }
  };

  // ===== Phase 2: power iteration; step from ||Qb|| with safety margin =====
  float step;
  {
    float lam = 0.f;
    #pragma unroll 1
    for (int pi = 0; pi < POWER_ITERS; ++pi) {
      f32x4 y0, y1; matvec(y0, y1);
      float* YYp = (pi & 1) ? YY1 : YY0;
      publish(YYp, y0, y1);
      __syncthreads();
      float nrm = 0.f;
      #pragma unroll
      for (int gg = 0; gg < 4; ++gg)
        #pragma unroll
        for (int c = 0; c < 4; ++c) {
          const float tv = YYp[(((hq ^ gg) * 4 + c) << 4) + lm];
          nrm += tv * tv;
          zr[gg][c] = tv;
        }
      nrm = rfl(red16(nrm));
      const float nn = sqrtf(nrm);
      lam = nn;                               // ||Q b_{k-1}|| (b normalized)
      const float rb = 1.f / (nn + 1e-12f);
      #pragma unroll
      for (int gg = 0; gg < 4; ++gg)
        #pragma unroll
        for (int c = 0; c < 4; ++c) zr[gg][c] *= rb;
    }
    step = 1.f / (2.f * (1.15f * lam) + 1e-6f);
  }

  // ===== Phase 3: FISTA + gradient-based adaptive restart — quarter-split
  // state, 1 barrier/iter, tiered tolerance exit. =====
  float wo4[4], rr4[4];
  #pragma unroll
  for (int c = 0; c < 4; ++c) {
    rr4[c] = rets[b * NA + ((4 * hq + c) << 4) + lm];
    wo4[c] = 1.f / 256.f;
  }
  #pragma unroll
  for (int gg = 0; gg < 4; ++gg)
    #pragma unroll
    for (int c = 0; c < 4; ++c) zr[gg][c] = 1.f / 256.f;
  float tt = 1.f;
  float tauw = 1e30f;
  float kest = 32.f;

  #pragma unroll 1
  for (int it = 0; it < PGD_ITERS; ++it) {
    f32x4 y0, y1; matvec(y0, y1);
    float* YYp = (it & 1) ? YY0 : YY1;
    publish(YYp, y0, y1);
    __syncthreads();

    // own columns only: v = z - step*(2y - r)
    float vq[4];
    #pragma unroll
    for (int c = 0; c < 4; ++c) {
      const float yv = YYp[((4 * hq + c) << 4) + lm];
      vq[c] = zr[0][c] - step * (2.f * yv - rr4[c]);
    }

    // Projection (verified R10/R12/R14/R17): uniform-scalar secant w/ early
    // exit; f-tol 4e-5 (tau error invisible at the f16-Q floor).
    float lo = -1e30f, hi = 1e30f;
    float tau = tauw;
    float fprev = 0.f, tprev = 0.f;
    bool have = false;
    #pragma unroll 1
    for (int nit = 0; nit < 16; ++nit) {
      float sp = clamp01(vq[0] - tau) + clamp01(vq[1] - tau)
               + clamp01(vq[2] - tau) + clamp01(vq[3] - tau);
      const float s = redwave_add(sp);
      if (nit == 0) {
        const float pm = redwave_max(fmaxf(fmaxf(vq[0], vq[1]), fmaxf(vq[2], vq[3])));
        lo = pm - 1.0f; hi = pm;              // root always in [max-1, max]
        if (!(tau > lo && tau < hi)) { tau = 0.5f * (lo + hi); continue; }
      }
      const float f = s - 1.f;
      if (fabsf(f) <= 4e-5f) break;
      if (f > 0.f) lo = tau; else hi = tau;
      if (hi - lo < 1e-7f) break;
      float kc = have ? ((f - fprev) / (tprev - tau)) : kest;
      if (!(kc > 0.5f)) kc = kest;
      const float tn = tau + f / kc;
      fprev = f; tprev = tau; have = true;
      kest = fmaxf(kc, 1.f);
      const float tc = (tn > lo && tn < hi) ? tn : 0.5f * (lo + hi);
      if (tc == tau) break;
      tau = tc;
    }
    tauw = tau;

    // w+ = clamp(v - tau); accumulate exit metric and restart test
    float wn4[4];
    float dsum = 0.f, rs = 0.f;
    #pragma unroll
    for (int c = 0; c < 4; ++c) {
      wn4[c] = clamp01(vq[c] - tau);
      dsum += fabsf(wn4[c] - wo4[c]);
      rs   += (zr[0][c] - wn4[c]) * (wn4[c] - wo4[c]);
    }
    const float dtot = redwave_add(dsum);
    const float rtot = redwave_add(rs);

    // Tiered early exit — final calibrated point on the measured curve:
    // {1e-5, 1e-4} -> 9.8e-4; {3e-4 tiers} -> 1.95e-3; {5e-4 tiers} ->
    // 1.95e-3 (model conservative: restart collapses dtot near solution).
    // base 1e-3, >=32 iters 2e-3, >=64 iters 4e-3 -> predicted 2-8e-3,
    // still >2.5x under the 2e-2 threshold.
    const float tol = (it >= 64) ? 4e-3f : (it >= 32) ? 2e-3f : 1e-3f;
    const bool fin = (it == PGD_ITERS - 1) || (dtot <= tol);
    if (fin) {
      if (w8 == 0) {
        #pragma unroll
        for (int c = 0; c < 4; ++c)
          out[(size_t)b * NA + ((4 * hq + c) << 4) + lm] = wn4[c];
      }
      break;
    }

    // gradient restart: momentum opposes the step -> reset tt (coef -> 0)
    if (rtot > 0.f) tt = 1.f;
    const float tnew = 0.5f * (1.f + sqrtf(1.f + 4.f * tt * tt));
    const float coef = (tt - 1.f) / tnew;
    float zn[4];
    #pragma unroll
    for (int c = 0; c < 4; ++c) {
      zn[c] = wn4[c] + coef * (wn4[c] - wo4[c]);
      wo4[c] = wn4[c];
    }
    tt = tnew;

    // f32-exact 3-way exchange refills the row-relative replicas
    #pragma unroll
    for (int c = 0; c < 4; ++c) {
      zr[0][c] = zn[c];
      zr[1][c] = __shfl_xor(zn[c], 16);
      zr[2][c] = __shfl_xor(zn[c], 32);
      zr[3][c] = __shfl_xor(zn[c], 48);
    }
  }
}

extern "C" void kernel_launch(void* const* d_in, const int* in_sizes, int n_in,
                              void* d_out, int out_size, void* d_ws, size_t ws_size,
                              hipStream_t stream) {
  (void)in_sizes; (void)n_in; (void)out_size; (void)d_ws; (void)ws_size;
  const float* rets = (const float*)d_in[0];
  const float* cov  = (const float*)d_in[1];
  const float* gam  = (const float*)d_in[2];
  const float* alp  = (const float*)d_in[3];
  float* out = (float*)d_out;
  hipLaunchKernelGGL(markowitz_kernel, dim3(NS), dim3(512), 0, stream,
                     rets, cov, gam, alp, out);
}